// Round 12
// baseline (3801.086 us; speedup 1.0000x reference)
//
#include <hip/hip_runtime.h>
#include <hip/hip_bf16.h>
#include <math.h>

// Problem constants
#define B_   8
#define NB_  2048
#define NS_  1024
#define Cc_  768
#define HID_ 3072
#define NP_  1024
#define NH_  6
#define HD_  128

__device__ __forceinline__ float gelu_exact(float v) {
  return 0.5f * v * (1.0f + erff(v * 0.7071067811865476f));
}

// split f32 into 3 bf16 planes (truncation; dropped residual ~2^-24 rel)
__device__ __forceinline__ void split3(float v, unsigned short& h,
                                       unsigned short& m, unsigned short& l) {
  unsigned hb = __float_as_uint(v) & 0xffff0000u;
  float r1 = v - __uint_as_float(hb);
  unsigned mb = __float_as_uint(r1) & 0xffff0000u;
  float r2 = r1 - __uint_as_float(mb);
  unsigned lb = __float_as_uint(r2) & 0xffff0000u;
  h = (unsigned short)(hb >> 16);
  m = (unsigned short)(mb >> 16);
  l = (unsigned short)(lb >> 16);
}

typedef short bf16x8 __attribute__((ext_vector_type(8)));
typedef float f32x4 __attribute__((ext_vector_type(4)));

#define BLOCK_REDUCE_ADD(red, tid)                                              \
  for (int off_ = 128; off_; off_ >>= 1) {                                      \
    if ((tid) < off_) red[(tid)] += red[(tid) + off_];                          \
    __syncthreads();                                                            \
  }

// ---------------- LayerNorm -> 3 bf16 planes [row][3*768] ----------------
__global__ __launch_bounds__(256) void ln_split(
    const float* __restrict__ x, unsigned short* __restrict__ y,
    const float* __restrict__ w, const float* __restrict__ b) {
  __shared__ float red[256];
  int row = blockIdx.x, tid = threadIdx.x;
  const float* xr = x + (size_t)row * Cc_;
  float v0 = xr[tid], v1 = xr[tid + 256], v2 = xr[tid + 512];
  red[tid] = v0 + v1 + v2;
  __syncthreads();
  BLOCK_REDUCE_ADD(red, tid);
  float mu = red[0] / (float)Cc_;
  __syncthreads();
  float d0 = v0 - mu, d1 = v1 - mu, d2 = v2 - mu;
  red[tid] = d0 * d0 + d1 * d1 + d2 * d2;
  __syncthreads();
  BLOCK_REDUCE_ADD(red, tid);
  float var = red[0] / (float)Cc_;
  float rs = 1.0f / sqrtf(var + 1e-5f);
  unsigned short* yr = y + (size_t)row * 2304;
  float vals[3] = {d0 * rs * w[tid] + b[tid],
                   d1 * rs * w[tid + 256] + b[tid + 256],
                   d2 * rs * w[tid + 512] + b[tid + 512]};
#pragma unroll
  for (int t = 0; t < 3; ++t) {
    int c = tid + (t << 8);
    unsigned short h16, m16, l16;
    split3(vals[t], h16, m16, l16);
    yr[c] = h16; yr[768 + c] = m16; yr[1536 + c] = l16;
  }
}

// ---------------- f32 [8192][768] -> 3 bf16 planes ----------------
__global__ __launch_bounds__(256) void split_kernel(
    const float* __restrict__ x, unsigned short* __restrict__ y) {
  size_t idx = (size_t)blockIdx.x * 256 + threadIdx.x;  // < 8192*768
  int c = (int)(idx % Cc_);
  int row = (int)(idx / Cc_);
  unsigned short h16, m16, l16;
  split3(x[idx], h16, m16, l16);
  unsigned short* yr = y + (size_t)row * 2304;
  yr[c] = h16; yr[768 + c] = m16; yr[1536 + c] = l16;
}

// ---------------- Row L2-normalize ----------------
__global__ __launch_bounds__(256) void rownorm_kernel(
    const float* __restrict__ x, float* __restrict__ y) {
  __shared__ float red[256];
  int row = blockIdx.x, tid = threadIdx.x;
  const float* xr = x + (size_t)row * Cc_;
  float* yr = y + (size_t)row * Cc_;
  float v0 = xr[tid], v1 = xr[tid + 256], v2 = xr[tid + 512];
  red[tid] = v0 * v0 + v1 * v1 + v2 * v2;
  __syncthreads();
  BLOCK_REDUCE_ADD(red, tid);
  float den = fmaxf(sqrtf(red[0]), 1e-12f);
  yr[tid]       = v0 / den;
  yr[tid + 256] = v1 / den;
  yr[tid + 512] = v2 / den;
}

// --------- weight convert: W rows k in [0,K), col ncol0+n -> out[N][3K] ----
__global__ __launch_bounds__(256) void wconv(
    const float* __restrict__ W, unsigned short* __restrict__ out,
    int K, int N, int ldw, int ncol0) {
  int k = blockIdx.x * 256 + threadIdx.x;
  int n = blockIdx.y;
  float v = W[(size_t)k * ldw + ncol0 + n];
  unsigned short h16, m16, l16;
  split3(v, h16, m16, l16);
  size_t base = (size_t)n * 3 * K;
  out[base + k] = h16;
  out[base + K + k] = m16;
  out[base + 2 * K + k] = l16;
}

// ---------------- MFMA GEMM over 3-split bf16 planes ----------------
// A planes [M][3K] bf16; B planes [N][3K] bf16 (op-B transposed).
// K'' = 6K via segments pa={0,0,1,0,1,2}, pb={0,1,0,2,1,0}.
// 128x128 tile, 4 waves, mfma_f32_16x16x32_bf16, dbuf LDS, one
// lgkmcnt(0)+s_barrier per 64-wide k-tile. XCD-aware block swizzle
// (requires gridDim.x*gridDim.y % 8 == 0).
// z: batch via azs/bzs/zstride strides AND/OR reduction split (z%nsplit).
// EPI: 5 = gelu(v+bias) -> 3 bf16 planes Cs[m][3*Kout]
//      6 = f32:  Cf[z*zstride + m*ldc + n] = v
//      7 = f32:  Cf[z*zstride + m*ldc + n] += v
template <int EPI, bool AGATHER, bool MDEV>
__global__ __launch_bounds__(256) void mgemm(
    const unsigned short* __restrict__ Ap, const unsigned short* __restrict__ Bp,
    float* __restrict__ Cf, unsigned short* __restrict__ Cs,
    const float* __restrict__ bias,
    const int* __restrict__ perm, const int* __restrict__ mdev,
    int M, int N, int K, int ldc, int Kout, int nsplit,
    long azs, long bzs, long zstride, float scale) {
  __shared__ unsigned short As[2][8192];
  __shared__ unsigned short Bs[2][8192];
  int z = blockIdx.z;
  // XCD swizzle: contiguous y-chunk per XCD
  int gx = gridDim.x;
  int id = blockIdx.y * gx + blockIdx.x;
  int per = (gx * gridDim.y) >> 3;
  int nid = (id & 7) * per + (id >> 3);
  int bx = nid % gx, by = nid / gx;
  int Me = MDEV ? mdev[0] : M;
  int m0 = by * 128, n0 = bx * 128;
  if (MDEV && m0 >= Me) return;
  const unsigned short* ApB = Ap + (size_t)z * azs;
  const unsigned short* BpB = Bp + (size_t)z * bzs;
  int tid = threadIdx.x;
  int lane = tid & 63, w = tid >> 6;
  int wr = w >> 1, wc = w & 1;
  int K3 = 3 * K;
  int tps = K >> 6;        // 64-wide tiles per plane-segment
  int KT = 6 * tps;
  int span = KT / nsplit;
  int zr = z % nsplit;
  int tt0 = zr * span, tt1 = tt0 + span;

  const unsigned short* agp[4];
  const unsigned short* bgp[4];
  int wswz[4];
#pragma unroll
  for (int p = 0; p < 4; ++p) {
    int r = (tid >> 3) + 32 * p;
    int ma = m0 + r;
    if (MDEV) ma = min(ma, Me - 1);
    if (AGATHER) ma = perm[ma];
    agp[p] = ApB + (size_t)ma * K3 + (tid & 7) * 8;
    bgp[p] = BpB + (size_t)(n0 + r) * K3 + (tid & 7) * 8;
    wswz[p] = r * 64 + (((tid & 7) ^ (r & 7)) << 3);
  }

  f32x4 acc[4][4];
  f32x4 zero4 = {0.f, 0.f, 0.f, 0.f};
#pragma unroll
  for (int i = 0; i < 4; ++i)
#pragma unroll
    for (int j = 0; j < 4; ++j) acc[i][j] = zero4;

  int kg = lane >> 4;
  int frm[4], frn[4];
#pragma unroll
  for (int f = 0; f < 4; ++f) {
    frm[f] = wr * 64 + f * 16 + (lane & 15);
    frn[f] = wc * 64 + f * 16 + (lane & 15);
  }

  bf16x8 ra[4], rb[4];
  {
    int seg = tt0 / tps, kt = tt0 - seg * tps;
    int pa = (0x210100u >> (4 * seg)) & 0xF;
    int pb = (0x012010u >> (4 * seg)) & 0xF;
    size_t ao = (size_t)(pa * K + kt * 64);
    size_t bo = (size_t)(pb * K + kt * 64);
#pragma unroll
    for (int p = 0; p < 4; ++p) {
      ra[p] = *(const bf16x8*)(agp[p] + ao);
      rb[p] = *(const bf16x8*)(bgp[p] + bo);
    }
  }

  for (int tt = tt0; tt < tt1; ++tt) {
    int cur = tt & 1;
#pragma unroll
    for (int p = 0; p < 4; ++p) {
      *(bf16x8*)&As[cur][wswz[p]] = ra[p];
      *(bf16x8*)&Bs[cur][wswz[p]] = rb[p];
    }
    if (tt + 1 < tt1) {
      int seg = (tt + 1) / tps, kt = (tt + 1) - seg * tps;
      int pa = (0x210100u >> (4 * seg)) & 0xF;
      int pb = (0x012010u >> (4 * seg)) & 0xF;
      size_t ao = (size_t)(pa * K + kt * 64);
      size_t bo = (size_t)(pb * K + kt * 64);
#pragma unroll
      for (int p = 0; p < 4; ++p) {
        ra[p] = *(const bf16x8*)(agp[p] + ao);
        rb[p] = *(const bf16x8*)(bgp[p] + bo);
      }
    }
    asm volatile("s_waitcnt lgkmcnt(0)" ::: "memory");
    __builtin_amdgcn_s_barrier();
#pragma unroll
    for (int ks = 0; ks < 2; ++ks) {
      int ch = ks * 4 + kg;
      bf16x8 af[4], bf[4];
#pragma unroll
      for (int f = 0; f < 4; ++f) {
        int r = frm[f];
        af[f] = *(const bf16x8*)&As[cur][r * 64 + ((ch ^ (r & 7)) << 3)];
      }
#pragma unroll
      for (int f = 0; f < 4; ++f) {
        int r = frn[f];
        bf[f] = *(const bf16x8*)&Bs[cur][r * 64 + ((ch ^ (r & 7)) << 3)];
      }
#pragma unroll
      for (int i = 0; i < 4; ++i)
#pragma unroll
        for (int j = 0; j < 4; ++j)
          acc[i][j] = __builtin_amdgcn_mfma_f32_16x16x32_bf16(
              af[i], bf[j], acc[i][j], 0, 0, 0);
    }
  }

  // epilogue: C/D layout col=lane&15, row=(lane>>4)*4+reg (m89-verified)
#pragma unroll
  for (int i = 0; i < 4; ++i) {
#pragma unroll
    for (int r = 0; r < 4; ++r) {
      int m = m0 + wr * 64 + i * 16 + kg * 4 + r;
      if (MDEV && m >= Me) continue;
#pragma unroll
      for (int j = 0; j < 4; ++j) {
        int n = n0 + wc * 64 + j * 16 + (lane & 15);
        float v = acc[i][j][r] * scale;
        if (EPI == 6) {
          Cf[(size_t)z * zstride + (size_t)m * ldc + n] = v;
        } else if (EPI == 7) {
          Cf[(size_t)z * zstride + (size_t)m * ldc + n] += v;
        } else if (EPI == 5) {
          float t = gelu_exact(v + bias[n]);
          unsigned short h16, m16, l16;
          split3(t, h16, m16, l16);
          size_t base = (size_t)m * 3 * Kout;
          Cs[base + n] = h16;
          Cs[base + Kout + n] = m16;
          Cs[base + 2 * Kout + n] = l16;
        }
      }
    }
  }
}

// ---------------- combine partials: out = bias + addsrc + P0 + P1 ----------
template <bool SCATTER>
__global__ __launch_bounds__(256) void combineP(
    const float* __restrict__ P0, const float* __restrict__ P1,
    const float* __restrict__ bias, const float* __restrict__ addsrc,
    const int* __restrict__ perm, const int* __restrict__ cnt,
    float* __restrict__ out) {
  int m = blockIdx.x;
  int c = threadIdx.x + (blockIdx.y << 8);
  if (SCATTER && m >= cnt[0]) return;
  int mo = SCATTER ? perm[m] : m;
  size_t pm = (size_t)m * 768 + c;
  out[(size_t)mo * 768 + c] =
      bias[c] + addsrc[(size_t)mo * 768 + c] + P0[pm] + P1[pm];
}

// ---------------- f32 GEMM (R5: 128x128, 8x8, reg-prefetch dbuf) ----------
template <int EPI, int TRB, bool AGATHER, bool MDEV>
__global__ __launch_bounds__(256) void gemm128(
    const float* __restrict__ A, const float* __restrict__ Bm,
    float* __restrict__ Cm, const float* __restrict__ bias,
    const float* __restrict__ addsrc, const int* __restrict__ perm,
    const int* __restrict__ mdev,
    int M, int N, int K, int lda, int ldb, int ldc,
    int d1, int d2,
    long a_s1, long a_s2, long a_s3,
    long b_s1, long b_s2, long b_s3,
    long c_s1, long c_s2, long c_s3,
    float scale) {
  __shared__ float As[2][16][132];
  __shared__ float Bs[2][16][132];
  int z = blockIdx.z;
  int z1 = z / (d1 * d2);
  int rem = z - z1 * d1 * d2;
  int z2 = rem / d2, z3 = rem - z2 * d2;
  const float* Ab = A + (size_t)z1 * a_s1 + (size_t)z2 * a_s2 + (size_t)z3 * a_s3;
  const float* Bb = Bm + (size_t)z1 * b_s1 + (size_t)z2 * b_s2 + (size_t)z3 * b_s3;
  float* Cb = Cm + (size_t)z1 * c_s1 + (size_t)z2 * c_s2 + (size_t)z3 * c_s3;
  int Me = MDEV ? mdev[0] : M;
  int m0 = blockIdx.y * 128, n0 = blockIdx.x * 128;
  if (MDEV && m0 >= Me) return;
  int tid = threadIdx.x;
  int tx = tid & 15, ty = tid >> 4;
  int arow = tid >> 2, akq = tid & 3;
  int ma0 = m0 + arow, ma1 = m0 + arow + 64;
  if (MDEV) { ma0 = min(ma0, Me - 1); ma1 = min(ma1, Me - 1); }
  if (AGATHER) { ma0 = perm[ma0]; ma1 = perm[ma1]; }
  const float* Ap0 = Ab + (size_t)ma0 * lda + akq * 4;
  const float* Ap1 = Ab + (size_t)ma1 * lda + akq * 4;
  const float* Bp0;
  const float* Bp1;
  int bw_r0 = 0, bw_c0 = 0, bw_r1 = 0;
  if (TRB == 0) {
    bw_r0 = tid >> 5; bw_c0 = (tid & 31) * 4; bw_r1 = bw_r0 + 8;
    Bp0 = Bb + (size_t)bw_r0 * ldb + n0 + bw_c0;
    Bp1 = Bb + (size_t)bw_r1 * ldb + n0 + bw_c0;
  } else {
    Bp0 = Bb + (size_t)(n0 + arow) * ldb + akq * 4;
    Bp1 = Bb + (size_t)(n0 + arow + 64) * ldb + akq * 4;
  }
  float4 pa0 = *(const float4*)Ap0;
  float4 pa1 = *(const float4*)Ap1;
  float4 pb0 = *(const float4*)Bp0;
  float4 pb1 = *(const float4*)Bp1;
  float acc[8][8] = {};
  int nt = K >> 4;
  for (int t = 0; t < nt; ++t) {
    int cur = t & 1;
    As[cur][akq * 4 + 0][arow] = pa0.x; As[cur][akq * 4 + 1][arow] = pa0.y;
    As[cur][akq * 4 + 2][arow] = pa0.z; As[cur][akq * 4 + 3][arow] = pa0.w;
    As[cur][akq * 4 + 0][arow + 64] = pa1.x; As[cur][akq * 4 + 1][arow + 64] = pa1.y;
    As[cur][akq * 4 + 2][arow + 64] = pa1.z; As[cur][akq * 4 + 3][arow + 64] = pa1.w;
    if (TRB == 0) {
      *(float4*)&Bs[cur][bw_r0][bw_c0] = pb0;
      *(float4*)&Bs[cur][bw_r1][bw_c0] = pb1;
    } else {
      Bs[cur][akq * 4 + 0][arow] = pb0.x; Bs[cur][akq * 4 + 1][arow] = pb0.y;
      Bs[cur][akq * 4 + 2][arow] = pb0.z; Bs[cur][akq * 4 + 3][arow] = pb0.w;
      Bs[cur][akq * 4 + 0][arow + 64] = pb1.x; Bs[cur][akq * 4 + 1][arow + 64] = pb1.y;
      Bs[cur][akq * 4 + 2][arow + 64] = pb1.z; Bs[cur][akq * 4 + 3][arow + 64] = pb1.w;
    }
    if (t + 1 < nt) {
      int kn = (t + 1) << 4;
      pa0 = *(const float4*)&Ap0[kn];
      pa1 = *(const float4*)&Ap1[kn];
      if (TRB == 0) {
        pb0 = *(const float4*)&Bp0[(size_t)kn * ldb];
        pb1 = *(const float4*)&Bp1[(size_t)kn * ldb];
      } else {
        pb0 = *(const float4*)&Bp0[kn];
        pb1 = *(const float4*)&Bp1[kn];
      }
    }
    asm volatile("s_waitcnt lgkmcnt(0)" ::: "memory");
    __builtin_amdgcn_s_barrier();
#pragma unroll
    for (int kk = 0; kk < 16; ++kk) {
      float a[8], b[8];
      *(float4*)&a[0] = *(const float4*)&As[cur][kk][ty * 4];
      *(float4*)&a[4] = *(const float4*)&As[cur][kk][ty * 4 + 64];
      *(float4*)&b[0] = *(const float4*)&Bs[cur][kk][tx * 4];
      *(float4*)&b[4] = *(const float4*)&Bs[cur][kk][tx * 4 + 64];
#pragma unroll
      for (int i = 0; i < 8; ++i)
#pragma unroll
        for (int j = 0; j < 8; ++j)
          acc[i][j] = fmaf(a[i], b[j], acc[i][j]);
    }
  }
#pragma unroll
  for (int i = 0; i < 8; ++i) {
    int m = m0 + ((i < 4) ? (ty * 4 + i) : (64 + ty * 4 + i - 4));
    if (!MDEV || m < Me) {
      int mo = (EPI == 4) ? perm[m] : m;
      int n = n0 + tx * 4;
      float v[8];
#pragma unroll
      for (int j = 0; j < 8; ++j) {
        int nj = (j < 4) ? (n + j) : (n + 64 + j - 4);
        v[j] = acc[i][j] * scale;
        if (EPI >= 1) v[j] += bias[nj];
        if (EPI == 2) v[j] = gelu_exact(v[j]);
        if (EPI == 3 || EPI == 4) v[j] += addsrc[(size_t)mo * ldc + nj];
      }
      float* cp = &Cb[(size_t)mo * ldc + n];
      *(float4*)cp = make_float4(v[0], v[1], v[2], v[3]);
      *(float4*)(cp + 64) = make_float4(v[4], v[5], v[6], v[7]);
    }
  }
}

// ---------------- PV split-K(16) reduce -> f32 ctx ----------------
__global__ __launch_bounds__(256) void pv_reduce(
    const float* __restrict__ part, float* __restrict__ ctx) {
  int i = blockIdx.x * 256 + threadIdx.x;
  int n = i & 127, m = (i >> 7) & 1023, h = i >> 17;
  float s = 0.f;
#pragma unroll
  for (int ks = 0; ks < 16; ++ks)
    s += part[(size_t)(ks * 6 + h) * 131072 + m * 128 + n];
  ctx[(size_t)m * 768 + h * 128 + n] = s;
}

// ---------------- Softmax (native exp) ----------------
template <int EPT, bool MASK>
__global__ __launch_bounds__(256) void softmax_kernel(
    float* __restrict__ s, const float* __restrict__ maskf) {
  __shared__ float red[256];
  int row = blockIdx.x, tid = threadIdx.x;
  float* sr = s + (size_t)row * (EPT * 256);
  const float* mb = MASK ? (maskf + (size_t)(row / 512) * 512) : nullptr;
  float v[EPT];
  float m = -3.0e38f;
#pragma unroll
  for (int t = 0; t < EPT; ++t) {
    int j = tid + (t << 8);
    float xv = sr[j];
    if (MASK) xv += (mb[j] != 0.0f) ? 0.0f : -1e9f;
    v[t] = xv;
    m = fmaxf(m, xv);
  }
  red[tid] = m;
  __syncthreads();
  for (int off = 128; off; off >>= 1) {
    if (tid < off) red[tid] = fmaxf(red[tid], red[tid + off]);
    __syncthreads();
  }
  m = red[0];
  __syncthreads();
  float ssum = 0.f;
#pragma unroll
  for (int t = 0; t < EPT; ++t) {
    v[t] = __expf(v[t] - m);
    ssum += v[t];
  }
  red[tid] = ssum;
  __syncthreads();
  BLOCK_REDUCE_ADD(red, tid);
  float tot = red[0];
#pragma unroll
  for (int t = 0; t < EPT; ++t) sr[tid + (t << 8)] = v[t] / tot;
}

// ---------------- MoE permutation build ----------------
__global__ __launch_bounds__(256) void build_perm(
    const int* __restrict__ tt, int* __restrict__ perm0,
    int* __restrict__ perm1, int* __restrict__ cnt) {
  int r = blockIdx.x * 256 + threadIdx.x;
  int t = tt[r];
  if (t == 0) { int p = atomicAdd(&cnt[0], 1); perm0[p] = r; }
  else        { int p = atomicAdd(&cnt[1], 1); perm1[p] = r; }
}

// ---------------- Token gather ----------------
__global__ __launch_bounds__(256) void gather_kernel(
    const float* __restrict__ xb, const int* __restrict__ bidx,
    float* __restrict__ tokens, float* __restrict__ maskf) {
  size_t idx = (size_t)blockIdx.x * 256 + threadIdx.x;
  int c = (int)(idx % Cc_);
  int i = (int)((idx / Cc_) % 512);
  int b = (int)(idx / ((size_t)Cc_ * 512));
  int id = bidx[b * NP_ + i];
  bool m = id >= 0;
  int idc = m ? id : 0;
  tokens[idx] = m ? xb[((size_t)b * NB_ + idc) * Cc_ + c] : 0.0f;
  if (c == 0) maskf[b * 512 + i] = m ? 1.0f : 0.0f;
}

// ---------------- ksum -> kernel ----------------
__global__ __launch_bounds__(256) void kernel_kernel(
    const float* __restrict__ agg, const float* __restrict__ maskf,
    float* __restrict__ kern, float* __restrict__ hasf) {
  __shared__ float red[256];
  __shared__ float ks[Cc_];
  __shared__ float s_cnt;
  int b = blockIdx.x, tid = threadIdx.x;
  const float* mb = maskf + b * 512;
  red[tid] = mb[tid] + mb[tid + 256];
  __syncthreads();
  BLOCK_REDUCE_ADD(red, tid);
  if (tid == 0) s_cnt = red[0];
  __syncthreads();
  float cnt = s_cnt;
  float dc = fmaxf(cnt, 1.0f);
  const float* ab = agg + (size_t)b * 512 * Cc_;
#pragma unroll
  for (int t = 0; t < 3; ++t) {
    int cc = tid + t * 256;
    float s = 0.f;
    for (int i = 0; i < 512; ++i) s = fmaf(ab[(size_t)i * Cc_ + cc], mb[i], s);
    ks[cc] = s / dc;
  }
  __syncthreads();
  float s2 = 0.f;
#pragma unroll
  for (int t = 0; t < 3; ++t) {
    float q = ks[tid + t * 256];
    s2 = fmaf(q, q, s2);
  }
  red[tid] = s2;
  __syncthreads();
  BLOCK_REDUCE_ADD(red, tid);
  float den = fmaxf(sqrtf(red[0]), 1e-12f);
  bool has = cnt > 0.5f;
#pragma unroll
  for (int t = 0; t < 3; ++t) {
    int cc = tid + t * 256;
    kern[(size_t)b * Cc_ + cc] = has ? (ks[cc] / den) : 0.0f;
  }
  if (tid == 0) hasf[b] = has ? 1.0f : 0.0f;
}

// ---------------- pos ----------------
__global__ __launch_bounds__(256) void pos_kernel(
    const float* __restrict__ xnorm, const float* __restrict__ kern,
    const float* __restrict__ hasf, float* __restrict__ pos) {
  __shared__ float red[256];
  int row = blockIdx.x, tid = threadIdx.x;
  int b = row >> 10;
  const float* xr = xnorm + (size_t)row * Cc_;
  const float* kr = kern + (size_t)b * Cc_;
  float s = xr[tid] * kr[tid];
  s = fmaf(xr[tid + 256], kr[tid + 256], s);
  s = fmaf(xr[tid + 512], kr[tid + 512], s);
  red[tid] = s;
  __syncthreads();
  BLOCK_REDUCE_ADD(red, tid);
  if (tid == 0) pos[row] = (hasf[b] > 0.5f) ? (red[0] + 1.0f) * 0.5f : 0.0f;
}

// ---------------- per-batch top-128 ----------------
__global__ __launch_bounds__(256) void topk_kernel(
    const float* __restrict__ pos, float* __restrict__ sel,
    float* __restrict__ topi) {
  __shared__ float vals[NS_];
  __shared__ float rv[256];
  __shared__ int ri[256];
  __shared__ int s_vk;
  int b = blockIdx.x, tid = threadIdx.x;
  const float* pr = pos + (size_t)b * NS_;
  int c65 = 0;
#pragma unroll
  for (int t = 0; t < 4; ++t) {
    float v = pr[tid + (t << 8)];
    vals[tid + (t << 8)] = v;
    if (v > 0.65f) ++c65;
  }
  ri[tid] = c65;
  __syncthreads();
  for (int off = 128; off; off >>= 1) {
    if (tid < off) ri[tid] += ri[tid + off];
    __syncthreads();
  }
  if (tid == 0) {
    int vk = ri[0] > 118 ? ri[0] : 118;
    s_vk = vk > 128 ? 128 : vk;
  }
  __syncthreads();
  int vk = s_vk;
  for (int r = 0; r < 128; ++r) {
    float bv = -3.0e38f;
    int bi = 0x7fffffff;
#pragma unroll
    for (int t = 0; t < 4; ++t) {
      int i = tid + (t << 8);
      float v = vals[i];
      if (v > bv) { bv = v; bi = i; }
    }
    rv[tid] = bv; ri[tid] = bi;
    __syncthreads();
    for (int off = 128; off; off >>= 1) {
      if (tid < off) {
        float ov = rv[tid + off]; int oi = ri[tid + off];
        if (ov > rv[tid] || (ov == rv[tid] && oi < ri[tid])) {
          rv[tid] = ov; ri[tid] = oi;
        }
      }
      __syncthreads();
    }
    if (tid == 0) {
      int wi = ri[0]; float wv = rv[0];
      topi[(size_t)b * 128 + r] = (float)wi;
      if (r < vk && wv > 0.0f) sel[((size_t)b * 128 + r) * NS_ + wi] = 1.0f;
      vals[wi] = -3.0e38f;
    }
    __syncthreads();
  }
}

extern "C" void kernel_launch(void* const* d_in, const int* in_sizes, int n_in,
                              void* d_out, int out_size, void* d_ws, size_t ws_size,
                              hipStream_t stream) {
  (void)in_sizes; (void)n_in; (void)out_size; (void)ws_size;
  const float* x_b = (const float*)d_in[0];
  const float* x_s = (const float*)d_in[1];
  const int* token_types = (const int*)d_in[2];
  const int* base_idxs = (const int*)d_in[3];
  const float* ln1_w = (const float*)d_in[4];
  const float* ln1_b = (const float*)d_in[5];
  const float* ln2_w = (const float*)d_in[6];
  const float* ln2_b = (const float*)d_in[7];
  const float* ln3_w = (const float*)d_in[8];
  const float* ln3_b = (const float*)d_in[9];
  const float* Wq = (const float*)d_in[10];
  const float* Wkv = (const float*)d_in[11];
  const float* es_w1 = (const float*)d_in[12];
  const float* es_b1 = (const float*)d_in[13];
  const float* es_w2 = (const float*)d_in[14];
  const float* es_b2 = (const float*)d_in[15];
  const float* el_w1 = (const float*)d_in[16];
  const float* el_b1 = (const float*)d_in[17];
  const float* el_w2 = (const float*)d_in[18];
  const float* el_b2 = (const float*)d_in[19];
  const float* mlp_w1 = (const float*)d_in[20];
  const float* mlp_b1 = (const float*)d_in[21];
  const float* mlp_w2 = (const float*)d_in[22];
  const float* mlp_b2 = (const float*)d_in[23];

  float* out = (float*)d_out;
  float* sel_out  = out;
  float* topi_out = out + 1048576;
  float* pos_out  = out + 1049600;
  float* x_out    = out + 1057792;
  float* kern_out = out + 7349248;

  // ---- workspace layout (floats), peak ~252 MB ----
  // Attention window [31457280, 62914560) = 31.5M fl:
  //   scores 12.6M + part 12.6M (full 16 splits, race-free) + ctxf 6.3M.
  float* w = (float*)d_ws;
  float* kv_f = w;                        // [0, 25165824)
  float* q_f  = w + 25165824;             // [25165824, 31457280)
  float* scores = w + 31457280;           // [31457280, 44040192)
  float* part   = w + 44040192;           // [44040192, 56623104)  16-split PV
  float* ctxf   = w + 56623104;           // [56623104, 62914560)
  // Phase 1 plane staging (dead after phase 1):
  unsigned short* xbnp = (unsigned short*)(w + 31457280);  // [31457280, 50331648)
  unsigned short* xsnp = (unsigned short*)(w + 50331648);  // [50331648, 59768832)
  unsigned short* wqp  = (unsigned short*)(w + 59768832);  // [59768832, 60653568)
  unsigned short* wkvp = (unsigned short*)(w + 60653568);  // [60653568, 62423040)
  // Phase 3/4 (FFN) overlays:
  unsigned short* ctxp = (unsigned short*)(w + 6291456);   // 18874368 us
  unsigned short* wb   = (unsigned short*)(w + 15728640);  // 42467328 us
  unsigned short* hp   = (unsigned short*)(w + 36962304);  // 37748736 us
  float* P0 = w;                                           // 6291456 fl
  const long ZS = 55836672;
  float* P1 = w + ZS;                                      // [55836672, 62128128)
  // Phase 5 overlays:
  float* xn     = w + 6291456;
  float* tokens = w + 12582912;
  float* aw     = w + 15728640;
  float* agg    = w + 17825792;
  // small block
  float* small  = w + 62914560;
  float* maskf  = small;
  float* hasf   = small + 4096;
  int* cnt      = (int*)(small + 4104);
  int* perm0    = (int*)(small + 4106);
  int* perm1    = (int*)(small + 12298);

  // weight plane sub-layout (ushort offsets in wb)
  unsigned short* esw1h[2] = {wb + 0,        wb + 3538944};
  unsigned short* elw1h[2] = {wb + 7077888,  wb + 10616832};
  unsigned short* mlw1h[2] = {wb + 14155776, wb + 17694720};
  unsigned short* esw2h[2] = {wb + 21233664, wb + 24772608};
  unsigned short* elw2h[2] = {wb + 28311552, wb + 31850496};
  unsigned short* mlw2h[2] = {wb + 35389440, wb + 38928384};

  const long NSC = (long)NS_ * Cc_;
  const long NB2C = (long)NB_ * 2 * Cc_;
  const long SNB = (long)NS_ * NB_;
  const float qk_scale = 0.08838834764831845f;
  const float sc_scale = 0.036084391824351615f;

  hipMemsetAsync(sel_out, 0, (size_t)1048576 * sizeof(float), stream);
  hipMemsetAsync(cnt, 0, 2 * sizeof(int), stream);

  // ---- phase 1: LN->planes, weight planes, q/kv on MFMA ----
  ln_split<<<B_ * NS_, 256, 0, stream>>>(x_s, xsnp, ln1_w, ln1_b);
  ln_split<<<B_ * NB_, 256, 0, stream>>>(x_b, xbnp, ln2_w, ln2_b);
  build_perm<<<32, 256, 0, stream>>>(token_types, perm0, perm1, cnt);
  wconv<<<dim3(3, 768), 256, 0, stream>>>(Wq, wqp, 768, 768, 768, 0);
  wconv<<<dim3(3, 1536), 256, 0, stream>>>(Wkv, wkvp, 768, 1536, 1536, 0);
  mgemm<6, false, false><<<dim3(6, 64, 1), 256, 0, stream>>>(
      xsnp, wqp, q_f, nullptr, nullptr, nullptr, nullptr,
      8192, 768, 768, 768, 0, 1, 0, 0, 0, 1.0f);
  mgemm<6, false, false><<<dim3(12, 128, 1), 256, 0, stream>>>(
      xbnp, wkvp, kv_f, nullptr, nullptr, nullptr, nullptr,
      16384, 1536, 768, 1536, 0, 1, 0, 0, 0, 1.0f);

  // ---- phase 2: attention (f32 QK^T + softmax + PV split-16) ----
  for (int b = 0; b < B_; ++b) {
    const float* qb = q_f + (size_t)b * NSC;
    const float* kb = kv_f + (size_t)b * NB2C;
    const float* vb = kb + Cc_;
    gemm128<0, 1, false, false><<<dim3(16, 8, 6), 256, 0, stream>>>(
        qb, kb, scores, nullptr, nullptr, nullptr, nullptr,
        1024, 2048, 128, 768, 1536, 2048,
        1, 1, 128, 0, 0, 128, 0, 0, SNB, 0, 0, qk_scale);
    softmax_kernel<8, false><<<6 * 1024, 256, 0, stream>>>(scores, nullptr);
    // z = h*16 + ks (d1=6, d2=16): C off = h*131072 + ks*786432
    //   = (ks*6+h)*131072  -- matches pv_reduce, bijective over 12.58M fl
    gemm128<0, 0, false, false><<<dim3(1, 8, 96), 256, 0, stream>>>(
        scores, vb, part, nullptr, nullptr, nullptr, nullptr,
        1024, 128, 128, 2048, 1536, 128,
        6, 16, 0, SNB, 128, 0, 128, 128 * 1536, 0, 131072, 786432, 1.0f);
    pv_reduce<<<3072, 256, 0, stream>>>(part, ctxf + (size_t)b * NSC);
  }

  // ---- phase 3: split ctx, convert FFN weights ----
  split_kernel<<<24576, 256, 0, stream>>>(ctxf, ctxp);
  for (int h = 0; h < 2; ++h) {
    wconv<<<dim3(3, 1536), 256, 0, stream>>>(es_w1, esw1h[h], 768, 1536, 3072, h * 1536);
    wconv<<<dim3(3, 1536), 256, 0, stream>>>(el_w1, elw1h[h], 768, 1536, 3072, h * 1536);
    wconv<<<dim3(3, 1536), 256, 0, stream>>>(mlp_w1, mlw1h[h], 768, 1536, 3072, h * 1536);
    wconv<<<dim3(6, 768), 256, 0, stream>>>(es_w2 + (size_t)h * 1536 * 768, esw2h[h], 1536, 768, 768, 0);
    wconv<<<dim3(6, 768), 256, 0, stream>>>(el_w2 + (size_t)h * 1536 * 768, elw2h[h], 1536, 768, 768, 0);
    wconv<<<dim3(6, 768), 256, 0, stream>>>(mlp_w2 + (size_t)h * 1536 * 768, mlw2h[h], 1536, 768, 768, 0);
  }

  // ---- phase 4: MoE experts + MLP on MFMA (hidden in 2 halves) ----
  for (int h = 0; h < 2; ++h) {
    mgemm<5, true, true><<<dim3(12, 64, 1), 256, 0, stream>>>(
        ctxp, esw1h[h], nullptr, hp, es_b1 + h * 1536, perm0, cnt,
        8192, 1536, 768, 0, 1536, 1, 0, 0, 0, 1.0f);
    if (h == 0)
      mgemm<6, false, true><<<dim3(6, 64, 2), 256, 0, stream>>>(
          hp, esw2h[h], P0, nullptr, nullptr, nullptr, cnt,
          8192, 768, 1536, 768, 0, 2, 0, 0, ZS, 1.0f);
    else
      mgemm<7, false, true><<<dim3(6, 64, 2), 256, 0, stream>>>(
          hp, esw2h[h], P0, nullptr, nullptr, nullptr, cnt,
          8192, 768, 1536, 768, 0, 2, 0, 0, ZS, 1.0f);
  }
  combineP<true><<<dim3(8192, 3), 256, 0, stream>>>(
      P0, P1, es_b2, x_s, perm0, cnt, x_out);
  for (int h = 0; h < 2; ++h) {
    mgemm<5, true, true><<<dim3(12, 64, 1), 256, 0, stream>>>(
        ctxp, elw1h[h], nullptr, hp, el_b1 + h * 1536, perm1, cnt + 1,
        8192, 1536, 768, 0, 1536, 1, 0, 0, 0, 1.0f);
    if (h == 0)
      mgemm<6, false, true><<<dim3(6, 64, 2), 256, 0, stream>>>(
          hp, elw2h[h], P0, nullptr, nullptr, nullptr, cnt + 1,
          8192, 768, 1536, 768, 0, 2, 0, 0, ZS, 1.0f);
    else
      mgemm<7, false, true><<<dim3(6, 64, 2), 256, 0, stream>>>(
          hp, elw2h[h], P0, nullptr, nullptr, nullptr, cnt + 1,
          8192, 768, 1536, 768, 0, 2, 0, 0, ZS, 1.0f);
  }
  combineP<true><<<dim3(8192, 3), 256, 0, stream>>>(
      P0, P1, el_b2, x_s, perm1, cnt + 1, x_out);
  ln_split<<<B_ * NS_, 256, 0, stream>>>(x_out, ctxp, ln3_w, ln3_b);
  for (int h = 0; h < 2; ++h) {
    mgemm<5, false, false><<<dim3(12, 64, 1), 256, 0, stream>>>(
        ctxp, mlw1h[h], nullptr, hp, mlp_b1 + h * 1536, nullptr, nullptr,
        8192, 1536, 768, 0, 1536, 1, 0, 0, 0, 1.0f);
    if (h == 0)
      mgemm<6, false, false><<<dim3(6, 64, 2), 256, 0, stream>>>(
          hp, mlw2h[h], P0, nullptr, nullptr, nullptr, nullptr,
          8192, 768, 1536, 768, 0, 2, 0, 0, ZS, 1.0f);
    else
      mgemm<7, false, false><<<dim3(6, 64, 2), 256, 0, stream>>>(
          hp, mlw2h[h], P0, nullptr, nullptr, nullptr, nullptr,
          8192, 768, 1536, 768, 0, 2, 0, 0, ZS, 1.0f);
  }
  combineP<false><<<dim3(8192, 3), 256, 0, stream>>>(
      P0, P1, mlp_b2, x_out, nullptr, nullptr, x_out);

  // ---- phase 5: scoring tail (f32) ----
  rownorm_kernel<<<B_ * NS_, 256, 0, stream>>>(x_out, xn);
  gather_kernel<<<12288, 256, 0, stream>>>(x_b, base_idxs, tokens, maskf);
  gemm128<0, 1, false, false><<<dim3(4, 4, 8), 256, 0, stream>>>(
      tokens, tokens, aw, nullptr, nullptr, nullptr, nullptr,
      512, 512, 768, 768, 768, 512,
      1, 1, 393216, 0, 0, 393216, 0, 0, 262144, 0, 0, sc_scale);
  softmax_kernel<2, true><<<8 * 512, 256, 0, stream>>>(aw, maskf);
  gemm128<0, 0, false, false><<<dim3(6, 4, 8), 256, 0, stream>>>(
      aw, tokens, agg, nullptr, nullptr, nullptr, nullptr,
      512, 768, 512, 512, 768, 768,
      1, 1, 262144, 0, 0, 393216, 0, 0, 393216, 0, 0, 1.0f);
  kernel_kernel<<<8, 256, 0, stream>>>(agg, maskf, kern_out, hasf);
  pos_kernel<<<B_ * NS_, 256, 0, stream>>>(xn, kern_out, hasf, pos_out);
  topk_kernel<<<8, 256, 0, stream>>>(pos_out, sel_out, topi_out);
}

// Round 13
// 3335.184 us; speedup vs baseline: 1.1397x; 1.1397x over previous
//
#include <hip/hip_runtime.h>
#include <hip/hip_bf16.h>
#include <math.h>

// Problem constants
#define B_   8
#define NB_  2048
#define NS_  1024
#define Cc_  768
#define HID_ 3072
#define NP_  1024
#define NH_  6
#define HD_  128

__device__ __forceinline__ float gelu_exact(float v) {
  return 0.5f * v * (1.0f + erff(v * 0.7071067811865476f));
}

// split f32 into 3 bf16 planes (truncation; dropped residual ~2^-24 rel)
__device__ __forceinline__ void split3(float v, unsigned short& h,
                                       unsigned short& m, unsigned short& l) {
  unsigned hb = __float_as_uint(v) & 0xffff0000u;
  float r1 = v - __uint_as_float(hb);
  unsigned mb = __float_as_uint(r1) & 0xffff0000u;
  float r2 = r1 - __uint_as_float(mb);
  unsigned lb = __float_as_uint(r2) & 0xffff0000u;
  h = (unsigned short)(hb >> 16);
  m = (unsigned short)(mb >> 16);
  l = (unsigned short)(lb >> 16);
}

typedef short bf16x8 __attribute__((ext_vector_type(8)));
typedef float f32x4 __attribute__((ext_vector_type(4)));

#define BLOCK_REDUCE_ADD(red, tid)                                              \
  for (int off_ = 128; off_; off_ >>= 1) {                                      \
    if ((tid) < off_) red[(tid)] += red[(tid) + off_];                          \
    __syncthreads();                                                            \
  }

// ---------------- LayerNorm -> 3 bf16 planes [row][3*768] ----------------
__global__ __launch_bounds__(256) void ln_split(
    const float* __restrict__ x, unsigned short* __restrict__ y,
    const float* __restrict__ w, const float* __restrict__ b) {
  __shared__ float red[256];
  int row = blockIdx.x, tid = threadIdx.x;
  const float* xr = x + (size_t)row * Cc_;
  float v0 = xr[tid], v1 = xr[tid + 256], v2 = xr[tid + 512];
  red[tid] = v0 + v1 + v2;
  __syncthreads();
  BLOCK_REDUCE_ADD(red, tid);
  float mu = red[0] / (float)Cc_;
  __syncthreads();
  float d0 = v0 - mu, d1 = v1 - mu, d2 = v2 - mu;
  red[tid] = d0 * d0 + d1 * d1 + d2 * d2;
  __syncthreads();
  BLOCK_REDUCE_ADD(red, tid);
  float var = red[0] / (float)Cc_;
  float rs = 1.0f / sqrtf(var + 1e-5f);
  unsigned short* yr = y + (size_t)row * 2304;
  float vals[3] = {d0 * rs * w[tid] + b[tid],
                   d1 * rs * w[tid + 256] + b[tid + 256],
                   d2 * rs * w[tid + 512] + b[tid + 512]};
#pragma unroll
  for (int t = 0; t < 3; ++t) {
    int c = tid + (t << 8);
    unsigned short h16, m16, l16;
    split3(vals[t], h16, m16, l16);
    yr[c] = h16; yr[768 + c] = m16; yr[1536 + c] = l16;
  }
}

// ---------------- f32 [8192][768] -> 3 bf16 planes ----------------
__global__ __launch_bounds__(256) void split_kernel(
    const float* __restrict__ x, unsigned short* __restrict__ y) {
  size_t idx = (size_t)blockIdx.x * 256 + threadIdx.x;  // < 8192*768
  int c = (int)(idx % Cc_);
  int row = (int)(idx / Cc_);
  unsigned short h16, m16, l16;
  split3(x[idx], h16, m16, l16);
  unsigned short* yr = y + (size_t)row * 2304;
  yr[c] = h16; yr[768 + c] = m16; yr[1536 + c] = l16;
}

// ---------------- Row L2-normalize ----------------
__global__ __launch_bounds__(256) void rownorm_kernel(
    const float* __restrict__ x, float* __restrict__ y) {
  __shared__ float red[256];
  int row = blockIdx.x, tid = threadIdx.x;
  const float* xr = x + (size_t)row * Cc_;
  float* yr = y + (size_t)row * Cc_;
  float v0 = xr[tid], v1 = xr[tid + 256], v2 = xr[tid + 512];
  red[tid] = v0 * v0 + v1 * v1 + v2 * v2;
  __syncthreads();
  BLOCK_REDUCE_ADD(red, tid);
  float den = fmaxf(sqrtf(red[0]), 1e-12f);
  yr[tid]       = v0 / den;
  yr[tid + 256] = v1 / den;
  yr[tid + 512] = v2 / den;
}

// --------- weight convert: W rows k in [0,K), col ncol0+n -> out[N][3K] ----
__global__ __launch_bounds__(256) void wconv(
    const float* __restrict__ W, unsigned short* __restrict__ out,
    int K, int N, int ldw, int ncol0) {
  int k = blockIdx.x * 256 + threadIdx.x;
  int n = blockIdx.y;
  float v = W[(size_t)k * ldw + ncol0 + n];
  unsigned short h16, m16, l16;
  split3(v, h16, m16, l16);
  size_t base = (size_t)n * 3 * K;
  out[base + k] = h16;
  out[base + K + k] = m16;
  out[base + 2 * K + k] = l16;
}

// ---------------- MFMA GEMM over 3-split bf16 planes ----------------
// A planes [M][3K] bf16; B planes [N][3K] bf16 (op-B transposed).
// K'' = 6K via segments pa={0,0,1,0,1,2}, pb={0,1,0,2,1,0}.
// 128x128 tile, 4 waves, mfma_f32_16x16x32_bf16, dbuf LDS, one
// lgkmcnt(0)+s_barrier per 64-wide k-tile.
// SWZ: XCD-aware block swizzle (needs gridDim.x*gridDim.y % 8 == 0).
//   MUST be false for MDEV launches: swizzle gives each XCD a contiguous
//   by-range, so with early-exit tiles half the XCDs would idle (R12 lesson).
// z: batch via azs/bzs/zstride strides AND/OR reduction split (z%nsplit).
// EPI: 5 = gelu(v+bias) -> 3 bf16 planes Cs[m][3*Kout]
//      6 = f32:  Cf[z*zstride + m*ldc + n] = v
//      7 = f32:  Cf[z*zstride + m*ldc + n] += v
template <int EPI, bool AGATHER, bool MDEV, bool SWZ>
__global__ __launch_bounds__(256) void mgemm(
    const unsigned short* __restrict__ Ap, const unsigned short* __restrict__ Bp,
    float* __restrict__ Cf, unsigned short* __restrict__ Cs,
    const float* __restrict__ bias,
    const int* __restrict__ perm, const int* __restrict__ mdev,
    int M, int N, int K, int ldc, int Kout, int nsplit,
    long azs, long bzs, long zstride, float scale) {
  __shared__ unsigned short As[2][8192];
  __shared__ unsigned short Bs[2][8192];
  int z = blockIdx.z;
  int bx, by;
  if (SWZ) {
    int gx = gridDim.x;
    int id = blockIdx.y * gx + blockIdx.x;
    int per = (gx * gridDim.y) >> 3;
    int nid = (id & 7) * per + (id >> 3);
    bx = nid % gx; by = nid / gx;
  } else {
    bx = blockIdx.x; by = blockIdx.y;
  }
  int Me = MDEV ? mdev[0] : M;
  int m0 = by * 128, n0 = bx * 128;
  if (MDEV && m0 >= Me) return;
  const unsigned short* ApB = Ap + (size_t)z * azs;
  const unsigned short* BpB = Bp + (size_t)z * bzs;
  int tid = threadIdx.x;
  int lane = tid & 63, w = tid >> 6;
  int wr = w >> 1, wc = w & 1;
  int K3 = 3 * K;
  int tps = K >> 6;        // 64-wide tiles per plane-segment
  int KT = 6 * tps;
  int span = KT / nsplit;
  int zr = z % nsplit;
  int tt0 = zr * span, tt1 = tt0 + span;

  const unsigned short* agp[4];
  const unsigned short* bgp[4];
  int wswz[4];
#pragma unroll
  for (int p = 0; p < 4; ++p) {
    int r = (tid >> 3) + 32 * p;
    int ma = m0 + r;
    if (MDEV) ma = min(ma, Me - 1);
    if (AGATHER) ma = perm[ma];
    agp[p] = ApB + (size_t)ma * K3 + (tid & 7) * 8;
    bgp[p] = BpB + (size_t)(n0 + r) * K3 + (tid & 7) * 8;
    wswz[p] = r * 64 + (((tid & 7) ^ (r & 7)) << 3);
  }

  f32x4 acc[4][4];
  f32x4 zero4 = {0.f, 0.f, 0.f, 0.f};
#pragma unroll
  for (int i = 0; i < 4; ++i)
#pragma unroll
    for (int j = 0; j < 4; ++j) acc[i][j] = zero4;

  int kg = lane >> 4;
  int frm[4], frn[4];
#pragma unroll
  for (int f = 0; f < 4; ++f) {
    frm[f] = wr * 64 + f * 16 + (lane & 15);
    frn[f] = wc * 64 + f * 16 + (lane & 15);
  }

  bf16x8 ra[4], rb[4];
  {
    int seg = tt0 / tps, kt = tt0 - seg * tps;
    int pa = (0x210100u >> (4 * seg)) & 0xF;
    int pb = (0x012010u >> (4 * seg)) & 0xF;
    size_t ao = (size_t)(pa * K + kt * 64);
    size_t bo = (size_t)(pb * K + kt * 64);
#pragma unroll
    for (int p = 0; p < 4; ++p) {
      ra[p] = *(const bf16x8*)(agp[p] + ao);
      rb[p] = *(const bf16x8*)(bgp[p] + bo);
    }
  }

  for (int tt = tt0; tt < tt1; ++tt) {
    int cur = tt & 1;
#pragma unroll
    for (int p = 0; p < 4; ++p) {
      *(bf16x8*)&As[cur][wswz[p]] = ra[p];
      *(bf16x8*)&Bs[cur][wswz[p]] = rb[p];
    }
    if (tt + 1 < tt1) {
      int seg = (tt + 1) / tps, kt = (tt + 1) - seg * tps;
      int pa = (0x210100u >> (4 * seg)) & 0xF;
      int pb = (0x012010u >> (4 * seg)) & 0xF;
      size_t ao = (size_t)(pa * K + kt * 64);
      size_t bo = (size_t)(pb * K + kt * 64);
#pragma unroll
      for (int p = 0; p < 4; ++p) {
        ra[p] = *(const bf16x8*)(agp[p] + ao);
        rb[p] = *(const bf16x8*)(bgp[p] + bo);
      }
    }
    asm volatile("s_waitcnt lgkmcnt(0)" ::: "memory");
    __builtin_amdgcn_s_barrier();
#pragma unroll
    for (int ks = 0; ks < 2; ++ks) {
      int ch = ks * 4 + kg;
      bf16x8 af[4], bf[4];
#pragma unroll
      for (int f = 0; f < 4; ++f) {
        int r = frm[f];
        af[f] = *(const bf16x8*)&As[cur][r * 64 + ((ch ^ (r & 7)) << 3)];
      }
#pragma unroll
      for (int f = 0; f < 4; ++f) {
        int r = frn[f];
        bf[f] = *(const bf16x8*)&Bs[cur][r * 64 + ((ch ^ (r & 7)) << 3)];
      }
#pragma unroll
      for (int i = 0; i < 4; ++i)
#pragma unroll
        for (int j = 0; j < 4; ++j)
          acc[i][j] = __builtin_amdgcn_mfma_f32_16x16x32_bf16(
              af[i], bf[j], acc[i][j], 0, 0, 0);
    }
  }

  // epilogue: C/D layout col=lane&15, row=(lane>>4)*4+reg (m89-verified)
#pragma unroll
  for (int i = 0; i < 4; ++i) {
#pragma unroll
    for (int r = 0; r < 4; ++r) {
      int m = m0 + wr * 64 + i * 16 + kg * 4 + r;
      if (MDEV && m >= Me) continue;
#pragma unroll
      for (int j = 0; j < 4; ++j) {
        int n = n0 + wc * 64 + j * 16 + (lane & 15);
        float v = acc[i][j][r] * scale;
        if (EPI == 6) {
          Cf[(size_t)z * zstride + (size_t)m * ldc + n] = v;
        } else if (EPI == 7) {
          Cf[(size_t)z * zstride + (size_t)m * ldc + n] += v;
        } else if (EPI == 5) {
          float t = gelu_exact(v + bias[n]);
          unsigned short h16, m16, l16;
          split3(t, h16, m16, l16);
          size_t base = (size_t)m * 3 * Kout;
          Cs[base + n] = h16;
          Cs[base + Kout + n] = m16;
          Cs[base + 2 * Kout + n] = l16;
        }
      }
    }
  }
}

// ---------------- combine partials: out = bias + addsrc + P0 + P1 ----------
template <bool SCATTER>
__global__ __launch_bounds__(256) void combineP(
    const float* __restrict__ P0, const float* __restrict__ P1,
    const float* __restrict__ bias, const float* __restrict__ addsrc,
    const int* __restrict__ perm, const int* __restrict__ cnt,
    float* __restrict__ out) {
  int m = blockIdx.x;
  int c = threadIdx.x + (blockIdx.y << 8);
  if (SCATTER && m >= cnt[0]) return;
  int mo = SCATTER ? perm[m] : m;
  size_t pm = (size_t)m * 768 + c;
  out[(size_t)mo * 768 + c] =
      bias[c] + addsrc[(size_t)mo * 768 + c] + P0[pm] + P1[pm];
}

// ---------------- f32 GEMM (R5: 128x128, 8x8, reg-prefetch dbuf) ----------
template <int EPI, int TRB, bool AGATHER, bool MDEV>
__global__ __launch_bounds__(256) void gemm128(
    const float* __restrict__ A, const float* __restrict__ Bm,
    float* __restrict__ Cm, const float* __restrict__ bias,
    const float* __restrict__ addsrc, const int* __restrict__ perm,
    const int* __restrict__ mdev,
    int M, int N, int K, int lda, int ldb, int ldc,
    int d1, int d2,
    long a_s1, long a_s2, long a_s3,
    long b_s1, long b_s2, long b_s3,
    long c_s1, long c_s2, long c_s3,
    float scale) {
  __shared__ float As[2][16][132];
  __shared__ float Bs[2][16][132];
  int z = blockIdx.z;
  int z1 = z / (d1 * d2);
  int rem = z - z1 * d1 * d2;
  int z2 = rem / d2, z3 = rem - z2 * d2;
  const float* Ab = A + (size_t)z1 * a_s1 + (size_t)z2 * a_s2 + (size_t)z3 * a_s3;
  const float* Bb = Bm + (size_t)z1 * b_s1 + (size_t)z2 * b_s2 + (size_t)z3 * b_s3;
  float* Cb = Cm + (size_t)z1 * c_s1 + (size_t)z2 * c_s2 + (size_t)z3 * c_s3;
  int Me = MDEV ? mdev[0] : M;
  int m0 = blockIdx.y * 128, n0 = blockIdx.x * 128;
  if (MDEV && m0 >= Me) return;
  int tid = threadIdx.x;
  int tx = tid & 15, ty = tid >> 4;
  int arow = tid >> 2, akq = tid & 3;
  int ma0 = m0 + arow, ma1 = m0 + arow + 64;
  if (MDEV) { ma0 = min(ma0, Me - 1); ma1 = min(ma1, Me - 1); }
  if (AGATHER) { ma0 = perm[ma0]; ma1 = perm[ma1]; }
  const float* Ap0 = Ab + (size_t)ma0 * lda + akq * 4;
  const float* Ap1 = Ab + (size_t)ma1 * lda + akq * 4;
  const float* Bp0;
  const float* Bp1;
  int bw_r0 = 0, bw_c0 = 0, bw_r1 = 0;
  if (TRB == 0) {
    bw_r0 = tid >> 5; bw_c0 = (tid & 31) * 4; bw_r1 = bw_r0 + 8;
    Bp0 = Bb + (size_t)bw_r0 * ldb + n0 + bw_c0;
    Bp1 = Bb + (size_t)bw_r1 * ldb + n0 + bw_c0;
  } else {
    Bp0 = Bb + (size_t)(n0 + arow) * ldb + akq * 4;
    Bp1 = Bb + (size_t)(n0 + arow + 64) * ldb + akq * 4;
  }
  float4 pa0 = *(const float4*)Ap0;
  float4 pa1 = *(const float4*)Ap1;
  float4 pb0 = *(const float4*)Bp0;
  float4 pb1 = *(const float4*)Bp1;
  float acc[8][8] = {};
  int nt = K >> 4;
  for (int t = 0; t < nt; ++t) {
    int cur = t & 1;
    As[cur][akq * 4 + 0][arow] = pa0.x; As[cur][akq * 4 + 1][arow] = pa0.y;
    As[cur][akq * 4 + 2][arow] = pa0.z; As[cur][akq * 4 + 3][arow] = pa0.w;
    As[cur][akq * 4 + 0][arow + 64] = pa1.x; As[cur][akq * 4 + 1][arow + 64] = pa1.y;
    As[cur][akq * 4 + 2][arow + 64] = pa1.z; As[cur][akq * 4 + 3][arow + 64] = pa1.w;
    if (TRB == 0) {
      *(float4*)&Bs[cur][bw_r0][bw_c0] = pb0;
      *(float4*)&Bs[cur][bw_r1][bw_c0] = pb1;
    } else {
      Bs[cur][akq * 4 + 0][arow] = pb0.x; Bs[cur][akq * 4 + 1][arow] = pb0.y;
      Bs[cur][akq * 4 + 2][arow] = pb0.z; Bs[cur][akq * 4 + 3][arow] = pb0.w;
      Bs[cur][akq * 4 + 0][arow + 64] = pb1.x; Bs[cur][akq * 4 + 1][arow + 64] = pb1.y;
      Bs[cur][akq * 4 + 2][arow + 64] = pb1.z; Bs[cur][akq * 4 + 3][arow + 64] = pb1.w;
    }
    if (t + 1 < nt) {
      int kn = (t + 1) << 4;
      pa0 = *(const float4*)&Ap0[kn];
      pa1 = *(const float4*)&Ap1[kn];
      if (TRB == 0) {
        pb0 = *(const float4*)&Bp0[(size_t)kn * ldb];
        pb1 = *(const float4*)&Bp1[(size_t)kn * ldb];
      } else {
        pb0 = *(const float4*)&Bp0[kn];
        pb1 = *(const float4*)&Bp1[kn];
      }
    }
    asm volatile("s_waitcnt lgkmcnt(0)" ::: "memory");
    __builtin_amdgcn_s_barrier();
#pragma unroll
    for (int kk = 0; kk < 16; ++kk) {
      float a[8], b[8];
      *(float4*)&a[0] = *(const float4*)&As[cur][kk][ty * 4];
      *(float4*)&a[4] = *(const float4*)&As[cur][kk][ty * 4 + 64];
      *(float4*)&b[0] = *(const float4*)&Bs[cur][kk][tx * 4];
      *(float4*)&b[4] = *(const float4*)&Bs[cur][kk][tx * 4 + 64];
#pragma unroll
      for (int i = 0; i < 8; ++i)
#pragma unroll
        for (int j = 0; j < 8; ++j)
          acc[i][j] = fmaf(a[i], b[j], acc[i][j]);
    }
  }
#pragma unroll
  for (int i = 0; i < 8; ++i) {
    int m = m0 + ((i < 4) ? (ty * 4 + i) : (64 + ty * 4 + i - 4));
    if (!MDEV || m < Me) {
      int mo = (EPI == 4) ? perm[m] : m;
      int n = n0 + tx * 4;
      float v[8];
#pragma unroll
      for (int j = 0; j < 8; ++j) {
        int nj = (j < 4) ? (n + j) : (n + 64 + j - 4);
        v[j] = acc[i][j] * scale;
        if (EPI >= 1) v[j] += bias[nj];
        if (EPI == 2) v[j] = gelu_exact(v[j]);
        if (EPI == 3 || EPI == 4) v[j] += addsrc[(size_t)mo * ldc + nj];
      }
      float* cp = &Cb[(size_t)mo * ldc + n];
      *(float4*)cp = make_float4(v[0], v[1], v[2], v[3]);
      *(float4*)(cp + 64) = make_float4(v[4], v[5], v[6], v[7]);
    }
  }
}

// ---------------- PV split-K(16) reduce -> f32 ctx ----------------
__global__ __launch_bounds__(256) void pv_reduce(
    const float* __restrict__ part, float* __restrict__ ctx) {
  int i = blockIdx.x * 256 + threadIdx.x;
  int n = i & 127, m = (i >> 7) & 1023, h = i >> 17;
  float s = 0.f;
#pragma unroll
  for (int ks = 0; ks < 16; ++ks)
    s += part[(size_t)(ks * 6 + h) * 131072 + m * 128 + n];
  ctx[(size_t)m * 768 + h * 128 + n] = s;
}

// ---------------- Softmax (native exp) ----------------
template <int EPT, bool MASK>
__global__ __launch_bounds__(256) void softmax_kernel(
    float* __restrict__ s, const float* __restrict__ maskf) {
  __shared__ float red[256];
  int row = blockIdx.x, tid = threadIdx.x;
  float* sr = s + (size_t)row * (EPT * 256);
  const float* mb = MASK ? (maskf + (size_t)(row / 512) * 512) : nullptr;
  float v[EPT];
  float m = -3.0e38f;
#pragma unroll
  for (int t = 0; t < EPT; ++t) {
    int j = tid + (t << 8);
    float xv = sr[j];
    if (MASK) xv += (mb[j] != 0.0f) ? 0.0f : -1e9f;
    v[t] = xv;
    m = fmaxf(m, xv);
  }
  red[tid] = m;
  __syncthreads();
  for (int off = 128; off; off >>= 1) {
    if (tid < off) red[tid] = fmaxf(red[tid], red[tid + off]);
    __syncthreads();
  }
  m = red[0];
  __syncthreads();
  float ssum = 0.f;
#pragma unroll
  for (int t = 0; t < EPT; ++t) {
    v[t] = __expf(v[t] - m);
    ssum += v[t];
  }
  red[tid] = ssum;
  __syncthreads();
  BLOCK_REDUCE_ADD(red, tid);
  float tot = red[0];
#pragma unroll
  for (int t = 0; t < EPT; ++t) sr[tid + (t << 8)] = v[t] / tot;
}

// ---------------- MoE permutation build ----------------
__global__ __launch_bounds__(256) void build_perm(
    const int* __restrict__ tt, int* __restrict__ perm0,
    int* __restrict__ perm1, int* __restrict__ cnt) {
  int r = blockIdx.x * 256 + threadIdx.x;
  int t = tt[r];
  if (t == 0) { int p = atomicAdd(&cnt[0], 1); perm0[p] = r; }
  else        { int p = atomicAdd(&cnt[1], 1); perm1[p] = r; }
}

// ---------------- Token gather ----------------
__global__ __launch_bounds__(256) void gather_kernel(
    const float* __restrict__ xb, const int* __restrict__ bidx,
    float* __restrict__ tokens, float* __restrict__ maskf) {
  size_t idx = (size_t)blockIdx.x * 256 + threadIdx.x;
  int c = (int)(idx % Cc_);
  int i = (int)((idx / Cc_) % 512);
  int b = (int)(idx / ((size_t)Cc_ * 512));
  int id = bidx[b * NP_ + i];
  bool m = id >= 0;
  int idc = m ? id : 0;
  tokens[idx] = m ? xb[((size_t)b * NB_ + idc) * Cc_ + c] : 0.0f;
  if (c == 0) maskf[b * 512 + i] = m ? 1.0f : 0.0f;
}

// ---------------- ksum -> kernel ----------------
__global__ __launch_bounds__(256) void kernel_kernel(
    const float* __restrict__ agg, const float* __restrict__ maskf,
    float* __restrict__ kern, float* __restrict__ hasf) {
  __shared__ float red[256];
  __shared__ float ks[Cc_];
  __shared__ float s_cnt;
  int b = blockIdx.x, tid = threadIdx.x;
  const float* mb = maskf + b * 512;
  red[tid] = mb[tid] + mb[tid + 256];
  __syncthreads();
  BLOCK_REDUCE_ADD(red, tid);
  if (tid == 0) s_cnt = red[0];
  __syncthreads();
  float cnt = s_cnt;
  float dc = fmaxf(cnt, 1.0f);
  const float* ab = agg + (size_t)b * 512 * Cc_;
#pragma unroll
  for (int t = 0; t < 3; ++t) {
    int cc = tid + t * 256;
    float s = 0.f;
    for (int i = 0; i < 512; ++i) s = fmaf(ab[(size_t)i * Cc_ + cc], mb[i], s);
    ks[cc] = s / dc;
  }
  __syncthreads();
  float s2 = 0.f;
#pragma unroll
  for (int t = 0; t < 3; ++t) {
    float q = ks[tid + t * 256];
    s2 = fmaf(q, q, s2);
  }
  red[tid] = s2;
  __syncthreads();
  BLOCK_REDUCE_ADD(red, tid);
  float den = fmaxf(sqrtf(red[0]), 1e-12f);
  bool has = cnt > 0.5f;
#pragma unroll
  for (int t = 0; t < 3; ++t) {
    int cc = tid + t * 256;
    kern[(size_t)b * Cc_ + cc] = has ? (ks[cc] / den) : 0.0f;
  }
  if (tid == 0) hasf[b] = has ? 1.0f : 0.0f;
}

// ---------------- pos ----------------
__global__ __launch_bounds__(256) void pos_kernel(
    const float* __restrict__ xnorm, const float* __restrict__ kern,
    const float* __restrict__ hasf, float* __restrict__ pos) {
  __shared__ float red[256];
  int row = blockIdx.x, tid = threadIdx.x;
  int b = row >> 10;
  const float* xr = xnorm + (size_t)row * Cc_;
  const float* kr = kern + (size_t)b * Cc_;
  float s = xr[tid] * kr[tid];
  s = fmaf(xr[tid + 256], kr[tid + 256], s);
  s = fmaf(xr[tid + 512], kr[tid + 512], s);
  red[tid] = s;
  __syncthreads();
  BLOCK_REDUCE_ADD(red, tid);
  if (tid == 0) pos[row] = (hasf[b] > 0.5f) ? (red[0] + 1.0f) * 0.5f : 0.0f;
}

// ---------------- per-batch top-128 ----------------
__global__ __launch_bounds__(256) void topk_kernel(
    const float* __restrict__ pos, float* __restrict__ sel,
    float* __restrict__ topi) {
  __shared__ float vals[NS_];
  __shared__ float rv[256];
  __shared__ int ri[256];
  __shared__ int s_vk;
  int b = blockIdx.x, tid = threadIdx.x;
  const float* pr = pos + (size_t)b * NS_;
  int c65 = 0;
#pragma unroll
  for (int t = 0; t < 4; ++t) {
    float v = pr[tid + (t << 8)];
    vals[tid + (t << 8)] = v;
    if (v > 0.65f) ++c65;
  }
  ri[tid] = c65;
  __syncthreads();
  for (int off = 128; off; off >>= 1) {
    if (tid < off) ri[tid] += ri[tid + off];
    __syncthreads();
  }
  if (tid == 0) {
    int vk = ri[0] > 118 ? ri[0] : 118;
    s_vk = vk > 128 ? 128 : vk;
  }
  __syncthreads();
  int vk = s_vk;
  for (int r = 0; r < 128; ++r) {
    float bv = -3.0e38f;
    int bi = 0x7fffffff;
#pragma unroll
    for (int t = 0; t < 4; ++t) {
      int i = tid + (t << 8);
      float v = vals[i];
      if (v > bv) { bv = v; bi = i; }
    }
    rv[tid] = bv; ri[tid] = bi;
    __syncthreads();
    for (int off = 128; off; off >>= 1) {
      if (tid < off) {
        float ov = rv[tid + off]; int oi = ri[tid + off];
        if (ov > rv[tid] || (ov == rv[tid] && oi < ri[tid])) {
          rv[tid] = ov; ri[tid] = oi;
        }
      }
      __syncthreads();
    }
    if (tid == 0) {
      int wi = ri[0]; float wv = rv[0];
      topi[(size_t)b * 128 + r] = (float)wi;
      if (r < vk && wv > 0.0f) sel[((size_t)b * 128 + r) * NS_ + wi] = 1.0f;
      vals[wi] = -3.0e38f;
    }
    __syncthreads();
  }
}

extern "C" void kernel_launch(void* const* d_in, const int* in_sizes, int n_in,
                              void* d_out, int out_size, void* d_ws, size_t ws_size,
                              hipStream_t stream) {
  (void)in_sizes; (void)n_in; (void)out_size; (void)ws_size;
  const float* x_b = (const float*)d_in[0];
  const float* x_s = (const float*)d_in[1];
  const int* token_types = (const int*)d_in[2];
  const int* base_idxs = (const int*)d_in[3];
  const float* ln1_w = (const float*)d_in[4];
  const float* ln1_b = (const float*)d_in[5];
  const float* ln2_w = (const float*)d_in[6];
  const float* ln2_b = (const float*)d_in[7];
  const float* ln3_w = (const float*)d_in[8];
  const float* ln3_b = (const float*)d_in[9];
  const float* Wq = (const float*)d_in[10];
  const float* Wkv = (const float*)d_in[11];
  const float* es_w1 = (const float*)d_in[12];
  const float* es_b1 = (const float*)d_in[13];
  const float* es_w2 = (const float*)d_in[14];
  const float* es_b2 = (const float*)d_in[15];
  const float* el_w1 = (const float*)d_in[16];
  const float* el_b1 = (const float*)d_in[17];
  const float* el_w2 = (const float*)d_in[18];
  const float* el_b2 = (const float*)d_in[19];
  const float* mlp_w1 = (const float*)d_in[20];
  const float* mlp_b1 = (const float*)d_in[21];
  const float* mlp_w2 = (const float*)d_in[22];
  const float* mlp_b2 = (const float*)d_in[23];

  float* out = (float*)d_out;
  float* sel_out  = out;
  float* topi_out = out + 1048576;
  float* pos_out  = out + 1049600;
  float* x_out    = out + 1057792;
  float* kern_out = out + 7349248;

  // ---- workspace layout (floats), peak ~252 MB ----
  // Attention window [31457280, 62914560) = 31.5M fl:
  //   scores 12.6M + part 12.6M (full 16 splits, race-free) + ctxf 6.3M.
  float* w = (float*)d_ws;
  float* kv_f = w;                        // [0, 25165824)
  float* q_f  = w + 25165824;             // [25165824, 31457280)
  float* scores = w + 31457280;           // [31457280, 44040192)
  float* part   = w + 44040192;           // [44040192, 56623104)  16-split PV
  float* ctxf   = w + 56623104;           // [56623104, 62914560)
  // Phase 1 plane staging (dead after phase 1):
  unsigned short* xbnp = (unsigned short*)(w + 31457280);  // [31457280, 50331648)
  unsigned short* xsnp = (unsigned short*)(w + 50331648);  // [50331648, 59768832)
  unsigned short* wqp  = (unsigned short*)(w + 59768832);  // [59768832, 60653568)
  unsigned short* wkvp = (unsigned short*)(w + 60653568);  // [60653568, 62423040)
  // Phase 3/4 (FFN) overlays:
  unsigned short* ctxp = (unsigned short*)(w + 6291456);   // 18874368 us
  unsigned short* wb   = (unsigned short*)(w + 15728640);  // 42467328 us
  unsigned short* hp   = (unsigned short*)(w + 36962304);  // 37748736 us
  float* P0 = w;                                           // 6291456 fl
  const long ZS = 55836672;
  float* P1 = w + ZS;                                      // [55836672, 62128128)
  // Phase 5 overlays:
  float* xn     = w + 6291456;
  float* tokens = w + 12582912;
  float* aw     = w + 15728640;
  float* agg    = w + 17825792;
  // small block
  float* small  = w + 62914560;
  float* maskf  = small;
  float* hasf   = small + 4096;
  int* cnt      = (int*)(small + 4104);
  int* perm0    = (int*)(small + 4106);
  int* perm1    = (int*)(small + 12298);

  // weight plane sub-layout (ushort offsets in wb)
  unsigned short* esw1h[2] = {wb + 0,        wb + 3538944};
  unsigned short* elw1h[2] = {wb + 7077888,  wb + 10616832};
  unsigned short* mlw1h[2] = {wb + 14155776, wb + 17694720};
  unsigned short* esw2h[2] = {wb + 21233664, wb + 24772608};
  unsigned short* elw2h[2] = {wb + 28311552, wb + 31850496};
  unsigned short* mlw2h[2] = {wb + 35389440, wb + 38928384};

  const long NSC = (long)NS_ * Cc_;
  const long NB2C = (long)NB_ * 2 * Cc_;
  const long SNB = (long)NS_ * NB_;
  const float qk_scale = 0.08838834764831845f;
  const float sc_scale = 0.036084391824351615f;

  hipMemsetAsync(sel_out, 0, (size_t)1048576 * sizeof(float), stream);
  hipMemsetAsync(cnt, 0, 2 * sizeof(int), stream);

  // ---- phase 1: LN->planes, weight planes, q/kv on MFMA ----
  ln_split<<<B_ * NS_, 256, 0, stream>>>(x_s, xsnp, ln1_w, ln1_b);
  ln_split<<<B_ * NB_, 256, 0, stream>>>(x_b, xbnp, ln2_w, ln2_b);
  build_perm<<<32, 256, 0, stream>>>(token_types, perm0, perm1, cnt);
  wconv<<<dim3(3, 768), 256, 0, stream>>>(Wq, wqp, 768, 768, 768, 0);
  wconv<<<dim3(3, 1536), 256, 0, stream>>>(Wkv, wkvp, 768, 1536, 1536, 0);
  mgemm<6, false, false, true><<<dim3(6, 64, 1), 256, 0, stream>>>(
      xsnp, wqp, q_f, nullptr, nullptr, nullptr, nullptr,
      8192, 768, 768, 768, 0, 1, 0, 0, 0, 1.0f);
  mgemm<6, false, false, true><<<dim3(12, 128, 1), 256, 0, stream>>>(
      xbnp, wkvp, kv_f, nullptr, nullptr, nullptr, nullptr,
      16384, 1536, 768, 1536, 0, 1, 0, 0, 0, 1.0f);

  // ---- phase 2: attention (f32 QK^T + softmax + PV split-16) ----
  for (int b = 0; b < B_; ++b) {
    const float* qb = q_f + (size_t)b * NSC;
    const float* kb = kv_f + (size_t)b * NB2C;
    const float* vb = kb + Cc_;
    gemm128<0, 1, false, false><<<dim3(16, 8, 6), 256, 0, stream>>>(
        qb, kb, scores, nullptr, nullptr, nullptr, nullptr,
        1024, 2048, 128, 768, 1536, 2048,
        1, 1, 128, 0, 0, 128, 0, 0, SNB, 0, 0, qk_scale);
    softmax_kernel<8, false><<<6 * 1024, 256, 0, stream>>>(scores, nullptr);
    // z = h*16 + ks (d1=6, d2=16): C off = h*131072 + ks*786432
    //   = (ks*6+h)*131072  -- matches pv_reduce, bijective over 12.58M fl
    gemm128<0, 0, false, false><<<dim3(1, 8, 96), 256, 0, stream>>>(
        scores, vb, part, nullptr, nullptr, nullptr, nullptr,
        1024, 128, 128, 2048, 1536, 128,
        6, 16, 0, SNB, 128, 0, 128, 128 * 1536, 0, 131072, 786432, 1.0f);
    pv_reduce<<<3072, 256, 0, stream>>>(part, ctxf + (size_t)b * NSC);
  }

  // ---- phase 3: split ctx, convert FFN weights ----
  split_kernel<<<24576, 256, 0, stream>>>(ctxf, ctxp);
  for (int h = 0; h < 2; ++h) {
    wconv<<<dim3(3, 1536), 256, 0, stream>>>(es_w1, esw1h[h], 768, 1536, 3072, h * 1536);
    wconv<<<dim3(3, 1536), 256, 0, stream>>>(el_w1, elw1h[h], 768, 1536, 3072, h * 1536);
    wconv<<<dim3(3, 1536), 256, 0, stream>>>(mlp_w1, mlw1h[h], 768, 1536, 3072, h * 1536);
    wconv<<<dim3(6, 768), 256, 0, stream>>>(es_w2 + (size_t)h * 1536 * 768, esw2h[h], 1536, 768, 768, 0);
    wconv<<<dim3(6, 768), 256, 0, stream>>>(el_w2 + (size_t)h * 1536 * 768, elw2h[h], 1536, 768, 768, 0);
    wconv<<<dim3(6, 768), 256, 0, stream>>>(mlp_w2 + (size_t)h * 1536 * 768, mlw2h[h], 1536, 768, 768, 0);
  }

  // ---- phase 4: MoE experts + MLP on MFMA (hidden in 2 halves) ----
  // MDEV launches: SWZ=false (early-exit tiles must stay XCD-uniform).
  for (int h = 0; h < 2; ++h) {
    mgemm<5, true, true, false><<<dim3(12, 64, 1), 256, 0, stream>>>(
        ctxp, esw1h[h], nullptr, hp, es_b1 + h * 1536, perm0, cnt,
        8192, 1536, 768, 0, 1536, 1, 0, 0, 0, 1.0f);
    if (h == 0)
      mgemm<6, false, true, false><<<dim3(6, 64, 2), 256, 0, stream>>>(
          hp, esw2h[h], P0, nullptr, nullptr, nullptr, cnt,
          8192, 768, 1536, 768, 0, 2, 0, 0, ZS, 1.0f);
    else
      mgemm<7, false, true, false><<<dim3(6, 64, 2), 256, 0, stream>>>(
          hp, esw2h[h], P0, nullptr, nullptr, nullptr, cnt,
          8192, 768, 1536, 768, 0, 2, 0, 0, ZS, 1.0f);
  }
  combineP<true><<<dim3(8192, 3), 256, 0, stream>>>(
      P0, P1, es_b2, x_s, perm0, cnt, x_out);
  for (int h = 0; h < 2; ++h) {
    mgemm<5, true, true, false><<<dim3(12, 64, 1), 256, 0, stream>>>(
        ctxp, elw1h[h], nullptr, hp, el_b1 + h * 1536, perm1, cnt + 1,
        8192, 1536, 768, 0, 1536, 1, 0, 0, 0, 1.0f);
    if (h == 0)
      mgemm<6, false, true, false><<<dim3(6, 64, 2), 256, 0, stream>>>(
          hp, elw2h[h], P0, nullptr, nullptr, nullptr, cnt + 1,
          8192, 768, 1536, 768, 0, 2, 0, 0, ZS, 1.0f);
    else
      mgemm<7, false, true, false><<<dim3(6, 64, 2), 256, 0, stream>>>(
          hp, elw2h[h], P0, nullptr, nullptr, nullptr, cnt + 1,
          8192, 768, 1536, 768, 0, 2, 0, 0, ZS, 1.0f);
  }
  combineP<true><<<dim3(8192, 3), 256, 0, stream>>>(
      P0, P1, el_b2, x_s, perm1, cnt + 1, x_out);
  ln_split<<<B_ * NS_, 256, 0, stream>>>(x_out, ctxp, ln3_w, ln3_b);
  for (int h = 0; h < 2; ++h) {
    mgemm<5, false, false, true><<<dim3(12, 64, 1), 256, 0, stream>>>(
        ctxp, mlw1h[h], nullptr, hp, mlp_b1 + h * 1536, nullptr, nullptr,
        8192, 1536, 768, 0, 1536, 1, 0, 0, 0, 1.0f);
    if (h == 0)
      mgemm<6, false, false, true><<<dim3(6, 64, 2), 256, 0, stream>>>(
          hp, mlw2h[h], P0, nullptr, nullptr, nullptr, nullptr,
          8192, 768, 1536, 768, 0, 2, 0, 0, ZS, 1.0f);
    else
      mgemm<7, false, false, true><<<dim3(6, 64, 2), 256, 0, stream>>>(
          hp, mlw2h[h], P0, nullptr, nullptr, nullptr, nullptr,
          8192, 768, 1536, 768, 0, 2, 0, 0, ZS, 1.0f);
  }
  combineP<false><<<dim3(8192, 3), 256, 0, stream>>>(
      P0, P1, mlp_b2, x_out, nullptr, nullptr, x_out);

  // ---- phase 5: scoring tail (f32) ----
  rownorm_kernel<<<B_ * NS_, 256, 0, stream>>>(x_out, xn);
  gather_kernel<<<12288, 256, 0, stream>>>(x_b, base_idxs, tokens, maskf);
  gemm128<0, 1, false, false><<<dim3(4, 4, 8), 256, 0, stream>>>(
      tokens, tokens, aw, nullptr, nullptr, nullptr, nullptr,
      512, 512, 768, 768, 768, 512,
      1, 1, 393216, 0, 0, 393216, 0, 0, 262144, 0, 0, sc_scale);
  softmax_kernel<2, true><<<8 * 512, 256, 0, stream>>>(aw, maskf);
  gemm128<0, 0, false, false><<<dim3(6, 4, 8), 256, 0, stream>>>(
      aw, tokens, agg, nullptr, nullptr, nullptr, nullptr,
      512, 768, 512, 512, 768, 768,
      1, 1, 262144, 0, 0, 393216, 0, 0, 393216, 0, 0, 1.0f);
  kernel_kernel<<<8, 256, 0, stream>>>(agg, maskf, kern_out, hasf);
  pos_kernel<<<B_ * NS_, 256, 0, stream>>>(xn, kern_out, hasf, pos_out);
  topk_kernel<<<8, 256, 0, stream>>>(pos_out, sel_out, topi_out);
}

// Round 14
// 3198.980 us; speedup vs baseline: 1.1882x; 1.0426x over previous
//
#include <hip/hip_runtime.h>
#include <hip/hip_bf16.h>
#include <math.h>

// Problem constants
#define B_   8
#define NB_  2048
#define NS_  1024
#define Cc_  768
#define HID_ 3072
#define NP_  1024
#define NH_  6
#define HD_  128

__device__ __forceinline__ float gelu_exact(float v) {
  return 0.5f * v * (1.0f + erff(v * 0.7071067811865476f));
}

// split f32 into 3 bf16 planes (truncation; dropped residual ~2^-24 rel)
__device__ __forceinline__ void split3(float v, unsigned short& h,
                                       unsigned short& m, unsigned short& l) {
  unsigned hb = __float_as_uint(v) & 0xffff0000u;
  float r1 = v - __uint_as_float(hb);
  unsigned mb = __float_as_uint(r1) & 0xffff0000u;
  float r2 = r1 - __uint_as_float(mb);
  unsigned lb = __float_as_uint(r2) & 0xffff0000u;
  h = (unsigned short)(hb >> 16);
  m = (unsigned short)(mb >> 16);
  l = (unsigned short)(lb >> 16);
}

typedef short bf16x8 __attribute__((ext_vector_type(8)));
typedef float f32x4 __attribute__((ext_vector_type(4)));

#define BLOCK_REDUCE_ADD(red, tid)                                              \
  for (int off_ = 128; off_; off_ >>= 1) {                                      \
    if ((tid) < off_) red[(tid)] += red[(tid) + off_];                          \
    __syncthreads();                                                            \
  }

// ---------------- LayerNorm -> 3 bf16 planes [row][3*768] ----------------
__global__ __launch_bounds__(256) void ln_split(
    const float* __restrict__ x, unsigned short* __restrict__ y,
    const float* __restrict__ w, const float* __restrict__ b) {
  __shared__ float red[256];
  int row = blockIdx.x, tid = threadIdx.x;
  const float* xr = x + (size_t)row * Cc_;
  float v0 = xr[tid], v1 = xr[tid + 256], v2 = xr[tid + 512];
  red[tid] = v0 + v1 + v2;
  __syncthreads();
  BLOCK_REDUCE_ADD(red, tid);
  float mu = red[0] / (float)Cc_;
  __syncthreads();
  float d0 = v0 - mu, d1 = v1 - mu, d2 = v2 - mu;
  red[tid] = d0 * d0 + d1 * d1 + d2 * d2;
  __syncthreads();
  BLOCK_REDUCE_ADD(red, tid);
  float var = red[0] / (float)Cc_;
  float rs = 1.0f / sqrtf(var + 1e-5f);
  unsigned short* yr = y + (size_t)row * 2304;
  float vals[3] = {d0 * rs * w[tid] + b[tid],
                   d1 * rs * w[tid + 256] + b[tid + 256],
                   d2 * rs * w[tid + 512] + b[tid + 512]};
#pragma unroll
  for (int t = 0; t < 3; ++t) {
    int c = tid + (t << 8);
    unsigned short h16, m16, l16;
    split3(vals[t], h16, m16, l16);
    yr[c] = h16; yr[768 + c] = m16; yr[1536 + c] = l16;
  }
}

// ---------------- f32 [8192][768] -> 3 bf16 planes ----------------
__global__ __launch_bounds__(256) void split_kernel(
    const float* __restrict__ x, unsigned short* __restrict__ y) {
  size_t idx = (size_t)blockIdx.x * 256 + threadIdx.x;  // < 8192*768
  int c = (int)(idx % Cc_);
  int row = (int)(idx / Cc_);
  unsigned short h16, m16, l16;
  split3(x[idx], h16, m16, l16);
  unsigned short* yr = y + (size_t)row * 2304;
  yr[c] = h16; yr[768 + c] = m16; yr[1536 + c] = l16;
}

// ---------------- Row L2-normalize ----------------
__global__ __launch_bounds__(256) void rownorm_kernel(
    const float* __restrict__ x, float* __restrict__ y) {
  __shared__ float red[256];
  int row = blockIdx.x, tid = threadIdx.x;
  const float* xr = x + (size_t)row * Cc_;
  float* yr = y + (size_t)row * Cc_;
  float v0 = xr[tid], v1 = xr[tid + 256], v2 = xr[tid + 512];
  red[tid] = v0 * v0 + v1 * v1 + v2 * v2;
  __syncthreads();
  BLOCK_REDUCE_ADD(red, tid);
  float den = fmaxf(sqrtf(red[0]), 1e-12f);
  yr[tid]       = v0 / den;
  yr[tid + 256] = v1 / den;
  yr[tid + 512] = v2 / den;
}

// --------- weight convert: W rows k in [0,K), col ncol0+n -> out[N][3K] ----
__global__ __launch_bounds__(256) void wconv(
    const float* __restrict__ W, unsigned short* __restrict__ out,
    int K, int N, int ldw, int ncol0) {
  int k = blockIdx.x * 256 + threadIdx.x;
  int n = blockIdx.y;
  float v = W[(size_t)k * ldw + ncol0 + n];
  unsigned short h16, m16, l16;
  split3(v, h16, m16, l16);
  size_t base = (size_t)n * 3 * K;
  out[base + k] = h16;
  out[base + K + k] = m16;
  out[base + 2 * K + k] = l16;
}

// --------- mega weight convert: all 12 FFN plane jobs in one launch --------
// z 0-5: w1 halves (K=768, ldw=3072, ncol0=h*1536, N=1536)
// z 6-11: w2 halves (K=1536, ldw=768, src += h*1536*768, N=768)
// out offsets match the wb sub-layout exactly.
__global__ __launch_bounds__(256) void wconv12(
    const float* __restrict__ w1a, const float* __restrict__ w1b,
    const float* __restrict__ w1c, const float* __restrict__ w2a,
    const float* __restrict__ w2b, const float* __restrict__ w2c,
    unsigned short* __restrict__ wb) {
  int z = blockIdx.z;
  int k = blockIdx.x * 256 + threadIdx.x;
  int n = blockIdx.y;
  const float* W;
  int K, ldw, ncol0;
  size_t out_off;
  if (z < 6) {
    K = 768; ldw = 3072;
    int m = z >> 1, h = z & 1;
    W = (m == 0) ? w1a : ((m == 1) ? w1b : w1c);
    ncol0 = h * 1536;
    out_off = (size_t)m * 7077888 + (size_t)h * 3538944;
    if (k >= 768) return;
  } else {
    K = 1536; ldw = 768; ncol0 = 0;
    int m = (z - 6) >> 1, h = z & 1;
    W = ((m == 0) ? w2a : ((m == 1) ? w2b : w2c)) + (size_t)h * 1536 * 768;
    out_off = 21233664 + (size_t)m * 7077888 + (size_t)h * 3538944;
    if (n >= 768) return;
  }
  float v = W[(size_t)k * ldw + ncol0 + n];
  unsigned short h16, m16, l16;
  split3(v, h16, m16, l16);
  size_t base = out_off + (size_t)n * 3 * K;
  wb[base + k] = h16;
  wb[base + K + k] = m16;
  wb[base + 2 * K + k] = l16;
}

// ---------------- MFMA GEMM over 3-split bf16 planes ----------------
// A planes [M][3K] bf16; B planes [N][3K] bf16 (op-B transposed).
// K'' = 6K via segments pa={0,0,1,0,1,2}, pb={0,1,0,2,1,0}.
// 128x128 tile, 4 waves, mfma_f32_16x16x32_bf16, dbuf LDS, one
// lgkmcnt(0)+s_barrier per 64-wide k-tile.
// SWZ: XCD-aware block swizzle (needs gridDim.x*gridDim.y % 8 == 0).
//   MUST be false for MDEV launches (R12 lesson: early-exit imbalance).
// EPI: 5 = gelu(v+bias) -> 3 bf16 planes Cs[m][3*Kout]
//      6 = f32:  Cf[z*zstride + m*ldc + n] = v
//      7 = f32:  Cf[z*zstride + m*ldc + n] += v
template <int EPI, bool AGATHER, bool MDEV, bool SWZ>
__global__ __launch_bounds__(256) void mgemm(
    const unsigned short* __restrict__ Ap, const unsigned short* __restrict__ Bp,
    float* __restrict__ Cf, unsigned short* __restrict__ Cs,
    const float* __restrict__ bias,
    const int* __restrict__ perm, const int* __restrict__ mdev,
    int M, int N, int K, int ldc, int Kout, int nsplit,
    long azs, long bzs, long zstride, float scale) {
  __shared__ unsigned short As[2][8192];
  __shared__ unsigned short Bs[2][8192];
  int z = blockIdx.z;
  int bx, by;
  if (SWZ) {
    int gx = gridDim.x;
    int id = blockIdx.y * gx + blockIdx.x;
    int per = (gx * gridDim.y) >> 3;
    int nid = (id & 7) * per + (id >> 3);
    bx = nid % gx; by = nid / gx;
  } else {
    bx = blockIdx.x; by = blockIdx.y;
  }
  int Me = MDEV ? mdev[0] : M;
  int m0 = by * 128, n0 = bx * 128;
  if (MDEV && m0 >= Me) return;
  const unsigned short* ApB = Ap + (size_t)z * azs;
  const unsigned short* BpB = Bp + (size_t)z * bzs;
  int tid = threadIdx.x;
  int lane = tid & 63, w = tid >> 6;
  int wr = w >> 1, wc = w & 1;
  int K3 = 3 * K;
  int tps = K >> 6;        // 64-wide tiles per plane-segment
  int KT = 6 * tps;
  int span = KT / nsplit;
  int zr = z % nsplit;
  int tt0 = zr * span, tt1 = tt0 + span;

  const unsigned short* agp[4];
  const unsigned short* bgp[4];
  int wswz[4];
#pragma unroll
  for (int p = 0; p < 4; ++p) {
    int r = (tid >> 3) + 32 * p;
    int ma = m0 + r;
    if (MDEV) ma = min(ma, Me - 1);
    if (AGATHER) ma = perm[ma];
    agp[p] = ApB + (size_t)ma * K3 + (tid & 7) * 8;
    bgp[p] = BpB + (size_t)(n0 + r) * K3 + (tid & 7) * 8;
    wswz[p] = r * 64 + (((tid & 7) ^ (r & 7)) << 3);
  }

  f32x4 acc[4][4];
  f32x4 zero4 = {0.f, 0.f, 0.f, 0.f};
#pragma unroll
  for (int i = 0; i < 4; ++i)
#pragma unroll
    for (int j = 0; j < 4; ++j) acc[i][j] = zero4;

  int kg = lane >> 4;
  int frm[4], frn[4];
#pragma unroll
  for (int f = 0; f < 4; ++f) {
    frm[f] = wr * 64 + f * 16 + (lane & 15);
    frn[f] = wc * 64 + f * 16 + (lane & 15);
  }

  bf16x8 ra[4], rb[4];
  {
    int seg = tt0 / tps, kt = tt0 - seg * tps;
    int pa = (0x210100u >> (4 * seg)) & 0xF;
    int pb = (0x012010u >> (4 * seg)) & 0xF;
    size_t ao = (size_t)(pa * K + kt * 64);
    size_t bo = (size_t)(pb * K + kt * 64);
#pragma unroll
    for (int p = 0; p < 4; ++p) {
      ra[p] = *(const bf16x8*)(agp[p] + ao);
      rb[p] = *(const bf16x8*)(bgp[p] + bo);
    }
  }

  for (int tt = tt0; tt < tt1; ++tt) {
    int cur = tt & 1;
#pragma unroll
    for (int p = 0; p < 4; ++p) {
      *(bf16x8*)&As[cur][wswz[p]] = ra[p];
      *(bf16x8*)&Bs[cur][wswz[p]] = rb[p];
    }
    if (tt + 1 < tt1) {
      int seg = (tt + 1) / tps, kt = (tt + 1) - seg * tps;
      int pa = (0x210100u >> (4 * seg)) & 0xF;
      int pb = (0x012010u >> (4 * seg)) & 0xF;
      size_t ao = (size_t)(pa * K + kt * 64);
      size_t bo = (size_t)(pb * K + kt * 64);
#pragma unroll
      for (int p = 0; p < 4; ++p) {
        ra[p] = *(const bf16x8*)(agp[p] + ao);
        rb[p] = *(const bf16x8*)(bgp[p] + bo);
      }
    }
    asm volatile("s_waitcnt lgkmcnt(0)" ::: "memory");
    __builtin_amdgcn_s_barrier();
#pragma unroll
    for (int ks = 0; ks < 2; ++ks) {
      int ch = ks * 4 + kg;
      bf16x8 af[4], bf[4];
#pragma unroll
      for (int f = 0; f < 4; ++f) {
        int r = frm[f];
        af[f] = *(const bf16x8*)&As[cur][r * 64 + ((ch ^ (r & 7)) << 3)];
      }
#pragma unroll
      for (int f = 0; f < 4; ++f) {
        int r = frn[f];
        bf[f] = *(const bf16x8*)&Bs[cur][r * 64 + ((ch ^ (r & 7)) << 3)];
      }
#pragma unroll
      for (int i = 0; i < 4; ++i)
#pragma unroll
        for (int j = 0; j < 4; ++j)
          acc[i][j] = __builtin_amdgcn_mfma_f32_16x16x32_bf16(
              af[i], bf[j], acc[i][j], 0, 0, 0);
    }
  }

  // epilogue: C/D layout col=lane&15, row=(lane>>4)*4+reg (m89-verified)
#pragma unroll
  for (int i = 0; i < 4; ++i) {
#pragma unroll
    for (int r = 0; r < 4; ++r) {
      int m = m0 + wr * 64 + i * 16 + kg * 4 + r;
      if (MDEV && m >= Me) continue;
#pragma unroll
      for (int j = 0; j < 4; ++j) {
        int n = n0 + wc * 64 + j * 16 + (lane & 15);
        float v = acc[i][j][r] * scale;
        if (EPI == 6) {
          Cf[(size_t)z * zstride + (size_t)m * ldc + n] = v;
        } else if (EPI == 7) {
          Cf[(size_t)z * zstride + (size_t)m * ldc + n] += v;
        } else if (EPI == 5) {
          float t = gelu_exact(v + bias[n]);
          unsigned short h16, m16, l16;
          split3(t, h16, m16, l16);
          size_t base = (size_t)m * 3 * Kout;
          Cs[base + n] = h16;
          Cs[base + Kout + n] = m16;
          Cs[base + 2 * Kout + n] = l16;
        }
      }
    }
  }
}

// ---------------- combine partials: out = bias + addsrc + P0 + P1 ----------
template <bool SCATTER>
__global__ __launch_bounds__(256) void combineP(
    const float* __restrict__ P0, const float* __restrict__ P1,
    const float* __restrict__ bias, const float* __restrict__ addsrc,
    const int* __restrict__ perm, const int* __restrict__ cnt,
    float* __restrict__ out) {
  int m = blockIdx.x;
  int c = threadIdx.x + (blockIdx.y << 8);
  if (SCATTER && m >= cnt[0]) return;
  int mo = SCATTER ? perm[m] : m;
  size_t pm = (size_t)m * 768 + c;
  out[(size_t)mo * 768 + c] =
      bias[c] + addsrc[(size_t)mo * 768 + c] + P0[pm] + P1[pm];
}

// ---------------- f32 GEMM (R5: 128x128, 8x8, reg-prefetch dbuf) ----------
template <int EPI, int TRB, bool AGATHER, bool MDEV>
__global__ __launch_bounds__(256) void gemm128(
    const float* __restrict__ A, const float* __restrict__ Bm,
    float* __restrict__ Cm, const float* __restrict__ bias,
    const float* __restrict__ addsrc, const int* __restrict__ perm,
    const int* __restrict__ mdev,
    int M, int N, int K, int lda, int ldb, int ldc,
    int d1, int d2,
    long a_s1, long a_s2, long a_s3,
    long b_s1, long b_s2, long b_s3,
    long c_s1, long c_s2, long c_s3,
    float scale) {
  __shared__ float As[2][16][132];
  __shared__ float Bs[2][16][132];
  int z = blockIdx.z;
  int z1 = z / (d1 * d2);
  int rem = z - z1 * d1 * d2;
  int z2 = rem / d2, z3 = rem - z2 * d2;
  const float* Ab = A + (size_t)z1 * a_s1 + (size_t)z2 * a_s2 + (size_t)z3 * a_s3;
  const float* Bb = Bm + (size_t)z1 * b_s1 + (size_t)z2 * b_s2 + (size_t)z3 * b_s3;
  float* Cb = Cm + (size_t)z1 * c_s1 + (size_t)z2 * c_s2 + (size_t)z3 * c_s3;
  int Me = MDEV ? mdev[0] : M;
  int m0 = blockIdx.y * 128, n0 = blockIdx.x * 128;
  if (MDEV && m0 >= Me) return;
  int tid = threadIdx.x;
  int tx = tid & 15, ty = tid >> 4;
  int arow = tid >> 2, akq = tid & 3;
  int ma0 = m0 + arow, ma1 = m0 + arow + 64;
  if (MDEV) { ma0 = min(ma0, Me - 1); ma1 = min(ma1, Me - 1); }
  if (AGATHER) { ma0 = perm[ma0]; ma1 = perm[ma1]; }
  const float* Ap0 = Ab + (size_t)ma0 * lda + akq * 4;
  const float* Ap1 = Ab + (size_t)ma1 * lda + akq * 4;
  const float* Bp0;
  const float* Bp1;
  int bw_r0 = 0, bw_c0 = 0, bw_r1 = 0;
  if (TRB == 0) {
    bw_r0 = tid >> 5; bw_c0 = (tid & 31) * 4; bw_r1 = bw_r0 + 8;
    Bp0 = Bb + (size_t)bw_r0 * ldb + n0 + bw_c0;
    Bp1 = Bb + (size_t)bw_r1 * ldb + n0 + bw_c0;
  } else {
    Bp0 = Bb + (size_t)(n0 + arow) * ldb + akq * 4;
    Bp1 = Bb + (size_t)(n0 + arow + 64) * ldb + akq * 4;
  }
  float4 pa0 = *(const float4*)Ap0;
  float4 pa1 = *(const float4*)Ap1;
  float4 pb0 = *(const float4*)Bp0;
  float4 pb1 = *(const float4*)Bp1;
  float acc[8][8] = {};
  int nt = K >> 4;
  for (int t = 0; t < nt; ++t) {
    int cur = t & 1;
    As[cur][akq * 4 + 0][arow] = pa0.x; As[cur][akq * 4 + 1][arow] = pa0.y;
    As[cur][akq * 4 + 2][arow] = pa0.z; As[cur][akq * 4 + 3][arow] = pa0.w;
    As[cur][akq * 4 + 0][arow + 64] = pa1.x; As[cur][akq * 4 + 1][arow + 64] = pa1.y;
    As[cur][akq * 4 + 2][arow + 64] = pa1.z; As[cur][akq * 4 + 3][arow + 64] = pa1.w;
    if (TRB == 0) {
      *(float4*)&Bs[cur][bw_r0][bw_c0] = pb0;
      *(float4*)&Bs[cur][bw_r1][bw_c0] = pb1;
    } else {
      Bs[cur][akq * 4 + 0][arow] = pb0.x; Bs[cur][akq * 4 + 1][arow] = pb0.y;
      Bs[cur][akq * 4 + 2][arow] = pb0.z; Bs[cur][akq * 4 + 3][arow] = pb0.w;
      Bs[cur][akq * 4 + 0][arow + 64] = pb1.x; Bs[cur][akq * 4 + 1][arow + 64] = pb1.y;
      Bs[cur][akq * 4 + 2][arow + 64] = pb1.z; Bs[cur][akq * 4 + 3][arow + 64] = pb1.w;
    }
    if (t + 1 < nt) {
      int kn = (t + 1) << 4;
      pa0 = *(const float4*)&Ap0[kn];
      pa1 = *(const float4*)&Ap1[kn];
      if (TRB == 0) {
        pb0 = *(const float4*)&Bp0[(size_t)kn * ldb];
        pb1 = *(const float4*)&Bp1[(size_t)kn * ldb];
      } else {
        pb0 = *(const float4*)&Bp0[kn];
        pb1 = *(const float4*)&Bp1[kn];
      }
    }
    asm volatile("s_waitcnt lgkmcnt(0)" ::: "memory");
    __builtin_amdgcn_s_barrier();
#pragma unroll
    for (int kk = 0; kk < 16; ++kk) {
      float a[8], b[8];
      *(float4*)&a[0] = *(const float4*)&As[cur][kk][ty * 4];
      *(float4*)&a[4] = *(const float4*)&As[cur][kk][ty * 4 + 64];
      *(float4*)&b[0] = *(const float4*)&Bs[cur][kk][tx * 4];
      *(float4*)&b[4] = *(const float4*)&Bs[cur][kk][tx * 4 + 64];
#pragma unroll
      for (int i = 0; i < 8; ++i)
#pragma unroll
        for (int j = 0; j < 8; ++j)
          acc[i][j] = fmaf(a[i], b[j], acc[i][j]);
    }
  }
#pragma unroll
  for (int i = 0; i < 8; ++i) {
    int m = m0 + ((i < 4) ? (ty * 4 + i) : (64 + ty * 4 + i - 4));
    if (!MDEV || m < Me) {
      int mo = (EPI == 4) ? perm[m] : m;
      int n = n0 + tx * 4;
      float v[8];
#pragma unroll
      for (int j = 0; j < 8; ++j) {
        int nj = (j < 4) ? (n + j) : (n + 64 + j - 4);
        v[j] = acc[i][j] * scale;
        if (EPI >= 1) v[j] += bias[nj];
        if (EPI == 2) v[j] = gelu_exact(v[j]);
        if (EPI == 3 || EPI == 4) v[j] += addsrc[(size_t)mo * ldc + nj];
      }
      float* cp = &Cb[(size_t)mo * ldc + n];
      *(float4*)cp = make_float4(v[0], v[1], v[2], v[3]);
      *(float4*)(cp + 64) = make_float4(v[4], v[5], v[6], v[7]);
    }
  }
}

// ---------------- PV split-K(16) reduce -> f32 ctx ----------------
__global__ __launch_bounds__(256) void pv_reduce(
    const float* __restrict__ part, float* __restrict__ ctx) {
  int i = blockIdx.x * 256 + threadIdx.x;
  int n = i & 127, m = (i >> 7) & 1023, h = i >> 17;
  float s = 0.f;
#pragma unroll
  for (int ks = 0; ks < 16; ++ks)
    s += part[(size_t)(ks * 6 + h) * 131072 + m * 128 + n];
  ctx[(size_t)m * 768 + h * 128 + n] = s;
}

// ---------------- Softmax (native exp, hoisted reciprocal) ----------------
template <int EPT, bool MASK>
__global__ __launch_bounds__(256) void softmax_kernel(
    float* __restrict__ s, const float* __restrict__ maskf) {
  __shared__ float red[256];
  int row = blockIdx.x, tid = threadIdx.x;
  float* sr = s + (size_t)row * (EPT * 256);
  const float* mb = MASK ? (maskf + (size_t)(row / 512) * 512) : nullptr;
  float v[EPT];
  float m = -3.0e38f;
#pragma unroll
  for (int t = 0; t < EPT; ++t) {
    int j = tid + (t << 8);
    float xv = sr[j];
    if (MASK) xv += (mb[j] != 0.0f) ? 0.0f : -1e9f;
    v[t] = xv;
    m = fmaxf(m, xv);
  }
  red[tid] = m;
  __syncthreads();
  for (int off = 128; off; off >>= 1) {
    if (tid < off) red[tid] = fmaxf(red[tid], red[tid + off]);
    __syncthreads();
  }
  m = red[0];
  __syncthreads();
  float ssum = 0.f;
#pragma unroll
  for (int t = 0; t < EPT; ++t) {
    v[t] = __expf(v[t] - m);
    ssum += v[t];
  }
  red[tid] = ssum;
  __syncthreads();
  BLOCK_REDUCE_ADD(red, tid);
  float inv = 1.0f / red[0];
#pragma unroll
  for (int t = 0; t < EPT; ++t) sr[tid + (t << 8)] = v[t] * inv;
}

// ---------------- MoE permutation build ----------------
__global__ __launch_bounds__(256) void build_perm(
    const int* __restrict__ tt, int* __restrict__ perm0,
    int* __restrict__ perm1, int* __restrict__ cnt) {
  int r = blockIdx.x * 256 + threadIdx.x;
  int t = tt[r];
  if (t == 0) { int p = atomicAdd(&cnt[0], 1); perm0[p] = r; }
  else        { int p = atomicAdd(&cnt[1], 1); perm1[p] = r; }
}

// ---------------- Token gather ----------------
__global__ __launch_bounds__(256) void gather_kernel(
    const float* __restrict__ xb, const int* __restrict__ bidx,
    float* __restrict__ tokens, float* __restrict__ maskf) {
  size_t idx = (size_t)blockIdx.x * 256 + threadIdx.x;
  int c = (int)(idx % Cc_);
  int i = (int)((idx / Cc_) % 512);
  int b = (int)(idx / ((size_t)Cc_ * 512));
  int id = bidx[b * NP_ + i];
  bool m = id >= 0;
  int idc = m ? id : 0;
  tokens[idx] = m ? xb[((size_t)b * NB_ + idc) * Cc_ + c] : 0.0f;
  if (c == 0) maskf[b * 512 + i] = m ? 1.0f : 0.0f;
}

// ---------------- ksum -> kernel ----------------
__global__ __launch_bounds__(256) void kernel_kernel(
    const float* __restrict__ agg, const float* __restrict__ maskf,
    float* __restrict__ kern, float* __restrict__ hasf) {
  __shared__ float red[256];
  __shared__ float ks[Cc_];
  __shared__ float s_cnt;
  int b = blockIdx.x, tid = threadIdx.x;
  const float* mb = maskf + b * 512;
  red[tid] = mb[tid] + mb[tid + 256];
  __syncthreads();
  BLOCK_REDUCE_ADD(red, tid);
  if (tid == 0) s_cnt = red[0];
  __syncthreads();
  float cnt = s_cnt;
  float dc = fmaxf(cnt, 1.0f);
  const float* ab = agg + (size_t)b * 512 * Cc_;
#pragma unroll
  for (int t = 0; t < 3; ++t) {
    int cc = tid + t * 256;
    float s = 0.f;
    for (int i = 0; i < 512; ++i) s = fmaf(ab[(size_t)i * Cc_ + cc], mb[i], s);
    ks[cc] = s / dc;
  }
  __syncthreads();
  float s2 = 0.f;
#pragma unroll
  for (int t = 0; t < 3; ++t) {
    float q = ks[tid + t * 256];
    s2 = fmaf(q, q, s2);
  }
  red[tid] = s2;
  __syncthreads();
  BLOCK_REDUCE_ADD(red, tid);
  float den = fmaxf(sqrtf(red[0]), 1e-12f);
  bool has = cnt > 0.5f;
#pragma unroll
  for (int t = 0; t < 3; ++t) {
    int cc = tid + t * 256;
    kern[(size_t)b * Cc_ + cc] = has ? (ks[cc] / den) : 0.0f;
  }
  if (tid == 0) hasf[b] = has ? 1.0f : 0.0f;
}

// ---------------- pos ----------------
__global__ __launch_bounds__(256) void pos_kernel(
    const float* __restrict__ xnorm, const float* __restrict__ kern,
    const float* __restrict__ hasf, float* __restrict__ pos) {
  __shared__ float red[256];
  int row = blockIdx.x, tid = threadIdx.x;
  int b = row >> 10;
  const float* xr = xnorm + (size_t)row * Cc_;
  const float* kr = kern + (size_t)b * Cc_;
  float s = xr[tid] * kr[tid];
  s = fmaf(xr[tid + 256], kr[tid + 256], s);
  s = fmaf(xr[tid + 512], kr[tid + 512], s);
  red[tid] = s;
  __syncthreads();
  BLOCK_REDUCE_ADD(red, tid);
  if (tid == 0) pos[row] = (hasf[b] > 0.5f) ? (red[0] + 1.0f) * 0.5f : 0.0f;
}

// ---------------- per-batch top-128 via bitonic sort ----------------
// Sort all 1024 (value desc, index asc on ties) = jax stable top_k order.
__global__ __launch_bounds__(256) void topk_kernel(
    const float* __restrict__ pos, float* __restrict__ sel,
    float* __restrict__ topi) {
  __shared__ float sv[NS_];
  __shared__ int si[NS_];
  __shared__ int red[256];
  __shared__ int s_vk;
  int b = blockIdx.x, tid = threadIdx.x;
  const float* pr = pos + (size_t)b * NS_;
  int c65 = 0;
#pragma unroll
  for (int t = 0; t < 4; ++t) {
    int i = tid + (t << 8);
    float v = pr[i];
    sv[i] = v; si[i] = i;
    if (v > 0.65f) ++c65;
  }
  red[tid] = c65;
  __syncthreads();
  for (int off = 128; off; off >>= 1) {
    if (tid < off) red[tid] += red[tid + off];
    __syncthreads();
  }
  if (tid == 0) {
    int vk = red[0] > 118 ? red[0] : 118;
    s_vk = vk > 128 ? 128 : vk;
  }
  // bitonic sort (55 passes)
  for (int k = 2; k <= NS_; k <<= 1) {
    for (int j = k >> 1; j > 0; j >>= 1) {
      __syncthreads();
#pragma unroll
      for (int t = 0; t < 4; ++t) {
        int i = tid + (t << 8);
        int l = i ^ j;
        if (l > i) {
          bool up = ((i & k) == 0);
          float vi = sv[i], vl = sv[l];
          int ii = si[i], il = si[l];
          // gt: arr[i] belongs AFTER arr[l] in final (desc-val, asc-idx) order
          bool gt = (vi < vl) || (vi == vl && ii > il);
          if (up == gt) {
            sv[i] = vl; sv[l] = vi;
            si[i] = il; si[l] = ii;
          }
        }
      }
    }
  }
  __syncthreads();
  if (tid < 128) {
    int wi = si[tid];
    float wv = sv[tid];
    topi[(size_t)b * 128 + tid] = (float)wi;
    if (tid < s_vk && wv > 0.0f) sel[((size_t)b * 128 + tid) * NS_ + wi] = 1.0f;
  }
}

extern "C" void kernel_launch(void* const* d_in, const int* in_sizes, int n_in,
                              void* d_out, int out_size, void* d_ws, size_t ws_size,
                              hipStream_t stream) {
  (void)in_sizes; (void)n_in; (void)out_size; (void)ws_size;
  const float* x_b = (const float*)d_in[0];
  const float* x_s = (const float*)d_in[1];
  const int* token_types = (const int*)d_in[2];
  const int* base_idxs = (const int*)d_in[3];
  const float* ln1_w = (const float*)d_in[4];
  const float* ln1_b = (const float*)d_in[5];
  const float* ln2_w = (const float*)d_in[6];
  const float* ln2_b = (const float*)d_in[7];
  const float* ln3_w = (const float*)d_in[8];
  const float* ln3_b = (const float*)d_in[9];
  const float* Wq = (const float*)d_in[10];
  const float* Wkv = (const float*)d_in[11];
  const float* es_w1 = (const float*)d_in[12];
  const float* es_b1 = (const float*)d_in[13];
  const float* es_w2 = (const float*)d_in[14];
  const float* es_b2 = (const float*)d_in[15];
  const float* el_w1 = (const float*)d_in[16];
  const float* el_b1 = (const float*)d_in[17];
  const float* el_w2 = (const float*)d_in[18];
  const float* el_b2 = (const float*)d_in[19];
  const float* mlp_w1 = (const float*)d_in[20];
  const float* mlp_b1 = (const float*)d_in[21];
  const float* mlp_w2 = (const float*)d_in[22];
  const float* mlp_b2 = (const float*)d_in[23];

  float* out = (float*)d_out;
  float* sel_out  = out;
  float* topi_out = out + 1048576;
  float* pos_out  = out + 1049600;
  float* x_out    = out + 1057792;
  float* kern_out = out + 7349248;

  // ---- workspace layout (floats), peak ~252 MB ----
  float* w = (float*)d_ws;
  float* kv_f = w;                        // [0, 25165824)
  float* q_f  = w + 25165824;             // [25165824, 31457280)
  float* scores = w + 31457280;           // [31457280, 44040192)
  float* part   = w + 44040192;           // [44040192, 56623104)  16-split PV
  float* ctxf   = w + 56623104;           // [56623104, 62914560)
  // Phase 1 plane staging (dead after phase 1):
  unsigned short* xbnp = (unsigned short*)(w + 31457280);
  unsigned short* xsnp = (unsigned short*)(w + 50331648);
  unsigned short* wqp  = (unsigned short*)(w + 59768832);
  unsigned short* wkvp = (unsigned short*)(w + 60653568);
  // Phase 3/4 (FFN) overlays:
  unsigned short* ctxp = (unsigned short*)(w + 6291456);   // 18874368 us
  unsigned short* wb   = (unsigned short*)(w + 15728640);  // 42467328 us
  unsigned short* hp   = (unsigned short*)(w + 36962304);  // 37748736 us
  float* P0 = w;                                           // 6291456 fl
  const long ZS = 55836672;
  float* P1 = w + ZS;                                      // [55836672, 62128128)
  // Phase 5 overlays:
  float* xn     = w + 6291456;
  float* tokens = w + 12582912;
  float* aw     = w + 15728640;
  float* agg    = w + 17825792;
  // small block
  float* small  = w + 62914560;
  float* maskf  = small;
  float* hasf   = small + 4096;
  int* cnt      = (int*)(small + 4104);
  int* perm0    = (int*)(small + 4106);
  int* perm1    = (int*)(small + 12298);

  // weight plane sub-layout (ushort offsets in wb; wconv12 writes these)
  unsigned short* esw1h[2] = {wb + 0,        wb + 3538944};
  unsigned short* elw1h[2] = {wb + 7077888,  wb + 10616832};
  unsigned short* mlw1h[2] = {wb + 14155776, wb + 17694720};
  unsigned short* esw2h[2] = {wb + 21233664, wb + 24772608};
  unsigned short* elw2h[2] = {wb + 28311552, wb + 31850496};
  unsigned short* mlw2h[2] = {wb + 35389440, wb + 38928384};

  const long NSC = (long)NS_ * Cc_;
  const long NB2C = (long)NB_ * 2 * Cc_;
  const long SNB = (long)NS_ * NB_;
  const float qk_scale = 0.08838834764831845f;
  const float sc_scale = 0.036084391824351615f;

  hipMemsetAsync(sel_out, 0, (size_t)1048576 * sizeof(float), stream);
  hipMemsetAsync(cnt, 0, 2 * sizeof(int), stream);

  // ---- phase 1: LN->planes, weight planes, q/kv on MFMA ----
  ln_split<<<B_ * NS_, 256, 0, stream>>>(x_s, xsnp, ln1_w, ln1_b);
  ln_split<<<B_ * NB_, 256, 0, stream>>>(x_b, xbnp, ln2_w, ln2_b);
  build_perm<<<32, 256, 0, stream>>>(token_types, perm0, perm1, cnt);
  wconv<<<dim3(3, 768), 256, 0, stream>>>(Wq, wqp, 768, 768, 768, 0);
  wconv<<<dim3(3, 1536), 256, 0, stream>>>(Wkv, wkvp, 768, 1536, 1536, 0);
  mgemm<6, false, false, true><<<dim3(6, 64, 1), 256, 0, stream>>>(
      xsnp, wqp, q_f, nullptr, nullptr, nullptr, nullptr,
      8192, 768, 768, 768, 0, 1, 0, 0, 0, 1.0f);
  mgemm<6, false, false, true><<<dim3(12, 128, 1), 256, 0, stream>>>(
      xbnp, wkvp, kv_f, nullptr, nullptr, nullptr, nullptr,
      16384, 1536, 768, 1536, 0, 1, 0, 0, 0, 1.0f);

  // ---- phase 2: attention (f32 QK^T + softmax + PV split-16) ----
  for (int b = 0; b < B_; ++b) {
    const float* qb = q_f + (size_t)b * NSC;
    const float* kb = kv_f + (size_t)b * NB2C;
    const float* vb = kb + Cc_;
    gemm128<0, 1, false, false><<<dim3(16, 8, 6), 256, 0, stream>>>(
        qb, kb, scores, nullptr, nullptr, nullptr, nullptr,
        1024, 2048, 128, 768, 1536, 2048,
        1, 1, 128, 0, 0, 128, 0, 0, SNB, 0, 0, qk_scale);
    softmax_kernel<8, false><<<6 * 1024, 256, 0, stream>>>(scores, nullptr);
    // z = h*16 + ks (d1=6, d2=16): C off = h*131072 + ks*786432
    //   = (ks*6+h)*131072  -- matches pv_reduce, bijective over 12.58M fl
    gemm128<0, 0, false, false><<<dim3(1, 8, 96), 256, 0, stream>>>(
        scores, vb, part, nullptr, nullptr, nullptr, nullptr,
        1024, 128, 128, 2048, 1536, 128,
        6, 16, 0, SNB, 128, 0, 128, 128 * 1536, 0, 131072, 786432, 1.0f);
    pv_reduce<<<3072, 256, 0, stream>>>(part, ctxf + (size_t)b * NSC);
  }

  // ---- phase 3: split ctx, convert all FFN weights in one launch ----
  split_kernel<<<24576, 256, 0, stream>>>(ctxf, ctxp);
  wconv12<<<dim3(6, 1536, 12), 256, 0, stream>>>(
      es_w1, el_w1, mlp_w1, es_w2, el_w2, mlp_w2, wb);

  // ---- phase 4: MoE experts + MLP on MFMA (hidden in 2 halves) ----
  // MDEV launches: SWZ=false (early-exit tiles must stay XCD-uniform).
  for (int h = 0; h < 2; ++h) {
    mgemm<5, true, true, false><<<dim3(12, 64, 1), 256, 0, stream>>>(
        ctxp, esw1h[h], nullptr, hp, es_b1 + h * 1536, perm0, cnt,
        8192, 1536, 768, 0, 1536, 1, 0, 0, 0, 1.0f);
    if (h == 0)
      mgemm<6, false, true, false><<<dim3(6, 64, 2), 256, 0, stream>>>(
          hp, esw2h[h], P0, nullptr, nullptr, nullptr, cnt,
          8192, 768, 1536, 768, 0, 2, 0, 0, ZS, 1.0f);
    else
      mgemm<7, false, true, false><<<dim3(6, 64, 2), 256, 0, stream>>>(
          hp, esw2h[h], P0, nullptr, nullptr, nullptr, cnt,
          8192, 768, 1536, 768, 0, 2, 0, 0, ZS, 1.0f);
  }
  combineP<true><<<dim3(8192, 3), 256, 0, stream>>>(
      P0, P1, es_b2, x_s, perm0, cnt, x_out);
  for (int h = 0; h < 2; ++h) {
    mgemm<5, true, true, false><<<dim3(12, 64, 1), 256, 0, stream>>>(
        ctxp, elw1h[h], nullptr, hp, el_b1 + h * 1536, perm1, cnt + 1,
        8192, 1536, 768, 0, 1536, 1, 0, 0, 0, 1.0f);
    if (h == 0)
      mgemm<6, false, true, false><<<dim3(6, 64, 2), 256, 0, stream>>>(
          hp, elw2h[h], P0, nullptr, nullptr, nullptr, cnt + 1,
          8192, 768, 1536, 768, 0, 2, 0, 0, ZS, 1.0f);
    else
      mgemm<7, false, true, false><<<dim3(6, 64, 2), 256, 0, stream>>>(
          hp, elw2h[h], P0, nullptr, nullptr, nullptr, cnt + 1,
          8192, 768, 1536, 768, 0, 2, 0, 0, ZS, 1.0f);
  }
  combineP<true><<<dim3(8192, 3), 256, 0, stream>>>(
      P0, P1, el_b2, x_s, perm1, cnt + 1, x_out);
  ln_split<<<B_ * NS_, 256, 0, stream>>>(x_out, ctxp, ln3_w, ln3_b);
  for (int h = 0; h < 2; ++h) {
    mgemm<5, false, false, true><<<dim3(12, 64, 1), 256, 0, stream>>>(
        ctxp, mlw1h[h], nullptr, hp, mlp_b1 + h * 1536, nullptr, nullptr,
        8192, 1536, 768, 0, 1536, 1, 0, 0, 0, 1.0f);
    if (h == 0)
      mgemm<6, false, false, true><<<dim3(6, 64, 2), 256, 0, stream>>>(
          hp, mlw2h[h], P0, nullptr, nullptr, nullptr, nullptr,
          8192, 768, 1536, 768, 0, 2, 0, 0, ZS, 1.0f);
    else
      mgemm<7, false, false, true><<<dim3(6, 64, 2), 256, 0, stream>>>(
          hp, mlw2h[h], P0, nullptr, nullptr, nullptr, nullptr,
          8192, 768, 1536, 768, 0, 2, 0, 0, ZS, 1.0f);
  }
  combineP<false><<<dim3(8192, 3), 256, 0, stream>>>(
      P0, P1, mlp_b2, x_out, nullptr, nullptr, x_out);

  // ---- phase 5: scoring tail (f32) ----
  rownorm_kernel<<<B_ * NS_, 256, 0, stream>>>(x_out, xn);
  gather_kernel<<<12288, 256, 0, stream>>>(x_b, base_idxs, tokens, maskf);
  gemm128<0, 1, false, false><<<dim3(4, 4, 8), 256, 0, stream>>>(
      tokens, tokens, aw, nullptr, nullptr, nullptr, nullptr,
      512, 512, 768, 768, 768, 512,
      1, 1, 393216, 0, 0, 393216, 0, 0, 262144, 0, 0, sc_scale);
  softmax_kernel<2, true><<<8 * 512, 256, 0, stream>>>(aw, maskf);
  gemm128<0, 0, false, false><<<dim3(6, 4, 8), 256, 0, stream>>>(
      aw, tokens, agg, nullptr, nullptr, nullptr, nullptr,
      512, 768, 512, 512, 768, 768,
      1, 1, 262144, 0, 0, 393216, 0, 0, 393216, 0, 0, 1.0f);
  kernel_kernel<<<8, 256, 0, stream>>>(agg, maskf, kern_out, hasf);
  pos_kernel<<<B_ * NS_, 256, 0, stream>>>(xn, kern_out, hasf, pos_out);
  topk_kernel<<<8, 256, 0, stream>>>(pos_out, sel_out, topi_out);
}

// Round 15
// 3169.449 us; speedup vs baseline: 1.1993x; 1.0093x over previous
//
#include <hip/hip_runtime.h>
#include <hip/hip_bf16.h>
#include <math.h>

// Problem constants
#define B_   8
#define NB_  2048
#define NS_  1024
#define Cc_  768
#define HID_ 3072
#define NP_  1024
#define NH_  6
#define HD_  128

__device__ __forceinline__ float gelu_exact(float v) {
  return 0.5f * v * (1.0f + erff(v * 0.7071067811865476f));
}

// split f32 into 3 bf16 planes (truncation; dropped residual ~2^-24 rel)
__device__ __forceinline__ void split3(float v, unsigned short& h,
                                       unsigned short& m, unsigned short& l) {
  unsigned hb = __float_as_uint(v) & 0xffff0000u;
  float r1 = v - __uint_as_float(hb);
  unsigned mb = __float_as_uint(r1) & 0xffff0000u;
  float r2 = r1 - __uint_as_float(mb);
  unsigned lb = __float_as_uint(r2) & 0xffff0000u;
  h = (unsigned short)(hb >> 16);
  m = (unsigned short)(mb >> 16);
  l = (unsigned short)(lb >> 16);
}

typedef short bf16x8 __attribute__((ext_vector_type(8)));
typedef float f32x4 __attribute__((ext_vector_type(4)));

#define BLOCK_REDUCE_ADD(red, tid)                                              \
  for (int off_ = 128; off_; off_ >>= 1) {                                      \
    if ((tid) < off_) red[(tid)] += red[(tid) + off_];                          \
    __syncthreads();                                                            \
  }

// ------- merged LayerNorm -> 3 bf16 planes for x_s (rows<8192) and x_b -----
__global__ __launch_bounds__(256) void ln_split2(
    const float* __restrict__ xs, const float* __restrict__ xb,
    unsigned short* __restrict__ ys, unsigned short* __restrict__ yb,
    const float* __restrict__ w1, const float* __restrict__ b1,
    const float* __restrict__ w2, const float* __restrict__ b2) {
  __shared__ float red[256];
  int row = blockIdx.x, tid = threadIdx.x;
  const float* xr;
  unsigned short* yr;
  const float* w;
  const float* b;
  if (row < 8192) {
    xr = xs + (size_t)row * Cc_;
    yr = ys + (size_t)row * 2304;
    w = w1; b = b1;
  } else {
    int r2 = row - 8192;
    xr = xb + (size_t)r2 * Cc_;
    yr = yb + (size_t)r2 * 2304;
    w = w2; b = b2;
  }
  float v0 = xr[tid], v1 = xr[tid + 256], v2 = xr[tid + 512];
  red[tid] = v0 + v1 + v2;
  __syncthreads();
  BLOCK_REDUCE_ADD(red, tid);
  float mu = red[0] / (float)Cc_;
  __syncthreads();
  float d0 = v0 - mu, d1 = v1 - mu, d2 = v2 - mu;
  red[tid] = d0 * d0 + d1 * d1 + d2 * d2;
  __syncthreads();
  BLOCK_REDUCE_ADD(red, tid);
  float var = red[0] / (float)Cc_;
  float rs = 1.0f / sqrtf(var + 1e-5f);
  float vals[3] = {d0 * rs * w[tid] + b[tid],
                   d1 * rs * w[tid + 256] + b[tid + 256],
                   d2 * rs * w[tid + 512] + b[tid + 512]};
#pragma unroll
  for (int t = 0; t < 3; ++t) {
    int c = tid + (t << 8);
    unsigned short h16, m16, l16;
    split3(vals[t], h16, m16, l16);
    yr[c] = h16; yr[768 + c] = m16; yr[1536 + c] = l16;
  }
}

// ---------------- LayerNorm -> 3 bf16 planes (single src) ----------------
__global__ __launch_bounds__(256) void ln_split(
    const float* __restrict__ x, unsigned short* __restrict__ y,
    const float* __restrict__ w, const float* __restrict__ b) {
  __shared__ float red[256];
  int row = blockIdx.x, tid = threadIdx.x;
  const float* xr = x + (size_t)row * Cc_;
  float v0 = xr[tid], v1 = xr[tid + 256], v2 = xr[tid + 512];
  red[tid] = v0 + v1 + v2;
  __syncthreads();
  BLOCK_REDUCE_ADD(red, tid);
  float mu = red[0] / (float)Cc_;
  __syncthreads();
  float d0 = v0 - mu, d1 = v1 - mu, d2 = v2 - mu;
  red[tid] = d0 * d0 + d1 * d1 + d2 * d2;
  __syncthreads();
  BLOCK_REDUCE_ADD(red, tid);
  float var = red[0] / (float)Cc_;
  float rs = 1.0f / sqrtf(var + 1e-5f);
  unsigned short* yr = y + (size_t)row * 2304;
  float vals[3] = {d0 * rs * w[tid] + b[tid],
                   d1 * rs * w[tid + 256] + b[tid + 256],
                   d2 * rs * w[tid + 512] + b[tid + 512]};
#pragma unroll
  for (int t = 0; t < 3; ++t) {
    int c = tid + (t << 8);
    unsigned short h16, m16, l16;
    split3(vals[t], h16, m16, l16);
    yr[c] = h16; yr[768 + c] = m16; yr[1536 + c] = l16;
  }
}

// ---------------- f32 [8192][768] -> 3 bf16 planes ----------------
__global__ __launch_bounds__(256) void split_kernel(
    const float* __restrict__ x, unsigned short* __restrict__ y) {
  size_t idx = (size_t)blockIdx.x * 256 + threadIdx.x;  // < 8192*768
  int c = (int)(idx % Cc_);
  int row = (int)(idx / Cc_);
  unsigned short h16, m16, l16;
  split3(x[idx], h16, m16, l16);
  unsigned short* yr = y + (size_t)row * 2304;
  yr[c] = h16; yr[768 + c] = m16; yr[1536 + c] = l16;
}

// ------- merged Wq+Wkv plane convert: z=0 Wq(768 cols), z=1 Wkv(1536) ------
__global__ __launch_bounds__(256) void wconv2(
    const float* __restrict__ Wq, const float* __restrict__ Wkv,
    unsigned short* __restrict__ wqp, unsigned short* __restrict__ wkvp) {
  int z = blockIdx.z;
  int k = blockIdx.x * 256 + threadIdx.x;  // < 768
  int n = blockIdx.y;
  const float* W;
  unsigned short* out;
  int ldw;
  if (z == 0) {
    if (n >= 768) return;
    W = Wq; out = wqp; ldw = 768;
  } else {
    W = Wkv; out = wkvp; ldw = 1536;
  }
  float v = W[(size_t)k * ldw + n];
  unsigned short h16, m16, l16;
  split3(v, h16, m16, l16);
  size_t base = (size_t)n * 2304;
  out[base + k] = h16;
  out[base + 768 + k] = m16;
  out[base + 1536 + k] = l16;
}

// --------- mega weight convert: all 12 FFN plane jobs in one launch --------
__global__ __launch_bounds__(256) void wconv12(
    const float* __restrict__ w1a, const float* __restrict__ w1b,
    const float* __restrict__ w1c, const float* __restrict__ w2a,
    const float* __restrict__ w2b, const float* __restrict__ w2c,
    unsigned short* __restrict__ wb) {
  int z = blockIdx.z;
  int k = blockIdx.x * 256 + threadIdx.x;
  int n = blockIdx.y;
  const float* W;
  int K, ldw, ncol0;
  size_t out_off;
  if (z < 6) {
    K = 768; ldw = 3072;
    int m = z >> 1, h = z & 1;
    W = (m == 0) ? w1a : ((m == 1) ? w1b : w1c);
    ncol0 = h * 1536;
    out_off = (size_t)m * 7077888 + (size_t)h * 3538944;
    if (k >= 768) return;
  } else {
    K = 1536; ldw = 768; ncol0 = 0;
    int m = (z - 6) >> 1, h = z & 1;
    W = ((m == 0) ? w2a : ((m == 1) ? w2b : w2c)) + (size_t)h * 1536 * 768;
    out_off = 21233664 + (size_t)m * 7077888 + (size_t)h * 3538944;
    if (n >= 768) return;
  }
  float v = W[(size_t)k * ldw + ncol0 + n];
  unsigned short h16, m16, l16;
  split3(v, h16, m16, l16);
  size_t base = out_off + (size_t)n * 3 * K;
  wb[base + k] = h16;
  wb[base + K + k] = m16;
  wb[base + 2 * K + k] = l16;
}

// ---------------- MFMA GEMM over 3-split bf16 planes ----------------
// (unchanged from R14; SWZ must be false for MDEV launches — R12 lesson)
template <int EPI, bool AGATHER, bool MDEV, bool SWZ>
__global__ __launch_bounds__(256) void mgemm(
    const unsigned short* __restrict__ Ap, const unsigned short* __restrict__ Bp,
    float* __restrict__ Cf, unsigned short* __restrict__ Cs,
    const float* __restrict__ bias,
    const int* __restrict__ perm, const int* __restrict__ mdev,
    int M, int N, int K, int ldc, int Kout, int nsplit,
    long azs, long bzs, long zstride, float scale) {
  __shared__ unsigned short As[2][8192];
  __shared__ unsigned short Bs[2][8192];
  int z = blockIdx.z;
  int bx, by;
  if (SWZ) {
    int gx = gridDim.x;
    int id = blockIdx.y * gx + blockIdx.x;
    int per = (gx * gridDim.y) >> 3;
    int nid = (id & 7) * per + (id >> 3);
    bx = nid % gx; by = nid / gx;
  } else {
    bx = blockIdx.x; by = blockIdx.y;
  }
  int Me = MDEV ? mdev[0] : M;
  int m0 = by * 128, n0 = bx * 128;
  if (MDEV && m0 >= Me) return;
  const unsigned short* ApB = Ap + (size_t)z * azs;
  const unsigned short* BpB = Bp + (size_t)z * bzs;
  int tid = threadIdx.x;
  int lane = tid & 63, w = tid >> 6;
  int wr = w >> 1, wc = w & 1;
  int K3 = 3 * K;
  int tps = K >> 6;
  int KT = 6 * tps;
  int span = KT / nsplit;
  int zr = z % nsplit;
  int tt0 = zr * span, tt1 = tt0 + span;

  const unsigned short* agp[4];
  const unsigned short* bgp[4];
  int wswz[4];
#pragma unroll
  for (int p = 0; p < 4; ++p) {
    int r = (tid >> 3) + 32 * p;
    int ma = m0 + r;
    if (MDEV) ma = min(ma, Me - 1);
    if (AGATHER) ma = perm[ma];
    agp[p] = ApB + (size_t)ma * K3 + (tid & 7) * 8;
    bgp[p] = BpB + (size_t)(n0 + r) * K3 + (tid & 7) * 8;
    wswz[p] = r * 64 + (((tid & 7) ^ (r & 7)) << 3);
  }

  f32x4 acc[4][4];
  f32x4 zero4 = {0.f, 0.f, 0.f, 0.f};
#pragma unroll
  for (int i = 0; i < 4; ++i)
#pragma unroll
    for (int j = 0; j < 4; ++j) acc[i][j] = zero4;

  int kg = lane >> 4;
  int frm[4], frn[4];
#pragma unroll
  for (int f = 0; f < 4; ++f) {
    frm[f] = wr * 64 + f * 16 + (lane & 15);
    frn[f] = wc * 64 + f * 16 + (lane & 15);
  }

  bf16x8 ra[4], rb[4];
  {
    int seg = tt0 / tps, kt = tt0 - seg * tps;
    int pa = (0x210100u >> (4 * seg)) & 0xF;
    int pb = (0x012010u >> (4 * seg)) & 0xF;
    size_t ao = (size_t)(pa * K + kt * 64);
    size_t bo = (size_t)(pb * K + kt * 64);
#pragma unroll
    for (int p = 0; p < 4; ++p) {
      ra[p] = *(const bf16x8*)(agp[p] + ao);
      rb[p] = *(const bf16x8*)(bgp[p] + bo);
    }
  }

  for (int tt = tt0; tt < tt1; ++tt) {
    int cur = tt & 1;
#pragma unroll
    for (int p = 0; p < 4; ++p) {
      *(bf16x8*)&As[cur][wswz[p]] = ra[p];
      *(bf16x8*)&Bs[cur][wswz[p]] = rb[p];
    }
    if (tt + 1 < tt1) {
      int seg = (tt + 1) / tps, kt = (tt + 1) - seg * tps;
      int pa = (0x210100u >> (4 * seg)) & 0xF;
      int pb = (0x012010u >> (4 * seg)) & 0xF;
      size_t ao = (size_t)(pa * K + kt * 64);
      size_t bo = (size_t)(pb * K + kt * 64);
#pragma unroll
      for (int p = 0; p < 4; ++p) {
        ra[p] = *(const bf16x8*)(agp[p] + ao);
        rb[p] = *(const bf16x8*)(bgp[p] + bo);
      }
    }
    asm volatile("s_waitcnt lgkmcnt(0)" ::: "memory");
    __builtin_amdgcn_s_barrier();
#pragma unroll
    for (int ks = 0; ks < 2; ++ks) {
      int ch = ks * 4 + kg;
      bf16x8 af[4], bf[4];
#pragma unroll
      for (int f = 0; f < 4; ++f) {
        int r = frm[f];
        af[f] = *(const bf16x8*)&As[cur][r * 64 + ((ch ^ (r & 7)) << 3)];
      }
#pragma unroll
      for (int f = 0; f < 4; ++f) {
        int r = frn[f];
        bf[f] = *(const bf16x8*)&Bs[cur][r * 64 + ((ch ^ (r & 7)) << 3)];
      }
#pragma unroll
      for (int i = 0; i < 4; ++i)
#pragma unroll
        for (int j = 0; j < 4; ++j)
          acc[i][j] = __builtin_amdgcn_mfma_f32_16x16x32_bf16(
              af[i], bf[j], acc[i][j], 0, 0, 0);
    }
  }

  // epilogue: C/D layout col=lane&15, row=(lane>>4)*4+reg (m89-verified)
#pragma unroll
  for (int i = 0; i < 4; ++i) {
#pragma unroll
    for (int r = 0; r < 4; ++r) {
      int m = m0 + wr * 64 + i * 16 + kg * 4 + r;
      if (MDEV && m >= Me) continue;
#pragma unroll
      for (int j = 0; j < 4; ++j) {
        int n = n0 + wc * 64 + j * 16 + (lane & 15);
        float v = acc[i][j][r] * scale;
        if (EPI == 6) {
          Cf[(size_t)z * zstride + (size_t)m * ldc + n] = v;
        } else if (EPI == 7) {
          Cf[(size_t)z * zstride + (size_t)m * ldc + n] += v;
        } else if (EPI == 5) {
          float t = gelu_exact(v + bias[n]);
          unsigned short h16, m16, l16;
          split3(t, h16, m16, l16);
          size_t base = (size_t)m * 3 * Kout;
          Cs[base + n] = h16;
          Cs[base + Kout + n] = m16;
          Cs[base + 2 * Kout + n] = l16;
        }
      }
    }
  }
}

// ---------------- combine partials: out = bias + addsrc + P0 + P1 ----------
template <bool SCATTER>
__global__ __launch_bounds__(256) void combineP(
    const float* __restrict__ P0, const float* __restrict__ P1,
    const float* __restrict__ bias, const float* __restrict__ addsrc,
    const int* __restrict__ perm, const int* __restrict__ cnt,
    float* __restrict__ out) {
  int m = blockIdx.x;
  int c = threadIdx.x + (blockIdx.y << 8);
  if (SCATTER && m >= cnt[0]) return;
  int mo = SCATTER ? perm[m] : m;
  size_t pm = (size_t)m * 768 + c;
  out[(size_t)mo * 768 + c] =
      bias[c] + addsrc[(size_t)mo * 768 + c] + P0[pm] + P1[pm];
}

// ----- fused final combine + rownorm: x = bias+x+P0+P1; xn = x/||x|| -------
__global__ __launch_bounds__(256) void combine_norm(
    const float* __restrict__ P0, const float* __restrict__ P1,
    const float* __restrict__ bias, float* __restrict__ x,
    float* __restrict__ xn) {
  __shared__ float red[256];
  int m = blockIdx.x, tid = threadIdx.x;
  size_t rb = (size_t)m * 768;
  float v[3];
  float s2 = 0.f;
#pragma unroll
  for (int t = 0; t < 3; ++t) {
    int c = tid + (t << 8);
    v[t] = bias[c] + x[rb + c] + P0[rb + c] + P1[rb + c];
    s2 = fmaf(v[t], v[t], s2);
  }
  red[tid] = s2;
  __syncthreads();
  BLOCK_REDUCE_ADD(red, tid);
  float den = fmaxf(sqrtf(red[0]), 1e-12f);
  float inv = 1.0f / den;
#pragma unroll
  for (int t = 0; t < 3; ++t) {
    int c = tid + (t << 8);
    x[rb + c] = v[t];
    xn[rb + c] = v[t] * inv;
  }
}

// ---------------- f32 GEMM (R5: 128x128, 8x8, reg-prefetch dbuf) ----------
template <int EPI, int TRB, bool AGATHER, bool MDEV>
__global__ __launch_bounds__(256) void gemm128(
    const float* __restrict__ A, const float* __restrict__ Bm,
    float* __restrict__ Cm, const float* __restrict__ bias,
    const float* __restrict__ addsrc, const int* __restrict__ perm,
    const int* __restrict__ mdev,
    int M, int N, int K, int lda, int ldb, int ldc,
    int d1, int d2,
    long a_s1, long a_s2, long a_s3,
    long b_s1, long b_s2, long b_s3,
    long c_s1, long c_s2, long c_s3,
    float scale) {
  __shared__ float As[2][16][132];
  __shared__ float Bs[2][16][132];
  int z = blockIdx.z;
  int z1 = z / (d1 * d2);
  int rem = z - z1 * d1 * d2;
  int z2 = rem / d2, z3 = rem - z2 * d2;
  const float* Ab = A + (size_t)z1 * a_s1 + (size_t)z2 * a_s2 + (size_t)z3 * a_s3;
  const float* Bb = Bm + (size_t)z1 * b_s1 + (size_t)z2 * b_s2 + (size_t)z3 * b_s3;
  float* Cb = Cm + (size_t)z1 * c_s1 + (size_t)z2 * c_s2 + (size_t)z3 * c_s3;
  int Me = MDEV ? mdev[0] : M;
  int m0 = blockIdx.y * 128, n0 = blockIdx.x * 128;
  if (MDEV && m0 >= Me) return;
  int tid = threadIdx.x;
  int tx = tid & 15, ty = tid >> 4;
  int arow = tid >> 2, akq = tid & 3;
  int ma0 = m0 + arow, ma1 = m0 + arow + 64;
  if (MDEV) { ma0 = min(ma0, Me - 1); ma1 = min(ma1, Me - 1); }
  if (AGATHER) { ma0 = perm[ma0]; ma1 = perm[ma1]; }
  const float* Ap0 = Ab + (size_t)ma0 * lda + akq * 4;
  const float* Ap1 = Ab + (size_t)ma1 * lda + akq * 4;
  const float* Bp0;
  const float* Bp1;
  int bw_r0 = 0, bw_c0 = 0, bw_r1 = 0;
  if (TRB == 0) {
    bw_r0 = tid >> 5; bw_c0 = (tid & 31) * 4; bw_r1 = bw_r0 + 8;
    Bp0 = Bb + (size_t)bw_r0 * ldb + n0 + bw_c0;
    Bp1 = Bb + (size_t)bw_r1 * ldb + n0 + bw_c0;
  } else {
    Bp0 = Bb + (size_t)(n0 + arow) * ldb + akq * 4;
    Bp1 = Bb + (size_t)(n0 + arow + 64) * ldb + akq * 4;
  }
  float4 pa0 = *(const float4*)Ap0;
  float4 pa1 = *(const float4*)Ap1;
  float4 pb0 = *(const float4*)Bp0;
  float4 pb1 = *(const float4*)Bp1;
  float acc[8][8] = {};
  int nt = K >> 4;
  for (int t = 0; t < nt; ++t) {
    int cur = t & 1;
    As[cur][akq * 4 + 0][arow] = pa0.x; As[cur][akq * 4 + 1][arow] = pa0.y;
    As[cur][akq * 4 + 2][arow] = pa0.z; As[cur][akq * 4 + 3][arow] = pa0.w;
    As[cur][akq * 4 + 0][arow + 64] = pa1.x; As[cur][akq * 4 + 1][arow + 64] = pa1.y;
    As[cur][akq * 4 + 2][arow + 64] = pa1.z; As[cur][akq * 4 + 3][arow + 64] = pa1.w;
    if (TRB == 0) {
      *(float4*)&Bs[cur][bw_r0][bw_c0] = pb0;
      *(float4*)&Bs[cur][bw_r1][bw_c0] = pb1;
    } else {
      Bs[cur][akq * 4 + 0][arow] = pb0.x; Bs[cur][akq * 4 + 1][arow] = pb0.y;
      Bs[cur][akq * 4 + 2][arow] = pb0.z; Bs[cur][akq * 4 + 3][arow] = pb0.w;
      Bs[cur][akq * 4 + 0][arow + 64] = pb1.x; Bs[cur][akq * 4 + 1][arow + 64] = pb1.y;
      Bs[cur][akq * 4 + 2][arow + 64] = pb1.z; Bs[cur][akq * 4 + 3][arow + 64] = pb1.w;
    }
    if (t + 1 < nt) {
      int kn = (t + 1) << 4;
      pa0 = *(const float4*)&Ap0[kn];
      pa1 = *(const float4*)&Ap1[kn];
      if (TRB == 0) {
        pb0 = *(const float4*)&Bp0[(size_t)kn * ldb];
        pb1 = *(const float4*)&Bp1[(size_t)kn * ldb];
      } else {
        pb0 = *(const float4*)&Bp0[kn];
        pb1 = *(const float4*)&Bp1[kn];
      }
    }
    asm volatile("s_waitcnt lgkmcnt(0)" ::: "memory");
    __builtin_amdgcn_s_barrier();
#pragma unroll
    for (int kk = 0; kk < 16; ++kk) {
      float a[8], b[8];
      *(float4*)&a[0] = *(const float4*)&As[cur][kk][ty * 4];
      *(float4*)&a[4] = *(const float4*)&As[cur][kk][ty * 4 + 64];
      *(float4*)&b[0] = *(const float4*)&Bs[cur][kk][tx * 4];
      *(float4*)&b[4] = *(const float4*)&Bs[cur][kk][tx * 4 + 64];
#pragma unroll
      for (int i = 0; i < 8; ++i)
#pragma unroll
        for (int j = 0; j < 8; ++j)
          acc[i][j] = fmaf(a[i], b[j], acc[i][j]);
    }
  }
#pragma unroll
  for (int i = 0; i < 8; ++i) {
    int m = m0 + ((i < 4) ? (ty * 4 + i) : (64 + ty * 4 + i - 4));
    if (!MDEV || m < Me) {
      int mo = (EPI == 4) ? perm[m] : m;
      int n = n0 + tx * 4;
      float v[8];
#pragma unroll
      for (int j = 0; j < 8; ++j) {
        int nj = (j < 4) ? (n + j) : (n + 64 + j - 4);
        v[j] = acc[i][j] * scale;
        if (EPI >= 1) v[j] += bias[nj];
        if (EPI == 2) v[j] = gelu_exact(v[j]);
        if (EPI == 3 || EPI == 4) v[j] += addsrc[(size_t)mo * ldc + nj];
      }
      float* cp = &Cb[(size_t)mo * ldc + n];
      *(float4*)cp = make_float4(v[0], v[1], v[2], v[3]);
      *(float4*)(cp + 64) = make_float4(v[4], v[5], v[6], v[7]);
    }
  }
}

// ---------------- PV split-K(16) reduce -> f32 ctx ----------------
__global__ __launch_bounds__(256) void pv_reduce(
    const float* __restrict__ part, float* __restrict__ ctx) {
  int i = blockIdx.x * 256 + threadIdx.x;
  int n = i & 127, m = (i >> 7) & 1023, h = i >> 17;
  float s = 0.f;
#pragma unroll
  for (int ks = 0; ks < 16; ++ks)
    s += part[(size_t)(ks * 6 + h) * 131072 + m * 128 + n];
  ctx[(size_t)m * 768 + h * 128 + n] = s;
}

// ---------------- Softmax (native exp, hoisted reciprocal) ----------------
template <int EPT, bool MASK>
__global__ __launch_bounds__(256) void softmax_kernel(
    float* __restrict__ s, const float* __restrict__ maskf) {
  __shared__ float red[256];
  int row = blockIdx.x, tid = threadIdx.x;
  float* sr = s + (size_t)row * (EPT * 256);
  const float* mb = MASK ? (maskf + (size_t)(row / 512) * 512) : nullptr;
  float v[EPT];
  float m = -3.0e38f;
#pragma unroll
  for (int t = 0; t < EPT; ++t) {
    int j = tid + (t << 8);
    float xv = sr[j];
    if (MASK) xv += (mb[j] != 0.0f) ? 0.0f : -1e9f;
    v[t] = xv;
    m = fmaxf(m, xv);
  }
  red[tid] = m;
  __syncthreads();
  for (int off = 128; off; off >>= 1) {
    if (tid < off) red[tid] = fmaxf(red[tid], red[tid + off]);
    __syncthreads();
  }
  m = red[0];
  __syncthreads();
  float ssum = 0.f;
#pragma unroll
  for (int t = 0; t < EPT; ++t) {
    v[t] = __expf(v[t] - m);
    ssum += v[t];
  }
  red[tid] = ssum;
  __syncthreads();
  BLOCK_REDUCE_ADD(red, tid);
  float inv = 1.0f / red[0];
#pragma unroll
  for (int t = 0; t < EPT; ++t) sr[tid + (t << 8)] = v[t] * inv;
}

// ---------------- MoE permutation build ----------------
__global__ __launch_bounds__(256) void build_perm(
    const int* __restrict__ tt, int* __restrict__ perm0,
    int* __restrict__ perm1, int* __restrict__ cnt) {
  int r = blockIdx.x * 256 + threadIdx.x;
  int t = tt[r];
  if (t == 0) { int p = atomicAdd(&cnt[0], 1); perm0[p] = r; }
  else        { int p = atomicAdd(&cnt[1], 1); perm1[p] = r; }
}

// ---------------- Token gather ----------------
__global__ __launch_bounds__(256) void gather_kernel(
    const float* __restrict__ xb, const int* __restrict__ bidx,
    float* __restrict__ tokens, float* __restrict__ maskf) {
  size_t idx = (size_t)blockIdx.x * 256 + threadIdx.x;
  int c = (int)(idx % Cc_);
  int i = (int)((idx / Cc_) % 512);
  int b = (int)(idx / ((size_t)Cc_ * 512));
  int id = bidx[b * NP_ + i];
  bool m = id >= 0;
  int idc = m ? id : 0;
  tokens[idx] = m ? xb[((size_t)b * NB_ + idc) * Cc_ + c] : 0.0f;
  if (c == 0) maskf[b * 512 + i] = m ? 1.0f : 0.0f;
}

// ---------------- ksum -> kernel ----------------
__global__ __launch_bounds__(256) void kernel_kernel(
    const float* __restrict__ agg, const float* __restrict__ maskf,
    float* __restrict__ kern, float* __restrict__ hasf) {
  __shared__ float red[256];
  __shared__ float ks[Cc_];
  __shared__ float s_cnt;
  int b = blockIdx.x, tid = threadIdx.x;
  const float* mb = maskf + b * 512;
  red[tid] = mb[tid] + mb[tid + 256];
  __syncthreads();
  BLOCK_REDUCE_ADD(red, tid);
  if (tid == 0) s_cnt = red[0];
  __syncthreads();
  float cnt = s_cnt;
  float dc = fmaxf(cnt, 1.0f);
  const float* ab = agg + (size_t)b * 512 * Cc_;
#pragma unroll
  for (int t = 0; t < 3; ++t) {
    int cc = tid + t * 256;
    float s = 0.f;
    for (int i = 0; i < 512; ++i) s = fmaf(ab[(size_t)i * Cc_ + cc], mb[i], s);
    ks[cc] = s / dc;
  }
  __syncthreads();
  float s2 = 0.f;
#pragma unroll
  for (int t = 0; t < 3; ++t) {
    float q = ks[tid + t * 256];
    s2 = fmaf(q, q, s2);
  }
  red[tid] = s2;
  __syncthreads();
  BLOCK_REDUCE_ADD(red, tid);
  float den = fmaxf(sqrtf(red[0]), 1e-12f);
  bool has = cnt > 0.5f;
#pragma unroll
  for (int t = 0; t < 3; ++t) {
    int cc = tid + t * 256;
    kern[(size_t)b * Cc_ + cc] = has ? (ks[cc] / den) : 0.0f;
  }
  if (tid == 0) hasf[b] = has ? 1.0f : 0.0f;
}

// ---------------- pos ----------------
__global__ __launch_bounds__(256) void pos_kernel(
    const float* __restrict__ xnorm, const float* __restrict__ kern,
    const float* __restrict__ hasf, float* __restrict__ pos) {
  __shared__ float red[256];
  int row = blockIdx.x, tid = threadIdx.x;
  int b = row >> 10;
  const float* xr = xnorm + (size_t)row * Cc_;
  const float* kr = kern + (size_t)b * Cc_;
  float s = xr[tid] * kr[tid];
  s = fmaf(xr[tid + 256], kr[tid + 256], s);
  s = fmaf(xr[tid + 512], kr[tid + 512], s);
  red[tid] = s;
  __syncthreads();
  BLOCK_REDUCE_ADD(red, tid);
  if (tid == 0) pos[row] = (hasf[b] > 0.5f) ? (red[0] + 1.0f) * 0.5f : 0.0f;
}

// ---------------- per-batch top-128 via bitonic sort ----------------
__global__ __launch_bounds__(256) void topk_kernel(
    const float* __restrict__ pos, float* __restrict__ sel,
    float* __restrict__ topi) {
  __shared__ float sv[NS_];
  __shared__ int si[NS_];
  __shared__ int red[256];
  __shared__ int s_vk;
  int b = blockIdx.x, tid = threadIdx.x;
  const float* pr = pos + (size_t)b * NS_;
  int c65 = 0;
#pragma unroll
  for (int t = 0; t < 4; ++t) {
    int i = tid + (t << 8);
    float v = pr[i];
    sv[i] = v; si[i] = i;
    if (v > 0.65f) ++c65;
  }
  red[tid] = c65;
  __syncthreads();
  for (int off = 128; off; off >>= 1) {
    if (tid < off) red[tid] += red[tid + off];
    __syncthreads();
  }
  if (tid == 0) {
    int vk = red[0] > 118 ? red[0] : 118;
    s_vk = vk > 128 ? 128 : vk;
  }
  for (int k = 2; k <= NS_; k <<= 1) {
    for (int j = k >> 1; j > 0; j >>= 1) {
      __syncthreads();
#pragma unroll
      for (int t = 0; t < 4; ++t) {
        int i = tid + (t << 8);
        int l = i ^ j;
        if (l > i) {
          bool up = ((i & k) == 0);
          float vi = sv[i], vl = sv[l];
          int ii = si[i], il = si[l];
          bool gt = (vi < vl) || (vi == vl && ii > il);
          if (up == gt) {
            sv[i] = vl; sv[l] = vi;
            si[i] = il; si[l] = ii;
          }
        }
      }
    }
  }
  __syncthreads();
  if (tid < 128) {
    int wi = si[tid];
    float wv = sv[tid];
    topi[(size_t)b * 128 + tid] = (float)wi;
    if (tid < s_vk && wv > 0.0f) sel[((size_t)b * 128 + tid) * NS_ + wi] = 1.0f;
  }
}

extern "C" void kernel_launch(void* const* d_in, const int* in_sizes, int n_in,
                              void* d_out, int out_size, void* d_ws, size_t ws_size,
                              hipStream_t stream) {
  (void)in_sizes; (void)n_in; (void)out_size; (void)ws_size;
  const float* x_b = (const float*)d_in[0];
  const float* x_s = (const float*)d_in[1];
  const int* token_types = (const int*)d_in[2];
  const int* base_idxs = (const int*)d_in[3];
  const float* ln1_w = (const float*)d_in[4];
  const float* ln1_b = (const float*)d_in[5];
  const float* ln2_w = (const float*)d_in[6];
  const float* ln2_b = (const float*)d_in[7];
  const float* ln3_w = (const float*)d_in[8];
  const float* ln3_b = (const float*)d_in[9];
  const float* Wq = (const float*)d_in[10];
  const float* Wkv = (const float*)d_in[11];
  const float* es_w1 = (const float*)d_in[12];
  const float* es_b1 = (const float*)d_in[13];
  const float* es_w2 = (const float*)d_in[14];
  const float* es_b2 = (const float*)d_in[15];
  const float* el_w1 = (const float*)d_in[16];
  const float* el_b1 = (const float*)d_in[17];
  const float* el_w2 = (const float*)d_in[18];
  const float* el_b2 = (const float*)d_in[19];
  const float* mlp_w1 = (const float*)d_in[20];
  const float* mlp_b1 = (const float*)d_in[21];
  const float* mlp_w2 = (const float*)d_in[22];
  const float* mlp_b2 = (const float*)d_in[23];

  float* out = (float*)d_out;
  float* sel_out  = out;
  float* topi_out = out + 1048576;
  float* pos_out  = out + 1049600;
  float* x_out    = out + 1057792;
  float* kern_out = out + 7349248;

  // ---- workspace layout (floats), peak ~252 MB ----
  float* w = (float*)d_ws;
  float* kv_f = w;                        // [0, 25165824)
  float* q_f  = w + 25165824;             // [25165824, 31457280)
  float* scores = w + 31457280;           // [31457280, 44040192)
  float* part   = w + 44040192;           // [44040192, 56623104)  16-split PV
  float* ctxf   = w + 56623104;           // [56623104, 62914560)
  // Phase 1 plane staging (dead after phase 1):
  unsigned short* xbnp = (unsigned short*)(w + 31457280);
  unsigned short* xsnp = (unsigned short*)(w + 50331648);
  unsigned short* wqp  = (unsigned short*)(w + 59768832);
  unsigned short* wkvp = (unsigned short*)(w + 60653568);
  // Phase 3/4 (FFN) overlays:
  unsigned short* ctxp = (unsigned short*)(w + 6291456);   // 18874368 us
  unsigned short* wb   = (unsigned short*)(w + 15728640);  // 42467328 us
  unsigned short* hp   = (unsigned short*)(w + 36962304);  // 37748736 us
  float* P0 = w;                                           // 6291456 fl
  const long ZS = 55836672;
  float* P1 = w + ZS;                                      // [55836672, 62128128)
  // Phase 5 overlays:
  float* xn     = w + 6291456;
  float* tokens = w + 12582912;
  float* aw     = w + 15728640;
  float* agg    = w + 17825792;
  // small block
  float* small  = w + 62914560;
  float* maskf  = small;
  float* hasf   = small + 4096;
  int* cnt      = (int*)(small + 4104);
  int* perm0    = (int*)(small + 4106);
  int* perm1    = (int*)(small + 12298);

  // weight plane sub-layout (ushort offsets in wb; wconv12 writes these)
  unsigned short* esw1h[2] = {wb + 0,        wb + 3538944};
  unsigned short* elw1h[2] = {wb + 7077888,  wb + 10616832};
  unsigned short* mlw1h[2] = {wb + 14155776, wb + 17694720};
  unsigned short* esw2h[2] = {wb + 21233664, wb + 24772608};
  unsigned short* elw2h[2] = {wb + 28311552, wb + 31850496};
  unsigned short* mlw2h[2] = {wb + 35389440, wb + 38928384};

  const long NSC = (long)NS_ * Cc_;
  const long NB2C = (long)NB_ * 2 * Cc_;
  const long SNB = (long)NS_ * NB_;
  const float qk_scale = 0.08838834764831845f;
  const float sc_scale = 0.036084391824351615f;

  hipMemsetAsync(sel_out, 0, (size_t)1048576 * sizeof(float), stream);
  hipMemsetAsync(cnt, 0, 2 * sizeof(int), stream);

  // ---- phase 1: LN->planes (merged), weight planes (merged), q/kv MFMA ----
  ln_split2<<<24576, 256, 0, stream>>>(x_s, x_b, xsnp, xbnp,
                                       ln1_w, ln1_b, ln2_w, ln2_b);
  build_perm<<<32, 256, 0, stream>>>(token_types, perm0, perm1, cnt);
  wconv2<<<dim3(3, 1536, 2), 256, 0, stream>>>(Wq, Wkv, wqp, wkvp);
  mgemm<6, false, false, true><<<dim3(6, 64, 1), 256, 0, stream>>>(
      xsnp, wqp, q_f, nullptr, nullptr, nullptr, nullptr,
      8192, 768, 768, 768, 0, 1, 0, 0, 0, 1.0f);
  mgemm<6, false, false, true><<<dim3(12, 128, 1), 256, 0, stream>>>(
      xbnp, wkvp, kv_f, nullptr, nullptr, nullptr, nullptr,
      16384, 1536, 768, 1536, 0, 1, 0, 0, 0, 1.0f);

  // ---- phase 2: attention (f32 QK^T + softmax + PV split-16) ----
  for (int b = 0; b < B_; ++b) {
    const float* qb = q_f + (size_t)b * NSC;
    const float* kb = kv_f + (size_t)b * NB2C;
    const float* vb = kb + Cc_;
    gemm128<0, 1, false, false><<<dim3(16, 8, 6), 256, 0, stream>>>(
        qb, kb, scores, nullptr, nullptr, nullptr, nullptr,
        1024, 2048, 128, 768, 1536, 2048,
        1, 1, 128, 0, 0, 128, 0, 0, SNB, 0, 0, qk_scale);
    softmax_kernel<8, false><<<6 * 1024, 256, 0, stream>>>(scores, nullptr);
    gemm128<0, 0, false, false><<<dim3(1, 8, 96), 256, 0, stream>>>(
        scores, vb, part, nullptr, nullptr, nullptr, nullptr,
        1024, 128, 128, 2048, 1536, 128,
        6, 16, 0, SNB, 128, 0, 128, 128 * 1536, 0, 131072, 786432, 1.0f);
    pv_reduce<<<3072, 256, 0, stream>>>(part, ctxf + (size_t)b * NSC);
  }

  // ---- phase 3: split ctx, convert all FFN weights in one launch ----
  split_kernel<<<24576, 256, 0, stream>>>(ctxf, ctxp);
  wconv12<<<dim3(6, 1536, 12), 256, 0, stream>>>(
      es_w1, el_w1, mlp_w1, es_w2, el_w2, mlp_w2, wb);

  // ---- phase 4: MoE experts + MLP on MFMA (hidden in 2 halves) ----
  for (int h = 0; h < 2; ++h) {
    mgemm<5, true, true, false><<<dim3(12, 64, 1), 256, 0, stream>>>(
        ctxp, esw1h[h], nullptr, hp, es_b1 + h * 1536, perm0, cnt,
        8192, 1536, 768, 0, 1536, 1, 0, 0, 0, 1.0f);
    if (h == 0)
      mgemm<6, false, true, false><<<dim3(6, 64, 2), 256, 0, stream>>>(
          hp, esw2h[h], P0, nullptr, nullptr, nullptr, cnt,
          8192, 768, 1536, 768, 0, 2, 0, 0, ZS, 1.0f);
    else
      mgemm<7, false, true, false><<<dim3(6, 64, 2), 256, 0, stream>>>(
          hp, esw2h[h], P0, nullptr, nullptr, nullptr, cnt,
          8192, 768, 1536, 768, 0, 2, 0, 0, ZS, 1.0f);
  }
  combineP<true><<<dim3(8192, 3), 256, 0, stream>>>(
      P0, P1, es_b2, x_s, perm0, cnt, x_out);
  for (int h = 0; h < 2; ++h) {
    mgemm<5, true, true, false><<<dim3(12, 64, 1), 256, 0, stream>>>(
        ctxp, elw1h[h], nullptr, hp, el_b1 + h * 1536, perm1, cnt + 1,
        8192, 1536, 768, 0, 1536, 1, 0, 0, 0, 1.0f);
    if (h == 0)
      mgemm<6, false, true, false><<<dim3(6, 64, 2), 256, 0, stream>>>(
          hp, elw2h[h], P0, nullptr, nullptr, nullptr, cnt + 1,
          8192, 768, 1536, 768, 0, 2, 0, 0, ZS, 1.0f);
    else
      mgemm<7, false, true, false><<<dim3(6, 64, 2), 256, 0, stream>>>(
          hp, elw2h[h], P0, nullptr, nullptr, nullptr, cnt + 1,
          8192, 768, 1536, 768, 0, 2, 0, 0, ZS, 1.0f);
  }
  combineP<true><<<dim3(8192, 3), 256, 0, stream>>>(
      P0, P1, el_b2, x_s, perm1, cnt + 1, x_out);
  ln_split<<<B_ * NS_, 256, 0, stream>>>(x_out, ctxp, ln3_w, ln3_b);
  for (int h = 0; h < 2; ++h) {
    mgemm<5, false, false, true><<<dim3(12, 64, 1), 256, 0, stream>>>(
        ctxp, mlw1h[h], nullptr, hp, mlp_b1 + h * 1536, nullptr, nullptr,
        8192, 1536, 768, 0, 1536, 1, 0, 0, 0, 1.0f);
    if (h == 0)
      mgemm<6, false, false, true><<<dim3(6, 64, 2), 256, 0, stream>>>(
          hp, mlw2h[h], P0, nullptr, nullptr, nullptr, nullptr,
          8192, 768, 1536, 768, 0, 2, 0, 0, ZS, 1.0f);
    else
      mgemm<7, false, false, true><<<dim3(6, 64, 2), 256, 0, stream>>>(
          hp, mlw2h[h], P0, nullptr, nullptr, nullptr, nullptr,
          8192, 768, 1536, 768, 0, 2, 0, 0, ZS, 1.0f);
  }
  // fused MLP combine + rownorm: writes x_out AND xn
  combine_norm<<<8192, 256, 0, stream>>>(P0, P1, mlp_b2, x_out, xn);

  // ---- phase 5: scoring tail (f32) ----
  gather_kernel<<<12288, 256, 0, stream>>>(x_b, base_idxs, tokens, maskf);
  gemm128<0, 1, false, false><<<dim3(4, 4, 8), 256, 0, stream>>>(
      tokens, tokens, aw, nullptr, nullptr, nullptr, nullptr,
      512, 512, 768, 768, 768, 512,
      1, 1, 393216, 0, 0, 393216, 0, 0, 262144, 0, 0, sc_scale);
  softmax_kernel<2, true><<<8 * 512, 256, 0, stream>>>(aw, maskf);
  gemm128<0, 0, false, false><<<dim3(6, 4, 8), 256, 0, stream>>>(
      aw, tokens, agg, nullptr, nullptr, nullptr, nullptr,
      512, 768, 512, 512, 768, 768,
      1, 1, 262144, 0, 0, 393216, 0, 0, 393216, 0, 0, 1.0f);
  kernel_kernel<<<8, 256, 0, stream>>>(agg, maskf, kern_out, hasf);
  pos_kernel<<<B_ * NS_, 256, 0, stream>>>(xn, kern_out, hasf, pos_out);
  topk_kernel<<<8, 256, 0, stream>>>(pos_out, sel_out, topi_out);
}

// Round 16
// 3161.625 us; speedup vs baseline: 1.2023x; 1.0025x over previous
//
#include <hip/hip_runtime.h>
#include <hip/hip_bf16.h>
#include <math.h>

// Problem constants
#define B_   8
#define NB_  2048
#define NS_  1024
#define Cc_  768
#define HID_ 3072
#define NP_  1024
#define NH_  6
#define HD_  128

__device__ __forceinline__ float gelu_exact(float v) {
  return 0.5f * v * (1.0f + erff(v * 0.7071067811865476f));
}

// split f32 into 3 bf16 planes (truncation; dropped residual ~2^-24 rel)
__device__ __forceinline__ void split3(float v, unsigned short& h,
                                       unsigned short& m, unsigned short& l) {
  unsigned hb = __float_as_uint(v) & 0xffff0000u;
  float r1 = v - __uint_as_float(hb);
  unsigned mb = __float_as_uint(r1) & 0xffff0000u;
  float r2 = r1 - __uint_as_float(mb);
  unsigned lb = __float_as_uint(r2) & 0xffff0000u;
  h = (unsigned short)(hb >> 16);
  m = (unsigned short)(mb >> 16);
  l = (unsigned short)(lb >> 16);
}

typedef short bf16x8 __attribute__((ext_vector_type(8)));
typedef float f32x4 __attribute__((ext_vector_type(4)));

#define BLOCK_REDUCE_ADD(red, tid)                                              \
  for (int off_ = 128; off_; off_ >>= 1) {                                      \
    if ((tid) < off_) red[(tid)] += red[(tid) + off_];                          \
    __syncthreads();                                                            \
  }

// ------- merged LayerNorm -> 3 bf16 planes for x_s (rows<8192) and x_b -----
__global__ __launch_bounds__(256) void ln_split2(
    const float* __restrict__ xs, const float* __restrict__ xb,
    unsigned short* __restrict__ ys, unsigned short* __restrict__ yb,
    const float* __restrict__ w1, const float* __restrict__ b1,
    const float* __restrict__ w2, const float* __restrict__ b2) {
  __shared__ float red[256];
  int row = blockIdx.x, tid = threadIdx.x;
  const float* xr;
  unsigned short* yr;
  const float* w;
  const float* b;
  if (row < 8192) {
    xr = xs + (size_t)row * Cc_;
    yr = ys + (size_t)row * 2304;
    w = w1; b = b1;
  } else {
    int r2 = row - 8192;
    xr = xb + (size_t)r2 * Cc_;
    yr = yb + (size_t)r2 * 2304;
    w = w2; b = b2;
  }
  float v0 = xr[tid], v1 = xr[tid + 256], v2 = xr[tid + 512];
  red[tid] = v0 + v1 + v2;
  __syncthreads();
  BLOCK_REDUCE_ADD(red, tid);
  float mu = red[0] / (float)Cc_;
  __syncthreads();
  float d0 = v0 - mu, d1 = v1 - mu, d2 = v2 - mu;
  red[tid] = d0 * d0 + d1 * d1 + d2 * d2;
  __syncthreads();
  BLOCK_REDUCE_ADD(red, tid);
  float var = red[0] / (float)Cc_;
  float rs = 1.0f / sqrtf(var + 1e-5f);
  float vals[3] = {d0 * rs * w[tid] + b[tid],
                   d1 * rs * w[tid + 256] + b[tid + 256],
                   d2 * rs * w[tid + 512] + b[tid + 512]};
#pragma unroll
  for (int t = 0; t < 3; ++t) {
    int c = tid + (t << 8);
    unsigned short h16, m16, l16;
    split3(vals[t], h16, m16, l16);
    yr[c] = h16; yr[768 + c] = m16; yr[1536 + c] = l16;
  }
}

// ---------------- LayerNorm -> 3 bf16 planes (single src) ----------------
__global__ __launch_bounds__(256) void ln_split(
    const float* __restrict__ x, unsigned short* __restrict__ y,
    const float* __restrict__ w, const float* __restrict__ b) {
  __shared__ float red[256];
  int row = blockIdx.x, tid = threadIdx.x;
  const float* xr = x + (size_t)row * Cc_;
  float v0 = xr[tid], v1 = xr[tid + 256], v2 = xr[tid + 512];
  red[tid] = v0 + v1 + v2;
  __syncthreads();
  BLOCK_REDUCE_ADD(red, tid);
  float mu = red[0] / (float)Cc_;
  __syncthreads();
  float d0 = v0 - mu, d1 = v1 - mu, d2 = v2 - mu;
  red[tid] = d0 * d0 + d1 * d1 + d2 * d2;
  __syncthreads();
  BLOCK_REDUCE_ADD(red, tid);
  float var = red[0] / (float)Cc_;
  float rs = 1.0f / sqrtf(var + 1e-5f);
  unsigned short* yr = y + (size_t)row * 2304;
  float vals[3] = {d0 * rs * w[tid] + b[tid],
                   d1 * rs * w[tid + 256] + b[tid + 256],
                   d2 * rs * w[tid + 512] + b[tid + 512]};
#pragma unroll
  for (int t = 0; t < 3; ++t) {
    int c = tid + (t << 8);
    unsigned short h16, m16, l16;
    split3(vals[t], h16, m16, l16);
    yr[c] = h16; yr[768 + c] = m16; yr[1536 + c] = l16;
  }
}

// ---------------- f32 [8192][768] -> 3 bf16 planes ----------------
__global__ __launch_bounds__(256) void split_kernel(
    const float* __restrict__ x, unsigned short* __restrict__ y) {
  size_t idx = (size_t)blockIdx.x * 256 + threadIdx.x;  // < 8192*768
  int c = (int)(idx % Cc_);
  int row = (int)(idx / Cc_);
  unsigned short h16, m16, l16;
  split3(x[idx], h16, m16, l16);
  unsigned short* yr = y + (size_t)row * 2304;
  yr[c] = h16; yr[768 + c] = m16; yr[1536 + c] = l16;
}

// ------- merged Wq+Wkv plane convert: z=0 Wq(768 cols), z=1 Wkv(1536) ------
__global__ __launch_bounds__(256) void wconv2(
    const float* __restrict__ Wq, const float* __restrict__ Wkv,
    unsigned short* __restrict__ wqp, unsigned short* __restrict__ wkvp) {
  int z = blockIdx.z;
  int k = blockIdx.x * 256 + threadIdx.x;  // < 768
  int n = blockIdx.y;
  const float* W;
  unsigned short* out;
  int ldw;
  if (z == 0) {
    if (n >= 768) return;
    W = Wq; out = wqp; ldw = 768;
  } else {
    W = Wkv; out = wkvp; ldw = 1536;
  }
  float v = W[(size_t)k * ldw + n];
  unsigned short h16, m16, l16;
  split3(v, h16, m16, l16);
  size_t base = (size_t)n * 2304;
  out[base + k] = h16;
  out[base + 768 + k] = m16;
  out[base + 1536 + k] = l16;
}

// --------- mega weight convert: all 12 FFN plane jobs in one launch --------
__global__ __launch_bounds__(256) void wconv12(
    const float* __restrict__ w1a, const float* __restrict__ w1b,
    const float* __restrict__ w1c, const float* __restrict__ w2a,
    const float* __restrict__ w2b, const float* __restrict__ w2c,
    unsigned short* __restrict__ wb) {
  int z = blockIdx.z;
  int k = blockIdx.x * 256 + threadIdx.x;
  int n = blockIdx.y;
  const float* W;
  int K, ldw, ncol0;
  size_t out_off;
  if (z < 6) {
    K = 768; ldw = 3072;
    int m = z >> 1, h = z & 1;
    W = (m == 0) ? w1a : ((m == 1) ? w1b : w1c);
    ncol0 = h * 1536;
    out_off = (size_t)m * 7077888 + (size_t)h * 3538944;
    if (k >= 768) return;
  } else {
    K = 1536; ldw = 768; ncol0 = 0;
    int m = (z - 6) >> 1, h = z & 1;
    W = ((m == 0) ? w2a : ((m == 1) ? w2b : w2c)) + (size_t)h * 1536 * 768;
    out_off = 21233664 + (size_t)m * 7077888 + (size_t)h * 3538944;
    if (n >= 768) return;
  }
  float v = W[(size_t)k * ldw + ncol0 + n];
  unsigned short h16, m16, l16;
  split3(v, h16, m16, l16);
  size_t base = out_off + (size_t)n * 3 * K;
  wb[base + k] = h16;
  wb[base + K + k] = m16;
  wb[base + 2 * K + k] = l16;
}

// ---------------- MFMA GEMM over 3-split bf16 planes ----------------
// Depth-2 register prefetch (loads for tile t+2 issued at tile t); sync
// structure unchanged: exactly one lgkmcnt(0)+s_barrier per 64-wide k-tile.
// Named register sets (A/B) -> no runtime-indexed reg arrays (no scratch).
// SWZ must be false for MDEV launches (R12 lesson).
// EPI: 5 = gelu(v+bias) -> 3 bf16 planes Cs[m][3*Kout]
//      6 = f32:  Cf[z*zstride + m*ldc + n] = v
//      7 = f32:  Cf[z*zstride + m*ldc + n] += v
template <int EPI, bool AGATHER, bool MDEV, bool SWZ>
__global__ __launch_bounds__(256) void mgemm(
    const unsigned short* __restrict__ Ap, const unsigned short* __restrict__ Bp,
    float* __restrict__ Cf, unsigned short* __restrict__ Cs,
    const float* __restrict__ bias,
    const int* __restrict__ perm, const int* __restrict__ mdev,
    int M, int N, int K, int ldc, int Kout, int nsplit,
    long azs, long bzs, long zstride, float scale) {
  __shared__ unsigned short As[2][8192];
  __shared__ unsigned short Bs[2][8192];
  int z = blockIdx.z;
  int bx, by;
  if (SWZ) {
    int gx = gridDim.x;
    int id = blockIdx.y * gx + blockIdx.x;
    int per = (gx * gridDim.y) >> 3;
    int nid = (id & 7) * per + (id >> 3);
    bx = nid % gx; by = nid / gx;
  } else {
    bx = blockIdx.x; by = blockIdx.y;
  }
  int Me = MDEV ? mdev[0] : M;
  int m0 = by * 128, n0 = bx * 128;
  if (MDEV && m0 >= Me) return;
  const unsigned short* ApB = Ap + (size_t)z * azs;
  const unsigned short* BpB = Bp + (size_t)z * bzs;
  int tid = threadIdx.x;
  int lane = tid & 63, w = tid >> 6;
  int wr = w >> 1, wc = w & 1;
  int K3 = 3 * K;
  int tps = K >> 6;
  int KT = 6 * tps;
  int span = KT / nsplit;
  int zr = z % nsplit;
  int tt0 = zr * span, tt1 = tt0 + span;

  const unsigned short* agp[4];
  const unsigned short* bgp[4];
  int wswz[4];
#pragma unroll
  for (int p = 0; p < 4; ++p) {
    int r = (tid >> 3) + 32 * p;
    int ma = m0 + r;
    if (MDEV) ma = min(ma, Me - 1);
    if (AGATHER) ma = perm[ma];
    agp[p] = ApB + (size_t)ma * K3 + (tid & 7) * 8;
    bgp[p] = BpB + (size_t)(n0 + r) * K3 + (tid & 7) * 8;
    wswz[p] = r * 64 + (((tid & 7) ^ (r & 7)) << 3);
  }

  f32x4 acc[4][4];
  f32x4 zero4 = {0.f, 0.f, 0.f, 0.f};
#pragma unroll
  for (int i = 0; i < 4; ++i)
#pragma unroll
    for (int j = 0; j < 4; ++j) acc[i][j] = zero4;

  int kg = lane >> 4;
  int frm[4], frn[4];
#pragma unroll
  for (int f = 0; f < 4; ++f) {
    frm[f] = wr * 64 + f * 16 + (lane & 15);
    frn[f] = wc * 64 + f * 16 + (lane & 15);
  }

#define LOADTILE(RA, RB, TT)                                          \
  {                                                                   \
    int seg_ = (TT) / tps, kt_ = (TT) - seg_ * tps;                   \
    int pa_ = (0x210100u >> (4 * seg_)) & 0xF;                        \
    int pb_ = (0x012010u >> (4 * seg_)) & 0xF;                        \
    size_t ao_ = (size_t)(pa_ * K + kt_ * 64);                        \
    size_t bo_ = (size_t)(pb_ * K + kt_ * 64);                        \
    _Pragma("unroll")                                                 \
    for (int p = 0; p < 4; ++p) {                                     \
      RA[p] = *(const bf16x8*)(agp[p] + ao_);                         \
      RB[p] = *(const bf16x8*)(bgp[p] + bo_);                         \
    }                                                                 \
  }

#define KSTEP(CUR, RA, RB, NEXTTT)                                    \
  {                                                                   \
    _Pragma("unroll")                                                 \
    for (int p = 0; p < 4; ++p) {                                     \
      *(bf16x8*)&As[CUR][wswz[p]] = RA[p];                            \
      *(bf16x8*)&Bs[CUR][wswz[p]] = RB[p];                            \
    }                                                                 \
    if ((NEXTTT) < tt1) LOADTILE(RA, RB, (NEXTTT));                   \
    asm volatile("s_waitcnt lgkmcnt(0)" ::: "memory");                \
    __builtin_amdgcn_s_barrier();                                     \
    _Pragma("unroll")                                                 \
    for (int ks = 0; ks < 2; ++ks) {                                  \
      int ch = ks * 4 + kg;                                           \
      bf16x8 af[4], bf[4];                                            \
      _Pragma("unroll")                                               \
      for (int f = 0; f < 4; ++f) {                                   \
        int r = frm[f];                                               \
        af[f] = *(const bf16x8*)&As[CUR][r * 64 + ((ch ^ (r & 7)) << 3)]; \
      }                                                               \
      _Pragma("unroll")                                               \
      for (int f = 0; f < 4; ++f) {                                   \
        int r = frn[f];                                               \
        bf[f] = *(const bf16x8*)&Bs[CUR][r * 64 + ((ch ^ (r & 7)) << 3)]; \
      }                                                               \
      _Pragma("unroll")                                               \
      for (int i = 0; i < 4; ++i)                                     \
        _Pragma("unroll")                                             \
        for (int j = 0; j < 4; ++j)                                   \
          acc[i][j] = __builtin_amdgcn_mfma_f32_16x16x32_bf16(        \
              af[i], bf[j], acc[i][j], 0, 0, 0);                      \
    }                                                                 \
  }

  // prologue: tiles tt0 -> set A, tt0+1 -> set B (span >= 2 always; tt0 even)
  bf16x8 raA[4], rbA[4], raB[4], rbB[4];
  LOADTILE(raA, rbA, tt0);
  if (tt0 + 1 < tt1) LOADTILE(raB, rbB, tt0 + 1);

  int tt = tt0;
  for (; tt + 1 < tt1; tt += 2) {
    KSTEP(0, raA, rbA, tt + 2);
    KSTEP(1, raB, rbB, tt + 3);
  }
  if (tt < tt1) {
    KSTEP(0, raA, rbA, tt1);  // tail (never taken for even spans)
  }
#undef KSTEP
#undef LOADTILE

  // epilogue: C/D layout col=lane&15, row=(lane>>4)*4+reg (m89-verified)
#pragma unroll
  for (int i = 0; i < 4; ++i) {
#pragma unroll
    for (int r = 0; r < 4; ++r) {
      int m = m0 + wr * 64 + i * 16 + kg * 4 + r;
      if (MDEV && m >= Me) continue;
#pragma unroll
      for (int j = 0; j < 4; ++j) {
        int n = n0 + wc * 64 + j * 16 + (lane & 15);
        float v = acc[i][j][r] * scale;
        if (EPI == 6) {
          Cf[(size_t)z * zstride + (size_t)m * ldc + n] = v;
        } else if (EPI == 7) {
          Cf[(size_t)z * zstride + (size_t)m * ldc + n] += v;
        } else if (EPI == 5) {
          float t = gelu_exact(v + bias[n]);
          unsigned short h16, m16, l16;
          split3(t, h16, m16, l16);
          size_t base = (size_t)m * 3 * Kout;
          Cs[base + n] = h16;
          Cs[base + Kout + n] = m16;
          Cs[base + 2 * Kout + n] = l16;
        }
      }
    }
  }
}

// ---------------- combine partials: out = bias + addsrc + P0 + P1 ----------
template <bool SCATTER>
__global__ __launch_bounds__(256) void combineP(
    const float* __restrict__ P0, const float* __restrict__ P1,
    const float* __restrict__ bias, const float* __restrict__ addsrc,
    const int* __restrict__ perm, const int* __restrict__ cnt,
    float* __restrict__ out) {
  int m = blockIdx.x;
  int c = threadIdx.x + (blockIdx.y << 8);
  if (SCATTER && m >= cnt[0]) return;
  int mo = SCATTER ? perm[m] : m;
  size_t pm = (size_t)m * 768 + c;
  out[(size_t)mo * 768 + c] =
      bias[c] + addsrc[(size_t)mo * 768 + c] + P0[pm] + P1[pm];
}

// ----- fused final combine + rownorm: x = bias+x+P0+P1; xn = x/||x|| -------
__global__ __launch_bounds__(256) void combine_norm(
    const float* __restrict__ P0, const float* __restrict__ P1,
    const float* __restrict__ bias, float* __restrict__ x,
    float* __restrict__ xn) {
  __shared__ float red[256];
  int m = blockIdx.x, tid = threadIdx.x;
  size_t rb = (size_t)m * 768;
  float v[3];
  float s2 = 0.f;
#pragma unroll
  for (int t = 0; t < 3; ++t) {
    int c = tid + (t << 8);
    v[t] = bias[c] + x[rb + c] + P0[rb + c] + P1[rb + c];
    s2 = fmaf(v[t], v[t], s2);
  }
  red[tid] = s2;
  __syncthreads();
  BLOCK_REDUCE_ADD(red, tid);
  float den = fmaxf(sqrtf(red[0]), 1e-12f);
  float inv = 1.0f / den;
#pragma unroll
  for (int t = 0; t < 3; ++t) {
    int c = tid + (t << 8);
    x[rb + c] = v[t];
    xn[rb + c] = v[t] * inv;
  }
}

// ---------------- f32 GEMM (R5: 128x128, 8x8, reg-prefetch dbuf) ----------
template <int EPI, int TRB, bool AGATHER, bool MDEV>
__global__ __launch_bounds__(256) void gemm128(
    const float* __restrict__ A, const float* __restrict__ Bm,
    float* __restrict__ Cm, const float* __restrict__ bias,
    const float* __restrict__ addsrc, const int* __restrict__ perm,
    const int* __restrict__ mdev,
    int M, int N, int K, int lda, int ldb, int ldc,
    int d1, int d2,
    long a_s1, long a_s2, long a_s3,
    long b_s1, long b_s2, long b_s3,
    long c_s1, long c_s2, long c_s3,
    float scale) {
  __shared__ float As[2][16][132];
  __shared__ float Bs[2][16][132];
  int z = blockIdx.z;
  int z1 = z / (d1 * d2);
  int rem = z - z1 * d1 * d2;
  int z2 = rem / d2, z3 = rem - z2 * d2;
  const float* Ab = A + (size_t)z1 * a_s1 + (size_t)z2 * a_s2 + (size_t)z3 * a_s3;
  const float* Bb = Bm + (size_t)z1 * b_s1 + (size_t)z2 * b_s2 + (size_t)z3 * b_s3;
  float* Cb = Cm + (size_t)z1 * c_s1 + (size_t)z2 * c_s2 + (size_t)z3 * c_s3;
  int Me = MDEV ? mdev[0] : M;
  int m0 = blockIdx.y * 128, n0 = blockIdx.x * 128;
  if (MDEV && m0 >= Me) return;
  int tid = threadIdx.x;
  int tx = tid & 15, ty = tid >> 4;
  int arow = tid >> 2, akq = tid & 3;
  int ma0 = m0 + arow, ma1 = m0 + arow + 64;
  if (MDEV) { ma0 = min(ma0, Me - 1); ma1 = min(ma1, Me - 1); }
  if (AGATHER) { ma0 = perm[ma0]; ma1 = perm[ma1]; }
  const float* Ap0 = Ab + (size_t)ma0 * lda + akq * 4;
  const float* Ap1 = Ab + (size_t)ma1 * lda + akq * 4;
  const float* Bp0;
  const float* Bp1;
  int bw_r0 = 0, bw_c0 = 0, bw_r1 = 0;
  if (TRB == 0) {
    bw_r0 = tid >> 5; bw_c0 = (tid & 31) * 4; bw_r1 = bw_r0 + 8;
    Bp0 = Bb + (size_t)bw_r0 * ldb + n0 + bw_c0;
    Bp1 = Bb + (size_t)bw_r1 * ldb + n0 + bw_c0;
  } else {
    Bp0 = Bb + (size_t)(n0 + arow) * ldb + akq * 4;
    Bp1 = Bb + (size_t)(n0 + arow + 64) * ldb + akq * 4;
  }
  float4 pa0 = *(const float4*)Ap0;
  float4 pa1 = *(const float4*)Ap1;
  float4 pb0 = *(const float4*)Bp0;
  float4 pb1 = *(const float4*)Bp1;
  float acc[8][8] = {};
  int nt = K >> 4;
  for (int t = 0; t < nt; ++t) {
    int cur = t & 1;
    As[cur][akq * 4 + 0][arow] = pa0.x; As[cur][akq * 4 + 1][arow] = pa0.y;
    As[cur][akq * 4 + 2][arow] = pa0.z; As[cur][akq * 4 + 3][arow] = pa0.w;
    As[cur][akq * 4 + 0][arow + 64] = pa1.x; As[cur][akq * 4 + 1][arow + 64] = pa1.y;
    As[cur][akq * 4 + 2][arow + 64] = pa1.z; As[cur][akq * 4 + 3][arow + 64] = pa1.w;
    if (TRB == 0) {
      *(float4*)&Bs[cur][bw_r0][bw_c0] = pb0;
      *(float4*)&Bs[cur][bw_r1][bw_c0] = pb1;
    } else {
      Bs[cur][akq * 4 + 0][arow] = pb0.x; Bs[cur][akq * 4 + 1][arow] = pb0.y;
      Bs[cur][akq * 4 + 2][arow] = pb0.z; Bs[cur][akq * 4 + 3][arow] = pb0.w;
      Bs[cur][akq * 4 + 0][arow + 64] = pb1.x; Bs[cur][akq * 4 + 1][arow + 64] = pb1.y;
      Bs[cur][akq * 4 + 2][arow + 64] = pb1.z; Bs[cur][akq * 4 + 3][arow + 64] = pb1.w;
    }
    if (t + 1 < nt) {
      int kn = (t + 1) << 4;
      pa0 = *(const float4*)&Ap0[kn];
      pa1 = *(const float4*)&Ap1[kn];
      if (TRB == 0) {
        pb0 = *(const float4*)&Bp0[(size_t)kn * ldb];
        pb1 = *(const float4*)&Bp1[(size_t)kn * ldb];
      } else {
        pb0 = *(const float4*)&Bp0[kn];
        pb1 = *(const float4*)&Bp1[kn];
      }
    }
    asm volatile("s_waitcnt lgkmcnt(0)" ::: "memory");
    __builtin_amdgcn_s_barrier();
#pragma unroll
    for (int kk = 0; kk < 16; ++kk) {
      float a[8], b[8];
      *(float4*)&a[0] = *(const float4*)&As[cur][kk][ty * 4];
      *(float4*)&a[4] = *(const float4*)&As[cur][kk][ty * 4 + 64];
      *(float4*)&b[0] = *(const float4*)&Bs[cur][kk][tx * 4];
      *(float4*)&b[4] = *(const float4*)&Bs[cur][kk][tx * 4 + 64];
#pragma unroll
      for (int i = 0; i < 8; ++i)
#pragma unroll
        for (int j = 0; j < 8; ++j)
          acc[i][j] = fmaf(a[i], b[j], acc[i][j]);
    }
  }
#pragma unroll
  for (int i = 0; i < 8; ++i) {
    int m = m0 + ((i < 4) ? (ty * 4 + i) : (64 + ty * 4 + i - 4));
    if (!MDEV || m < Me) {
      int mo = (EPI == 4) ? perm[m] : m;
      int n = n0 + tx * 4;
      float v[8];
#pragma unroll
      for (int j = 0; j < 8; ++j) {
        int nj = (j < 4) ? (n + j) : (n + 64 + j - 4);
        v[j] = acc[i][j] * scale;
        if (EPI >= 1) v[j] += bias[nj];
        if (EPI == 2) v[j] = gelu_exact(v[j]);
        if (EPI == 3 || EPI == 4) v[j] += addsrc[(size_t)mo * ldc + nj];
      }
      float* cp = &Cb[(size_t)mo * ldc + n];
      *(float4*)cp = make_float4(v[0], v[1], v[2], v[3]);
      *(float4*)(cp + 64) = make_float4(v[4], v[5], v[6], v[7]);
    }
  }
}

// ---------------- PV split-K(16) reduce -> f32 ctx ----------------
__global__ __launch_bounds__(256) void pv_reduce(
    const float* __restrict__ part, float* __restrict__ ctx) {
  int i = blockIdx.x * 256 + threadIdx.x;
  int n = i & 127, m = (i >> 7) & 1023, h = i >> 17;
  float s = 0.f;
#pragma unroll
  for (int ks = 0; ks < 16; ++ks)
    s += part[(size_t)(ks * 6 + h) * 131072 + m * 128 + n];
  ctx[(size_t)m * 768 + h * 128 + n] = s;
}

// ---------------- Softmax (native exp, hoisted reciprocal) ----------------
template <int EPT, bool MASK>
__global__ __launch_bounds__(256) void softmax_kernel(
    float* __restrict__ s, const float* __restrict__ maskf) {
  __shared__ float red[256];
  int row = blockIdx.x, tid = threadIdx.x;
  float* sr = s + (size_t)row * (EPT * 256);
  const float* mb = MASK ? (maskf + (size_t)(row / 512) * 512) : nullptr;
  float v[EPT];
  float m = -3.0e38f;
#pragma unroll
  for (int t = 0; t < EPT; ++t) {
    int j = tid + (t << 8);
    float xv = sr[j];
    if (MASK) xv += (mb[j] != 0.0f) ? 0.0f : -1e9f;
    v[t] = xv;
    m = fmaxf(m, xv);
  }
  red[tid] = m;
  __syncthreads();
  for (int off = 128; off; off >>= 1) {
    if (tid < off) red[tid] = fmaxf(red[tid], red[tid + off]);
    __syncthreads();
  }
  m = red[0];
  __syncthreads();
  float ssum = 0.f;
#pragma unroll
  for (int t = 0; t < EPT; ++t) {
    v[t] = __expf(v[t] - m);
    ssum += v[t];
  }
  red[tid] = ssum;
  __syncthreads();
  BLOCK_REDUCE_ADD(red, tid);
  float inv = 1.0f / red[0];
#pragma unroll
  for (int t = 0; t < EPT; ++t) sr[tid + (t << 8)] = v[t] * inv;
}

// ---------------- MoE permutation build ----------------
__global__ __launch_bounds__(256) void build_perm(
    const int* __restrict__ tt, int* __restrict__ perm0,
    int* __restrict__ perm1, int* __restrict__ cnt) {
  int r = blockIdx.x * 256 + threadIdx.x;
  int t = tt[r];
  if (t == 0) { int p = atomicAdd(&cnt[0], 1); perm0[p] = r; }
  else        { int p = atomicAdd(&cnt[1], 1); perm1[p] = r; }
}

// ---------------- Token gather ----------------
__global__ __launch_bounds__(256) void gather_kernel(
    const float* __restrict__ xb, const int* __restrict__ bidx,
    float* __restrict__ tokens, float* __restrict__ maskf) {
  size_t idx = (size_t)blockIdx.x * 256 + threadIdx.x;
  int c = (int)(idx % Cc_);
  int i = (int)((idx / Cc_) % 512);
  int b = (int)(idx / ((size_t)Cc_ * 512));
  int id = bidx[b * NP_ + i];
  bool m = id >= 0;
  int idc = m ? id : 0;
  tokens[idx] = m ? xb[((size_t)b * NB_ + idc) * Cc_ + c] : 0.0f;
  if (c == 0) maskf[b * 512 + i] = m ? 1.0f : 0.0f;
}

// ---------------- ksum -> kernel ----------------
__global__ __launch_bounds__(256) void kernel_kernel(
    const float* __restrict__ agg, const float* __restrict__ maskf,
    float* __restrict__ kern, float* __restrict__ hasf) {
  __shared__ float red[256];
  __shared__ float ks[Cc_];
  __shared__ float s_cnt;
  int b = blockIdx.x, tid = threadIdx.x;
  const float* mb = maskf + b * 512;
  red[tid] = mb[tid] + mb[tid + 256];
  __syncthreads();
  BLOCK_REDUCE_ADD(red, tid);
  if (tid == 0) s_cnt = red[0];
  __syncthreads();
  float cnt = s_cnt;
  float dc = fmaxf(cnt, 1.0f);
  const float* ab = agg + (size_t)b * 512 * Cc_;
#pragma unroll
  for (int t = 0; t < 3; ++t) {
    int cc = tid + t * 256;
    float s = 0.f;
    for (int i = 0; i < 512; ++i) s = fmaf(ab[(size_t)i * Cc_ + cc], mb[i], s);
    ks[cc] = s / dc;
  }
  __syncthreads();
  float s2 = 0.f;
#pragma unroll
  for (int t = 0; t < 3; ++t) {
    float q = ks[tid + t * 256];
    s2 = fmaf(q, q, s2);
  }
  red[tid] = s2;
  __syncthreads();
  BLOCK_REDUCE_ADD(red, tid);
  float den = fmaxf(sqrtf(red[0]), 1e-12f);
  bool has = cnt > 0.5f;
#pragma unroll
  for (int t = 0; t < 3; ++t) {
    int cc = tid + t * 256;
    kern[(size_t)b * Cc_ + cc] = has ? (ks[cc] / den) : 0.0f;
  }
  if (tid == 0) hasf[b] = has ? 1.0f : 0.0f;
}

// ---------------- pos ----------------
__global__ __launch_bounds__(256) void pos_kernel(
    const float* __restrict__ xnorm, const float* __restrict__ kern,
    const float* __restrict__ hasf, float* __restrict__ pos) {
  __shared__ float red[256];
  int row = blockIdx.x, tid = threadIdx.x;
  int b = row >> 10;
  const float* xr = xnorm + (size_t)row * Cc_;
  const float* kr = kern + (size_t)b * Cc_;
  float s = xr[tid] * kr[tid];
  s = fmaf(xr[tid + 256], kr[tid + 256], s);
  s = fmaf(xr[tid + 512], kr[tid + 512], s);
  red[tid] = s;
  __syncthreads();
  BLOCK_REDUCE_ADD(red, tid);
  if (tid == 0) pos[row] = (hasf[b] > 0.5f) ? (red[0] + 1.0f) * 0.5f : 0.0f;
}

// ---------------- per-batch top-128 via bitonic sort ----------------
__global__ __launch_bounds__(256) void topk_kernel(
    const float* __restrict__ pos, float* __restrict__ sel,
    float* __restrict__ topi) {
  __shared__ float sv[NS_];
  __shared__ int si[NS_];
  __shared__ int red[256];
  __shared__ int s_vk;
  int b = blockIdx.x, tid = threadIdx.x;
  const float* pr = pos + (size_t)b * NS_;
  int c65 = 0;
#pragma unroll
  for (int t = 0; t < 4; ++t) {
    int i = tid + (t << 8);
    float v = pr[i];
    sv[i] = v; si[i] = i;
    if (v > 0.65f) ++c65;
  }
  red[tid] = c65;
  __syncthreads();
  for (int off = 128; off; off >>= 1) {
    if (tid < off) red[tid] += red[tid + off];
    __syncthreads();
  }
  if (tid == 0) {
    int vk = red[0] > 118 ? red[0] : 118;
    s_vk = vk > 128 ? 128 : vk;
  }
  for (int k = 2; k <= NS_; k <<= 1) {
    for (int j = k >> 1; j > 0; j >>= 1) {
      __syncthreads();
#pragma unroll
      for (int t = 0; t < 4; ++t) {
        int i = tid + (t << 8);
        int l = i ^ j;
        if (l > i) {
          bool up = ((i & k) == 0);
          float vi = sv[i], vl = sv[l];
          int ii = si[i], il = si[l];
          bool gt = (vi < vl) || (vi == vl && ii > il);
          if (up == gt) {
            sv[i] = vl; sv[l] = vi;
            si[i] = il; si[l] = ii;
          }
        }
      }
    }
  }
  __syncthreads();
  if (tid < 128) {
    int wi = si[tid];
    float wv = sv[tid];
    topi[(size_t)b * 128 + tid] = (float)wi;
    if (tid < s_vk && wv > 0.0f) sel[((size_t)b * 128 + tid) * NS_ + wi] = 1.0f;
  }
}

extern "C" void kernel_launch(void* const* d_in, const int* in_sizes, int n_in,
                              void* d_out, int out_size, void* d_ws, size_t ws_size,
                              hipStream_t stream) {
  (void)in_sizes; (void)n_in; (void)out_size; (void)ws_size;
  const float* x_b = (const float*)d_in[0];
  const float* x_s = (const float*)d_in[1];
  const int* token_types = (const int*)d_in[2];
  const int* base_idxs = (const int*)d_in[3];
  const float* ln1_w = (const float*)d_in[4];
  const float* ln1_b = (const float*)d_in[5];
  const float* ln2_w = (const float*)d_in[6];
  const float* ln2_b = (const float*)d_in[7];
  const float* ln3_w = (const float*)d_in[8];
  const float* ln3_b = (const float*)d_in[9];
  const float* Wq = (const float*)d_in[10];
  const float* Wkv = (const float*)d_in[11];
  const float* es_w1 = (const float*)d_in[12];
  const float* es_b1 = (const float*)d_in[13];
  const float* es_w2 = (const float*)d_in[14];
  const float* es_b2 = (const float*)d_in[15];
  const float* el_w1 = (const float*)d_in[16];
  const float* el_b1 = (const float*)d_in[17];
  const float* el_w2 = (const float*)d_in[18];
  const float* el_b2 = (const float*)d_in[19];
  const float* mlp_w1 = (const float*)d_in[20];
  const float* mlp_b1 = (const float*)d_in[21];
  const float* mlp_w2 = (const float*)d_in[22];
  const float* mlp_b2 = (const float*)d_in[23];

  float* out = (float*)d_out;
  float* sel_out  = out;
  float* topi_out = out + 1048576;
  float* pos_out  = out + 1049600;
  float* x_out    = out + 1057792;
  float* kern_out = out + 7349248;

  // ---- workspace layout (floats), peak ~252 MB ----
  float* w = (float*)d_ws;
  float* kv_f = w;                        // [0, 25165824)
  float* q_f  = w + 25165824;             // [25165824, 31457280)
  float* scores = w + 31457280;           // [31457280, 44040192)
  float* part   = w + 44040192;           // [44040192, 56623104)  16-split PV
  float* ctxf   = w + 56623104;           // [56623104, 62914560)
  // Phase 1 plane staging (dead after phase 1):
  unsigned short* xbnp = (unsigned short*)(w + 31457280);
  unsigned short* xsnp = (unsigned short*)(w + 50331648);
  unsigned short* wqp  = (unsigned short*)(w + 59768832);
  unsigned short* wkvp = (unsigned short*)(w + 60653568);
  // Phase 3/4 (FFN) overlays:
  unsigned short* ctxp = (unsigned short*)(w + 6291456);   // 18874368 us
  unsigned short* wb   = (unsigned short*)(w + 15728640);  // 42467328 us
  unsigned short* hp   = (unsigned short*)(w + 36962304);  // 37748736 us
  float* P0 = w;                                           // 6291456 fl
  const long ZS = 55836672;
  float* P1 = w + ZS;                                      // [55836672, 62128128)
  // Phase 5 overlays:
  float* xn     = w + 6291456;
  float* tokens = w + 12582912;
  float* aw     = w + 15728640;
  float* agg    = w + 17825792;
  // small block
  float* small  = w + 62914560;
  float* maskf  = small;
  float* hasf   = small + 4096;
  int* cnt      = (int*)(small + 4104);
  int* perm0    = (int*)(small + 4106);
  int* perm1    = (int*)(small + 12298);

  // weight plane sub-layout (ushort offsets in wb; wconv12 writes these)
  unsigned short* esw1h[2] = {wb + 0,        wb + 3538944};
  unsigned short* elw1h[2] = {wb + 7077888,  wb + 10616832};
  unsigned short* mlw1h[2] = {wb + 14155776, wb + 17694720};
  unsigned short* esw2h[2] = {wb + 21233664, wb + 24772608};
  unsigned short* elw2h[2] = {wb + 28311552, wb + 31850496};
  unsigned short* mlw2h[2] = {wb + 35389440, wb + 38928384};

  const long NSC = (long)NS_ * Cc_;
  const long NB2C = (long)NB_ * 2 * Cc_;
  const long SNB = (long)NS_ * NB_;
  const float qk_scale = 0.08838834764831845f;
  const float sc_scale = 0.036084391824351615f;

  hipMemsetAsync(sel_out, 0, (size_t)1048576 * sizeof(float), stream);
  hipMemsetAsync(cnt, 0, 2 * sizeof(int), stream);

  // ---- phase 1: LN->planes (merged), weight planes (merged), q/kv MFMA ----
  ln_split2<<<24576, 256, 0, stream>>>(x_s, x_b, xsnp, xbnp,
                                       ln1_w, ln1_b, ln2_w, ln2_b);
  build_perm<<<32, 256, 0, stream>>>(token_types, perm0, perm1, cnt);
  wconv2<<<dim3(3, 1536, 2), 256, 0, stream>>>(Wq, Wkv, wqp, wkvp);
  mgemm<6, false, false, true><<<dim3(6, 64, 1), 256, 0, stream>>>(
      xsnp, wqp, q_f, nullptr, nullptr, nullptr, nullptr,
      8192, 768, 768, 768, 0, 1, 0, 0, 0, 1.0f);
  mgemm<6, false, false, true><<<dim3(12, 128, 1), 256, 0, stream>>>(
      xbnp, wkvp, kv_f, nullptr, nullptr, nullptr, nullptr,
      16384, 1536, 768, 1536, 0, 1, 0, 0, 0, 1.0f);

  // ---- phase 2: attention (f32 QK^T + softmax + PV split-16) ----
  for (int b = 0; b < B_; ++b) {
    const float* qb = q_f + (size_t)b * NSC;
    const float* kb = kv_f + (size_t)b * NB2C;
    const float* vb = kb + Cc_;
    gemm128<0, 1, false, false><<<dim3(16, 8, 6), 256, 0, stream>>>(
        qb, kb, scores, nullptr, nullptr, nullptr, nullptr,
        1024, 2048, 128, 768, 1536, 2048,
        1, 1, 128, 0, 0, 128, 0, 0, SNB, 0, 0, qk_scale);
    softmax_kernel<8, false><<<6 * 1024, 256, 0, stream>>>(scores, nullptr);
    gemm128<0, 0, false, false><<<dim3(1, 8, 96), 256, 0, stream>>>(
        scores, vb, part, nullptr, nullptr, nullptr, nullptr,
        1024, 128, 128, 2048, 1536, 128,
        6, 16, 0, SNB, 128, 0, 128, 128 * 1536, 0, 131072, 786432, 1.0f);
    pv_reduce<<<3072, 256, 0, stream>>>(part, ctxf + (size_t)b * NSC);
  }

  // ---- phase 3: split ctx, convert all FFN weights in one launch ----
  split_kernel<<<24576, 256, 0, stream>>>(ctxf, ctxp);
  wconv12<<<dim3(6, 1536, 12), 256, 0, stream>>>(
      es_w1, el_w1, mlp_w1, es_w2, el_w2, mlp_w2, wb);

  // ---- phase 4: MoE experts + MLP on MFMA (hidden in 2 halves) ----
  for (int h = 0; h < 2; ++h) {
    mgemm<5, true, true, false><<<dim3(12, 64, 1), 256, 0, stream>>>(
        ctxp, esw1h[h], nullptr, hp, es_b1 + h * 1536, perm0, cnt,
        8192, 1536, 768, 0, 1536, 1, 0, 0, 0, 1.0f);
    if (h == 0)
      mgemm<6, false, true, false><<<dim3(6, 64, 2), 256, 0, stream>>>(
          hp, esw2h[h], P0, nullptr, nullptr, nullptr, cnt,
          8192, 768, 1536, 768, 0, 2, 0, 0, ZS, 1.0f);
    else
      mgemm<7, false, true, false><<<dim3(6, 64, 2), 256, 0, stream>>>(
          hp, esw2h[h], P0, nullptr, nullptr, nullptr, cnt,
          8192, 768, 1536, 768, 0, 2, 0, 0, ZS, 1.0f);
  }
  combineP<true><<<dim3(8192, 3), 256, 0, stream>>>(
      P0, P1, es_b2, x_s, perm0, cnt, x_out);
  for (int h = 0; h < 2; ++h) {
    mgemm<5, true, true, false><<<dim3(12, 64, 1), 256, 0, stream>>>(
        ctxp, elw1h[h], nullptr, hp, el_b1 + h * 1536, perm1, cnt + 1,
        8192, 1536, 768, 0, 1536, 1, 0, 0, 0, 1.0f);
    if (h == 0)
      mgemm<6, false, true, false><<<dim3(6, 64, 2), 256, 0, stream>>>(
          hp, elw2h[h], P0, nullptr, nullptr, nullptr, cnt + 1,
          8192, 768, 1536, 768, 0, 2, 0, 0, ZS, 1.0f);
    else
      mgemm<7, false, true, false><<<dim3(6, 64, 2), 256, 0, stream>>>(
          hp, elw2h[h], P0, nullptr, nullptr, nullptr, cnt + 1,
          8192, 768, 1536, 768, 0, 2, 0, 0, ZS, 1.0f);
  }
  combineP<true><<<dim3(8192, 3), 256, 0, stream>>>(
      P0, P1, el_b2, x_s, perm1, cnt + 1, x_out);
  ln_split<<<B_ * NS_, 256, 0, stream>>>(x_out, ctxp, ln3_w, ln3_b);
  for (int h = 0; h < 2; ++h) {
    mgemm<5, false, false, true><<<dim3(12, 64, 1), 256, 0, stream>>>(
        ctxp, mlw1h[h], nullptr, hp, mlp_b1 + h * 1536, nullptr, nullptr,
        8192, 1536, 768, 0, 1536, 1, 0, 0, 0, 1.0f);
    if (h == 0)
      mgemm<6, false, false, true><<<dim3(6, 64, 2), 256, 0, stream>>>(
          hp, mlw2h[h], P0, nullptr, nullptr, nullptr, nullptr,
          8192, 768, 1536, 768, 0, 2, 0, 0, ZS, 1.0f);
    else
      mgemm<7, false, false, true><<<dim3(6, 64, 2), 256, 0, stream>>>(
          hp, mlw2h[h], P0, nullptr, nullptr, nullptr, nullptr,
          8192, 768, 1536, 768, 0, 2, 0, 0, ZS, 1.0f);
  }
  // fused MLP combine + rownorm: writes x_out AND xn
  combine_norm<<<8192, 256, 0, stream>>>(P0, P1, mlp_b2, x_out, xn);

  // ---- phase 5: scoring tail (f32) ----
  gather_kernel<<<12288, 256, 0, stream>>>(x_b, base_idxs, tokens, maskf);
  gemm128<0, 1, false, false><<<dim3(4, 4, 8), 256, 0, stream>>>(
      tokens, tokens, aw, nullptr, nullptr, nullptr, nullptr,
      512, 512, 768, 768, 768, 512,
      1, 1, 393216, 0, 0, 393216, 0, 0, 262144, 0, 0, sc_scale);
  softmax_kernel<2, true><<<8 * 512, 256, 0, stream>>>(aw, maskf);
  gemm128<0, 0, false, false><<<dim3(6, 4, 8), 256, 0, stream>>>(
      aw, tokens, agg, nullptr, nullptr, nullptr, nullptr,
      512, 768, 512, 512, 768, 768,
      1, 1, 262144, 0, 0, 393216, 0, 0, 393216, 0, 0, 1.0f);
  kernel_kernel<<<8, 256, 0, stream>>>(agg, maskf, kern_out, hasf);
  pos_kernel<<<B_ * NS_, 256, 0, stream>>>(xn, kern_out, hasf, pos_out);
  topk_kernel<<<8, 256, 0, stream>>>(pos_out, sel_out, topi_out);
}